// Round 7
// baseline (1276.829 us; speedup 1.0000x reference)
//
#include <hip/hip_runtime.h>
#include <hip/hip_bf16.h>
#include <cstdint>
#include <cstddef>

namespace {

constexpr int kB = 128;
constexpr int kS = 512;
constexpr int kM = kB * kS;   // 65536 rows

typedef __hip_bfloat16 bf16;
typedef __attribute__((ext_vector_type(8))) short short8;
typedef __attribute__((ext_vector_type(4))) float f32x4;

__device__ __forceinline__ float sig_(float x) {
  return __builtin_amdgcn_rcpf(1.f + __expf(-x));
}
__device__ __forceinline__ float tanh_(float x) {
  return 1.f - 2.f * __builtin_amdgcn_rcpf(__expf(2.f * x) + 1.f);
}
__device__ __forceinline__ float b2f(bf16 h) { return __bfloat162float(h); }
__device__ __forceinline__ bf16 f2b(float f) { return __float2bfloat16(f); }

// unpack 8 bf16 (one uint4) -> 8 floats
__device__ __forceinline__ void unpack8(uint4 v, float* o) {
  o[0] = __uint_as_float(v.x << 16); o[1] = __uint_as_float(v.x & 0xffff0000u);
  o[2] = __uint_as_float(v.y << 16); o[3] = __uint_as_float(v.y & 0xffff0000u);
  o[4] = __uint_as_float(v.z << 16); o[5] = __uint_as_float(v.z & 0xffff0000u);
  o[6] = __uint_as_float(v.w << 16); o[7] = __uint_as_float(v.w & 0xffff0000u);
}

__device__ __forceinline__ void gl_lds16(const void* g, void* l) {
  __builtin_amdgcn_global_load_lds((const __attribute__((address_space(1))) void*)g,
                                   (__attribute__((address_space(3))) void*)l, 16, 0, 0);
}

// fp32 -> bf16 weight conversion
__global__ void k_w2b(const float* __restrict__ s, bf16* __restrict__ d, int n) {
  int i = blockIdx.x * 256 + threadIdx.x;
  if (i < n) d[i] = f2b(s[i]);
}

// ---------------------------------------------------------------------------
// K1: per-tap char projection table (fp32, 372KB)
// ---------------------------------------------------------------------------
__global__ void k_table(const float* __restrict__ emb,
                        const float* __restrict__ cw3,
                        const float* __restrict__ cw5,
                        const float* __restrict__ cw7,
                        float* __restrict__ tbl) {
  int e = blockIdx.x;           // 0..15*97-1
  int tap = e / 97, ch = e % 97;
  int f = threadIdx.x;          // 0..63
  const float* w; int kk, dk;
  if (tap < 3)      { w = cw3; kk = 3; dk = tap; }
  else if (tap < 8) { w = cw5; kk = 5; dk = tap - 3; }
  else              { w = cw7; kk = 7; dk = tap - 8; }
  const float* er = emb + ch * 128;
  float s = 0.f;
  for (int c = 0; c < 128; ++c) s = fmaf(er[c], w[(f * 128 + c) * kk + dk], s);
  tbl[(size_t)e * 64 + f] = s;
}

// ---------------------------------------------------------------------------
// K2: conv via table gathers + bias + relu -> bf16 (B*S, 192)
// ---------------------------------------------------------------------------
__global__ void k_conv(const int* __restrict__ x, const float* __restrict__ tbl,
                       const float* __restrict__ cb3, const float* __restrict__ cb5,
                       const float* __restrict__ cb7, bf16* __restrict__ outA) {
  __shared__ int chs[70];
  int b = blockIdx.x >> 3;
  int s0 = (blockIdx.x & 7) << 6;
  int tid = threadIdx.x;
  if (tid < 70) {
    int g = s0 - 3 + tid;
    chs[tid] = (g >= 0 && g < kS) ? x[b * kS + g] : 0;   // char 0 => zero row
  }
  __syncthreads();
  int wv = tid >> 6;
  int f = tid & 63;
  int ntap, tap0, half; const float* cb;
  if (wv == 0)      { ntap = 3; tap0 = 0; half = 1; cb = cb3; }
  else if (wv == 1) { ntap = 5; tap0 = 3; half = 2; cb = cb5; }
  else              { ntap = 7; tap0 = 8; half = 3; cb = cb7; }
  float bias = cb[f];
  for (int p = 0; p < 64; ++p) {
    float acc = bias;
    for (int dk = 0; dk < ntap; ++dk) {
      int c = chs[p + 3 - half + dk];
      acc += tbl[(size_t)((tap0 + dk) * 97 + c) * 64 + f];
    }
    outA[(size_t)(b * kS + s0 + p) * 192 + wv * 64 + f] = f2b(fmaxf(acc, 0.f));
  }
}

// ---------------------------------------------------------------------------
// K3: highway via MFMA, fused dual GEMM (Wa and Wg in one pass).
// ---------------------------------------------------------------------------
__global__ __launch_bounds__(256) void k_hw(
    const bf16* __restrict__ A,
    const bf16* __restrict__ Wa, const float* __restrict__ Ba,
    const bf16* __restrict__ Wg, const float* __restrict__ Bg,
    bf16* __restrict__ outB) {
  __shared__ __align__(16) short As[128 * 64];
  __shared__ __align__(16) short Was[64 * 64];
  __shared__ __align__(16) short Wgs[64 * 64];
  constexpr int K = 192;
  int tid = threadIdx.x;
  int w = tid >> 6, l = tid & 63;
  int m0 = blockIdx.x * 128, n0 = blockIdx.y * 64;
  int wr = w >> 1, wc = w & 1;
  int lr = l >> 3, lc = l & 7;
  f32x4 accA[4][2], accG[4][2];
#pragma unroll
  for (int i = 0; i < 4; ++i)
#pragma unroll
    for (int j = 0; j < 2; ++j) { accA[i][j] = (f32x4)0.f; accG[i][j] = (f32x4)0.f; }

  for (int kc = 0; kc < K; kc += 64) {
    __syncthreads();
#pragma unroll
    for (int i = 0; i < 4; ++i) {
      int r = w * 32 + i * 8;
      gl_lds16(A + (size_t)(m0 + r + lr) * K + kc + lc * 8, &As[r * 64]);
    }
#pragma unroll
    for (int i = 0; i < 2; ++i) {
      int r = w * 16 + i * 8;
      gl_lds16(Wa + (size_t)(n0 + r + lr) * K + kc + lc * 8, &Was[r * 64]);
      gl_lds16(Wg + (size_t)(n0 + r + lr) * K + kc + lc * 8, &Wgs[r * 64]);
    }
    __syncthreads();
#pragma unroll
    for (int kf = 0; kf < 2; ++kf) {
      short8 af[4], ba[2], bg[2];
#pragma unroll
      for (int mt = 0; mt < 4; ++mt)
        af[mt] = *(const short8*)&As[(wr * 64 + mt * 16 + (l & 15)) * 64 + kf * 32 + (l >> 4) * 8];
#pragma unroll
      for (int nt = 0; nt < 2; ++nt) {
        int rn = (wc * 32 + nt * 16 + (l & 15)) * 64 + kf * 32 + (l >> 4) * 8;
        ba[nt] = *(const short8*)&Was[rn];
        bg[nt] = *(const short8*)&Wgs[rn];
      }
#pragma unroll
      for (int mt = 0; mt < 4; ++mt)
#pragma unroll
        for (int nt = 0; nt < 2; ++nt) {
          accA[mt][nt] = __builtin_amdgcn_mfma_f32_16x16x32_bf16(af[mt], ba[nt], accA[mt][nt], 0, 0, 0);
          accG[mt][nt] = __builtin_amdgcn_mfma_f32_16x16x32_bf16(af[mt], bg[nt], accG[mt][nt], 0, 0, 0);
        }
    }
  }
#pragma unroll
  for (int nt = 0; nt < 2; ++nt) {
    int n = n0 + wc * 32 + nt * 16 + (l & 15);
    float bav = Ba[n], bgv = Bg[n];
#pragma unroll
    for (int mt = 0; mt < 4; ++mt) {
      int mb = m0 + wr * 64 + mt * 16 + (l >> 4) * 4;
#pragma unroll
      for (int r = 0; r < 4; ++r) {
        float av = accA[mt][nt][r] + bav;
        float gv = accG[mt][nt][r] + bgv;
        float tt = sig_(gv);
        float orig = b2f(A[(size_t)(mb + r) * K + n]);
        outB[(size_t)(mb + r) * K + n] = f2b(tt * fmaxf(av, 0.f) + (1.f - tt) * orig);
      }
    }
  }
}

// ---------------------------------------------------------------------------
// K4: LSTM input projection via MFMA. BM=128, BN=128, BK=64, 4 waves 2x2.
// xg written TIME-MAJOR + GATE-LAST: xg[(t*128+seq)*1024 + dir*512 + u*4 + g]
// so the recurrence reads one uint2 (4 gates) per cell.
// ---------------------------------------------------------------------------
__global__ __launch_bounds__(256) void k_pgemm(
    const bf16* __restrict__ A, int K,
    const bf16* __restrict__ W,
    const float* __restrict__ bfw, const float* __restrict__ bbw,
    bf16* __restrict__ xg) {
  __shared__ __align__(16) short As[128 * 64];
  __shared__ __align__(16) short Bs[128 * 64];
  int tid = threadIdx.x;
  int w = tid >> 6, l = tid & 63;
  int m0 = blockIdx.x * 128, n0 = blockIdx.y * 128;
  int wr = w >> 1, wc = w & 1;
  int lr = l >> 3, lc = l & 7;
  f32x4 acc[4][4];
#pragma unroll
  for (int i = 0; i < 4; ++i)
#pragma unroll
    for (int j = 0; j < 4; ++j) acc[i][j] = (f32x4)0.f;

  for (int kc = 0; kc < K; kc += 64) {
    __syncthreads();
#pragma unroll
    for (int i = 0; i < 4; ++i) {
      int r = w * 32 + i * 8;
      gl_lds16(A + (size_t)(m0 + r + lr) * K + kc + lc * 8, &As[r * 64]);
      gl_lds16(W + (size_t)(n0 + r + lr) * K + kc + lc * 8, &Bs[r * 64]);
    }
    __syncthreads();
#pragma unroll
    for (int kf = 0; kf < 2; ++kf) {
      short8 af[4], bfr[4];
#pragma unroll
      for (int mt = 0; mt < 4; ++mt)
        af[mt] = *(const short8*)&As[(wr * 64 + mt * 16 + (l & 15)) * 64 + kf * 32 + (l >> 4) * 8];
#pragma unroll
      for (int nt = 0; nt < 4; ++nt)
        bfr[nt] = *(const short8*)&Bs[(wc * 64 + nt * 16 + (l & 15)) * 64 + kf * 32 + (l >> 4) * 8];
#pragma unroll
      for (int mt = 0; mt < 4; ++mt)
#pragma unroll
        for (int nt = 0; nt < 4; ++nt)
          acc[mt][nt] = __builtin_amdgcn_mfma_f32_16x16x32_bf16(af[mt], bfr[nt], acc[mt][nt], 0, 0, 0);
    }
  }
#pragma unroll
  for (int nt = 0; nt < 4; ++nt) {
    int n = n0 + wc * 64 + nt * 16 + (l & 15);
    float bv = (n < 512) ? bfw[n] : bbw[n - 512];
    int ncol = (n & 512) + ((n & 127) << 2) + ((n >> 7) & 3);   // gate-last remap
#pragma unroll
    for (int mt = 0; mt < 4; ++mt) {
      int mb = m0 + wr * 64 + mt * 16 + (l >> 4) * 4;
#pragma unroll
      for (int r = 0; r < 4; ++r) {
        int row = mb + r;                                  // seq-major: seq*512+t
        int rp = ((row & 511) << 7) | (row >> 9);          // time-major: t*128+seq
        xg[((size_t)rp << 10) + ncol] = f2b(acc[mt][nt][r] + bv);
      }
    }
  }
}

// ---------------------------------------------------------------------------
// K5: LSTM recurrence as per-step batched MFMA GEMM.  v3.
// Grid 64 = (dir 0..1) x (32 groups of 4 seqs). 512 threads = 8 waves (2/SIMD).
// Wave w owns u-chunk [w*16,w*16+16) for all 4 gates: 16 MFMA/step, wf=64 VGPR.
// B-fragment read from HT[l&3] -> MFMA col c carries seq (c&3) (broadcast,
// conflict-free). Then lane l's own acc holds a valid z for exactly one cell:
//   u_local=(l>>4)*4+((l>>2)&3), s=l&3, z[g]=acc[g][(l>>2)&3]  (3 cndmask/gate,
// no cross-lane ops). 1 cell/lane => 10 transcendentals/lane/step.
// xg gate-last: one uint2 per lane per step, prefetch distance 2.
// HT double-buffered [2][4][136] bf16; one barrier per step.
// ---------------------------------------------------------------------------
__global__ __launch_bounds__(512, 2) void k_rec3(
    const bf16* __restrict__ xg,
    const bf16* __restrict__ whhF, const bf16* __restrict__ whhB,
    bf16* __restrict__ out) {
  int blk = blockIdx.x;
  int dir = blk >> 5;
  int seq0 = (blk & 31) * 4;
  const short* whhs = (const short*)(dir ? whhB : whhF);
  const bool rev = (dir == 1);
  int tid = threadIdx.x;
  int w = tid >> 6, l = tid & 63;
  int ln = l & 15, lk = l >> 4;
  int s = l & 3;
  int r = (l >> 2) & 3;
  int ul = lk * 4 + r;            // my u within wave chunk (0..15)
  int u = w * 16 + ul;            // my u (0..127)
  int seq = seq0 + s;

  // whh A-fragments in registers: wf[g][kk], row = g*128 + w*16 + ln
  short8 wf[4][4];
#pragma unroll
  for (int g = 0; g < 4; ++g)
#pragma unroll
    for (int kk = 0; kk < 4; ++kk)
      wf[g][kk] = *(const short8*)&whhs[(size_t)(g * 128 + w * 16 + ln) * 128 + kk * 32 + lk * 8];

  __shared__ __align__(16) short HT[2][4][136];
  for (int i = tid; i < 2 * 4 * 136; i += 512) ((short*)HT)[i] = 0;

  float c = 0.f;

  const bf16* xbase = xg + (size_t)seq * 1024 + dir * 512 + u * 4;
  bf16* obase = out + (size_t)seq * 131072 + (size_t)dir * 128 + u;

  uint2 xA, xB;
  {
    int p0 = rev ? 511 : 0, p1 = rev ? 510 : 1;
    xA = *(const uint2*)(xbase + ((size_t)p0 << 17));
    xB = *(const uint2*)(xbase + ((size_t)p1 << 17));
  }
  __syncthreads();

  auto do_step = [&](int tphys, int tpref, const short* RB, short* WB, uint2& x) {
    // B-fragments: col c of B = h[seq c&3]  (broadcast read of rows 0..3)
    short8 b0 = *(const short8*)&RB[s * 136 + 0  + lk * 8];
    short8 b1 = *(const short8*)&RB[s * 136 + 32 + lk * 8];
    short8 b2 = *(const short8*)&RB[s * 136 + 64 + lk * 8];
    short8 b3 = *(const short8*)&RB[s * 136 + 96 + lk * 8];
    uint2 xc = x;
    x = *(const uint2*)(xbase + ((size_t)tpref << 17));   // prefetch t+2
    // Z = whh @ h : 16 MFMAs (4 independent chains of depth 4)
    f32x4 a[4];
#pragma unroll
    for (int g = 0; g < 4; ++g) a[g] = (f32x4)0.f;
#pragma unroll
    for (int g = 0; g < 4; ++g) a[g] = __builtin_amdgcn_mfma_f32_16x16x32_bf16(wf[g][0], b0, a[g], 0, 0, 0);
#pragma unroll
    for (int g = 0; g < 4; ++g) a[g] = __builtin_amdgcn_mfma_f32_16x16x32_bf16(wf[g][1], b1, a[g], 0, 0, 0);
#pragma unroll
    for (int g = 0; g < 4; ++g) a[g] = __builtin_amdgcn_mfma_f32_16x16x32_bf16(wf[g][2], b2, a[g], 0, 0, 0);
#pragma unroll
    for (int g = 0; g < 4; ++g) a[g] = __builtin_amdgcn_mfma_f32_16x16x32_bf16(wf[g][3], b3, a[g], 0, 0, 0);
    // in-lane select: z[g] = a[g][r]
    float z[4];
#pragma unroll
    for (int g = 0; g < 4; ++g) {
      float v01 = (r & 1) ? a[g][1] : a[g][0];
      float v23 = (r & 1) ? a[g][3] : a[g][2];
      z[g] = (r & 2) ? v23 : v01;
    }
    float xi = __uint_as_float(xc.x << 16);
    float xf = __uint_as_float(xc.x & 0xffff0000u);
    float xm = __uint_as_float(xc.y << 16);
    float xo = __uint_as_float(xc.y & 0xffff0000u);
    float ig = sig_(z[0] + xi), fg = sig_(z[1] + xf);
    float gv = tanh_(z[2] + xm), og = sig_(z[3] + xo);
    c = fmaf(fg, c, ig * gv);
    float h = og * tanh_(c);
    bf16 hb = f2b(h);
    unsigned short hs = *(unsigned short*)&hb;
    WB[s * 136 + u - w * 16 + w * 16] = 0;  // (no-op placeholder removed below)
    *(short*)&WB[s * 136 + u] = (short)hs;            // h -> HT[nxt] row s
    *(bf16*)(obase + (size_t)tphys * 256) = hb;       // h -> global
  };

  for (int t = 0; t < kS; t += 2) {
    int ta = rev ? 511 - t : t;
    int tb = rev ? 510 - t : t + 1;
    int pa = (t + 2 < kS) ? t + 2 : kS - 1;
    int pb = (t + 3 < kS) ? t + 3 : kS - 1;
    int tpa = rev ? 511 - pa : pa;
    int tpb = rev ? 511 - pb : pb;
    do_step(ta, tpa, &HT[0][0][0], &HT[1][0][0], xA);
    __syncthreads();
    do_step(tb, tpb, &HT[1][0][0], &HT[0][0][0], xB);
    __syncthreads();
  }
}

// ---------------------------------------------------------------------------
// K6: classifier + char mask. out1 bf16 -> em fp32 (or NEG)
// ---------------------------------------------------------------------------
__global__ __launch_bounds__(256) void k_cls(
    const bf16* __restrict__ out1, const float* __restrict__ cls_w,
    const float* __restrict__ cls_b, const int* __restrict__ x,
    float* __restrict__ em) {
  __shared__ float W[17 * 256];
  __shared__ float part[64 * 4 * 17];
  int tid = threadIdx.x;
  for (int i = tid; i < 17 * 256; i += 256) W[i] = cls_w[i];
  __syncthreads();
  int r = tid >> 2, q = tid & 3;
  size_t row = (size_t)blockIdx.x * 64 + r;
  float acc[17];
#pragma unroll
  for (int j = 0; j < 17; ++j) acc[j] = 0.f;
  const uint4* a4p = (const uint4*)(out1 + row * 256 + q * 64);
  for (int i = 0; i < 8; ++i) {
    float f8[8]; unpack8(a4p[i], f8);
#pragma unroll
    for (int j = 0; j < 17; ++j) {
      const float* wr = &W[j * 256 + q * 64 + i * 8];
#pragma unroll
      for (int e = 0; e < 8; ++e) acc[j] = fmaf(f8[e], wr[e], acc[j]);
    }
  }
#pragma unroll
  for (int j = 0; j < 17; ++j) part[(r * 4 + q) * 17 + j] = acc[j];
  __syncthreads();
  for (int idx = tid; idx < 64 * 17; idx += 256) {
    int rr = idx / 17, j = idx % 17;
    size_t row2 = (size_t)blockIdx.x * 64 + rr;
    float v = part[(rr * 4 + 0) * 17 + j] + part[(rr * 4 + 1) * 17 + j] +
              part[(rr * 4 + 2) * 17 + j] + part[(rr * 4 + 3) * 17 + j] + cls_b[j];
    em[row2 * 17 + j] = (x[row2] != 0) ? v : -1e9f;
  }
}

// ---------------------------------------------------------------------------
// K7: CRF loss per sequence (1 wave / block). res[b] = logZ - score
// ---------------------------------------------------------------------------
__global__ __launch_bounds__(64) void k_crf(
    const float* __restrict__ em, const int* __restrict__ tags,
    const float* __restrict__ mask, const float* __restrict__ trans,
    const float* __restrict__ start_t, const float* __restrict__ end_t,
    float* __restrict__ res) {
  int b = blockIdx.x;
  int lane = threadIdx.x;
  const float* emB = em + (size_t)b * kS * 17;
  const int* tg = tags + b * kS;
  const float* mk = mask + b * kS;

  float tcol[17];
  if (lane < 17) {
#pragma unroll
    for (int i = 0; i < 17; ++i) tcol[i] = trans[i * 17 + lane];
  }
  float sc = 0.f, msum = 0.f;
  for (int t = lane; t < kS; t += 64) msum += mk[t];
  for (int t = 1 + lane; t < kS; t += 64)
    sc += (trans[tg[t - 1] * 17 + tg[t]] + emB[(size_t)t * 17 + tg[t]]) * mk[t];
#pragma unroll
  for (int o = 32; o; o >>= 1) { sc += __shfl_xor(sc, o); msum += __shfl_xor(msum, o); }

  __shared__ float al[17];
  if (lane < 17) al[lane] = start_t[lane] + emB[lane];
  __syncthreads();
  for (int t = 1; t < kS; ++t) {
    float nxt = 0.f;
    if (lane < 17) {
      float v[17]; float mx = -3.4e38f;
#pragma unroll
      for (int i = 0; i < 17; ++i) { v[i] = al[i] + tcol[i]; mx = fmaxf(mx, v[i]); }
      float s = 0.f;
#pragma unroll
      for (int i = 0; i < 17; ++i) s += __expf(v[i] - mx);
      float m = mk[t];
      nxt = (mx + __logf(s) + emB[(size_t)t * 17 + lane]) * m + al[lane] * (1.f - m);
    }
    __syncthreads();
    if (lane < 17) al[lane] = nxt;
    __syncthreads();
  }
  float val = (lane < 17) ? al[lane] + end_t[lane] : -3.4e38f;
  float mx = val;
#pragma unroll
  for (int o = 32; o; o >>= 1) mx = fmaxf(mx, __shfl_xor(mx, o));
  float s = (lane < 17) ? __expf(val - mx) : 0.f;
#pragma unroll
  for (int o = 32; o; o >>= 1) s += __shfl_xor(s, o);
  float logZ = mx + __logf(s);
  if (lane == 0) {
    float score = sc + start_t[tg[0]] + emB[tg[0]];
    int last_real = (int)(msum + 0.5f) - 1;
    if (last_real >= 0) score += end_t[tg[last_real]];
    res[b] = logZ - score;
  }
}

// K8: deterministic mean over 128 sequences -> d_out[0]
__global__ void k_loss(const float* __restrict__ res, float* __restrict__ out) {
  __shared__ float s[128];
  int tid = threadIdx.x;
  s[tid] = res[tid];
  __syncthreads();
  for (int off = 64; off; off >>= 1) {
    if (tid < off) s[tid] += s[tid + off];
    __syncthreads();
  }
  if (tid == 0) out[0] = s[0] / 128.f;
}

}  // namespace

extern "C" void kernel_launch(void* const* d_in, const int* in_sizes, int n_in,
                              void* d_out, int out_size, void* d_ws, size_t ws_size,
                              hipStream_t stream) {
  (void)in_sizes; (void)n_in; (void)out_size; (void)ws_size;
  const int*   x       = (const int*)  d_in[0];
  const int*   tags    = (const int*)  d_in[1];
  const float* mask    = (const float*)d_in[2];
  const float* emb     = (const float*)d_in[3];
  const float* cw3     = (const float*)d_in[4];
  const float* cb3     = (const float*)d_in[5];
  const float* cw5     = (const float*)d_in[6];
  const float* cb5     = (const float*)d_in[7];
  const float* cw7     = (const float*)d_in[8];
  const float* cb7     = (const float*)d_in[9];
  const float* hw_w    = (const float*)d_in[10];
  const float* hw_b    = (const float*)d_in[11];
  const float* hwg_w   = (const float*)d_in[12];
  const float* hwg_b   = (const float*)d_in[13];
  const float* wih0f   = (const float*)d_in[14];
  const float* whh0f   = (const float*)d_in[15];
  const float* b0f     = (const float*)d_in[16];
  const float* wih0b   = (const float*)d_in[17];
  const float* whh0b   = (const float*)d_in[18];
  const float* b0b     = (const float*)d_in[19];
  const float* wih1f   = (const float*)d_in[20];
  const float* whh1f   = (const float*)d_in[21];
  const float* b1f     = (const float*)d_in[22];
  const float* wih1b   = (const float*)d_in[23];
  const float* whh1b   = (const float*)d_in[24];
  const float* b1b     = (const float*)d_in[25];
  const float* cls_w   = (const float*)d_in[26];
  const float* cls_b   = (const float*)d_in[27];
  const float* trans   = (const float*)d_in[28];
  const float* start_t = (const float*)d_in[29];
  const float* end_t   = (const float*)d_in[30];

  // Workspace layout. tbl fp32 | bf16 weights | bf16 activations. ~210 MB.
  char* ws = (char*)d_ws;
  const size_t OFF_W0 = 393216;                            // tbl is [0, 372KB)
  const size_t OFF_W1 = OFF_W0 + (size_t)1024 * 192 * 2;
  const size_t OFF_WA = OFF_W1 + (size_t)1024 * 256 * 2;
  const size_t OFF_WG = OFF_WA + (size_t)192 * 192 * 2;
  const size_t OFF_WH = OFF_WG + (size_t)192 * 192 * 2;    // 4x whh bf16 (512KB)
  const size_t OFF_A  = OFF_WH + (size_t)4 * 512 * 128 * 2;
  const size_t SZ_A   = (size_t)kM * 192 * 2;              // 24 MB
  const size_t OFF_B  = OFF_A + SZ_A;
  const size_t OFF_O0 = OFF_B + SZ_A;                      // out0 bf16 (32MB); em fp32 later
  const size_t OFF_XG = OFF_O0 + (size_t)kM * 256 * 2;     // xg bf16 dual (128MB)
  float* tbl  = (float*)ws;
  bf16*  W0b  = (bf16*)(ws + OFF_W0);
  bf16*  W1b  = (bf16*)(ws + OFF_W1);
  bf16*  WAb  = (bf16*)(ws + OFF_WA);
  bf16*  WGb  = (bf16*)(ws + OFF_WG);
  bf16*  WHb  = (bf16*)(ws + OFF_WH);
  bf16*  bufA = (bf16*)(ws + OFF_A);
  bf16*  bufB = (bf16*)(ws + OFF_B);
  bf16*  out0 = (bf16*)(ws + OFF_O0);
  bf16*  out1 = (bf16*)(ws + OFF_A);                       // bufA/bufB dead by rec1
  bf16*  xg   = (bf16*)(ws + OFF_XG);
  float* em   = (float*)(ws + OFF_O0);                     // out0 dead after proj1
  float* resv = (float*)(ws + OFF_O0 + (size_t)kM * 17 * 4);

  // weight conversion prepass
  k_w2b<<<384, 256, 0, stream>>>(wih0f, W0b, 512 * 192);
  k_w2b<<<384, 256, 0, stream>>>(wih0b, W0b + 512 * 192, 512 * 192);
  k_w2b<<<512, 256, 0, stream>>>(wih1f, W1b, 512 * 256);
  k_w2b<<<512, 256, 0, stream>>>(wih1b, W1b + 512 * 256, 512 * 256);
  k_w2b<<<144, 256, 0, stream>>>(hw_w, WAb, 192 * 192);
  k_w2b<<<144, 256, 0, stream>>>(hwg_w, WGb, 192 * 192);
  k_w2b<<<256, 256, 0, stream>>>(whh0f, WHb + 0 * 65536, 512 * 128);
  k_w2b<<<256, 256, 0, stream>>>(whh0b, WHb + 1 * 65536, 512 * 128);
  k_w2b<<<256, 256, 0, stream>>>(whh1f, WHb + 2 * 65536, 512 * 128);
  k_w2b<<<256, 256, 0, stream>>>(whh1b, WHb + 3 * 65536, 512 * 128);

  k_table<<<15 * 97, 64, 0, stream>>>(emb, cw3, cw5, cw7, tbl);
  k_conv<<<kB * (kS / 64), 192, 0, stream>>>(x, tbl, cb3, cb5, cb7, bufA);
  k_hw<<<dim3(kM / 128, 3), 256, 0, stream>>>(bufA, WAb, hw_b, WGb, hwg_b, bufB);

  k_pgemm<<<dim3(kM / 128, 8), 256, 0, stream>>>(bufB, 192, W0b, b0f, b0b, xg);
  k_rec3<<<64, 512, 0, stream>>>(xg, WHb + 0 * 65536, WHb + 1 * 65536, out0);
  k_pgemm<<<dim3(kM / 128, 8), 256, 0, stream>>>(out0, 256, W1b, b1f, b1b, xg);
  k_rec3<<<64, 512, 0, stream>>>(xg, WHb + 2 * 65536, WHb + 3 * 65536, out1);

  k_cls<<<kM / 64, 256, 0, stream>>>(out1, cls_w, cls_b, x, em);
  k_crf<<<kB, 64, 0, stream>>>(em, tags, mask, trans, start_t, end_t, resv);
  k_loss<<<1, 128, 0, stream>>>(resv, (float*)d_out);
}

// Round 8
// 1121.345 us; speedup vs baseline: 1.1387x; 1.1387x over previous
//
#include <hip/hip_runtime.h>
#include <hip/hip_bf16.h>
#include <cstdint>
#include <cstddef>

namespace {

constexpr int kB = 128;
constexpr int kS = 512;
constexpr int kM = kB * kS;   // 65536 rows

typedef __hip_bfloat16 bf16;
typedef __attribute__((ext_vector_type(8))) short short8;
typedef __attribute__((ext_vector_type(4))) float f32x4;

__device__ __forceinline__ float sig_(float x) {
  return __builtin_amdgcn_rcpf(1.f + __expf(-x));
}
__device__ __forceinline__ float tanh_(float x) {
  return 1.f - 2.f * __builtin_amdgcn_rcpf(__expf(2.f * x) + 1.f);
}
__device__ __forceinline__ float b2f(bf16 h) { return __bfloat162float(h); }
__device__ __forceinline__ bf16 f2b(float f) { return __float2bfloat16(f); }

// unpack 8 bf16 (one uint4) -> 8 floats
__device__ __forceinline__ void unpack8(uint4 v, float* o) {
  o[0] = __uint_as_float(v.x << 16); o[1] = __uint_as_float(v.x & 0xffff0000u);
  o[2] = __uint_as_float(v.y << 16); o[3] = __uint_as_float(v.y & 0xffff0000u);
  o[4] = __uint_as_float(v.z << 16); o[5] = __uint_as_float(v.z & 0xffff0000u);
  o[6] = __uint_as_float(v.w << 16); o[7] = __uint_as_float(v.w & 0xffff0000u);
}

__device__ __forceinline__ void gl_lds16(const void* g, void* l) {
  __builtin_amdgcn_global_load_lds((const __attribute__((address_space(1))) void*)g,
                                   (__attribute__((address_space(3))) void*)l, 16, 0, 0);
}

// fp32 -> bf16 weight conversion
__global__ void k_w2b(const float* __restrict__ s, bf16* __restrict__ d, int n) {
  int i = blockIdx.x * 256 + threadIdx.x;
  if (i < n) d[i] = f2b(s[i]);
}

// fp32 -> bf16 with gate-last row permutation: dst row (u*4+g) = src row (g*128+u)
__global__ void k_w2bp(const float* __restrict__ s, bf16* __restrict__ d, int K) {
  int i = blockIdx.x * 256 + threadIdx.x;
  if (i >= 512 * K) return;
  int n = i / K, k = i - n * K;
  int src = ((n & 3) * 128 + (n >> 2)) * K + k;
  d[i] = f2b(s[src]);
}

// ---------------------------------------------------------------------------
// K1: per-tap char projection table (fp32, 372KB)
// ---------------------------------------------------------------------------
__global__ void k_table(const float* __restrict__ emb,
                        const float* __restrict__ cw3,
                        const float* __restrict__ cw5,
                        const float* __restrict__ cw7,
                        float* __restrict__ tbl) {
  int e = blockIdx.x;           // 0..15*97-1
  int tap = e / 97, ch = e % 97;
  int f = threadIdx.x;          // 0..63
  const float* w; int kk, dk;
  if (tap < 3)      { w = cw3; kk = 3; dk = tap; }
  else if (tap < 8) { w = cw5; kk = 5; dk = tap - 3; }
  else              { w = cw7; kk = 7; dk = tap - 8; }
  const float* er = emb + ch * 128;
  float s = 0.f;
  for (int c = 0; c < 128; ++c) s = fmaf(er[c], w[(f * 128 + c) * kk + dk], s);
  tbl[(size_t)e * 64 + f] = s;
}

// ---------------------------------------------------------------------------
// K2: conv via table gathers + bias + relu -> bf16 (B*S, 192)
// ---------------------------------------------------------------------------
__global__ void k_conv(const int* __restrict__ x, const float* __restrict__ tbl,
                       const float* __restrict__ cb3, const float* __restrict__ cb5,
                       const float* __restrict__ cb7, bf16* __restrict__ outA) {
  __shared__ int chs[70];
  int b = blockIdx.x >> 3;
  int s0 = (blockIdx.x & 7) << 6;
  int tid = threadIdx.x;
  if (tid < 70) {
    int g = s0 - 3 + tid;
    chs[tid] = (g >= 0 && g < kS) ? x[b * kS + g] : 0;   // char 0 => zero row
  }
  __syncthreads();
  int wv = tid >> 6;
  int f = tid & 63;
  int ntap, tap0, half; const float* cb;
  if (wv == 0)      { ntap = 3; tap0 = 0; half = 1; cb = cb3; }
  else if (wv == 1) { ntap = 5; tap0 = 3; half = 2; cb = cb5; }
  else              { ntap = 7; tap0 = 8; half = 3; cb = cb7; }
  float bias = cb[f];
  for (int p = 0; p < 64; ++p) {
    float acc = bias;
    for (int dk = 0; dk < ntap; ++dk) {
      int c = chs[p + 3 - half + dk];
      acc += tbl[(size_t)((tap0 + dk) * 97 + c) * 64 + f];
    }
    outA[(size_t)(b * kS + s0 + p) * 192 + wv * 64 + f] = f2b(fmaxf(acc, 0.f));
  }
}

// ---------------------------------------------------------------------------
// K3: highway via MFMA, fused dual GEMM (Wa and Wg in one pass).
// ---------------------------------------------------------------------------
__global__ __launch_bounds__(256) void k_hw(
    const bf16* __restrict__ A,
    const bf16* __restrict__ Wa, const float* __restrict__ Ba,
    const bf16* __restrict__ Wg, const float* __restrict__ Bg,
    bf16* __restrict__ outB) {
  __shared__ __align__(16) short As[128 * 64];
  __shared__ __align__(16) short Was[64 * 64];
  __shared__ __align__(16) short Wgs[64 * 64];
  constexpr int K = 192;
  int tid = threadIdx.x;
  int w = tid >> 6, l = tid & 63;
  int m0 = blockIdx.x * 128, n0 = blockIdx.y * 64;
  int wr = w >> 1, wc = w & 1;
  int lr = l >> 3, lc = l & 7;
  f32x4 accA[4][2], accG[4][2];
#pragma unroll
  for (int i = 0; i < 4; ++i)
#pragma unroll
    for (int j = 0; j < 2; ++j) { accA[i][j] = (f32x4)0.f; accG[i][j] = (f32x4)0.f; }

  for (int kc = 0; kc < K; kc += 64) {
    __syncthreads();
#pragma unroll
    for (int i = 0; i < 4; ++i) {
      int r = w * 32 + i * 8;
      gl_lds16(A + (size_t)(m0 + r + lr) * K + kc + lc * 8, &As[r * 64]);
    }
#pragma unroll
    for (int i = 0; i < 2; ++i) {
      int r = w * 16 + i * 8;
      gl_lds16(Wa + (size_t)(n0 + r + lr) * K + kc + lc * 8, &Was[r * 64]);
      gl_lds16(Wg + (size_t)(n0 + r + lr) * K + kc + lc * 8, &Wgs[r * 64]);
    }
    __syncthreads();
#pragma unroll
    for (int kf = 0; kf < 2; ++kf) {
      short8 af[4], ba[2], bg[2];
#pragma unroll
      for (int mt = 0; mt < 4; ++mt)
        af[mt] = *(const short8*)&As[(wr * 64 + mt * 16 + (l & 15)) * 64 + kf * 32 + (l >> 4) * 8];
#pragma unroll
      for (int nt = 0; nt < 2; ++nt) {
        int rn = (wc * 32 + nt * 16 + (l & 15)) * 64 + kf * 32 + (l >> 4) * 8;
        ba[nt] = *(const short8*)&Was[rn];
        bg[nt] = *(const short8*)&Wgs[rn];
      }
#pragma unroll
      for (int mt = 0; mt < 4; ++mt)
#pragma unroll
        for (int nt = 0; nt < 2; ++nt) {
          accA[mt][nt] = __builtin_amdgcn_mfma_f32_16x16x32_bf16(af[mt], ba[nt], accA[mt][nt], 0, 0, 0);
          accG[mt][nt] = __builtin_amdgcn_mfma_f32_16x16x32_bf16(af[mt], bg[nt], accG[mt][nt], 0, 0, 0);
        }
    }
  }
#pragma unroll
  for (int nt = 0; nt < 2; ++nt) {
    int n = n0 + wc * 32 + nt * 16 + (l & 15);
    float bav = Ba[n], bgv = Bg[n];
#pragma unroll
    for (int mt = 0; mt < 4; ++mt) {
      int mb = m0 + wr * 64 + mt * 16 + (l >> 4) * 4;
#pragma unroll
      for (int r = 0; r < 4; ++r) {
        float av = accA[mt][nt][r] + bav;
        float gv = accG[mt][nt][r] + bgv;
        float tt = sig_(gv);
        float orig = b2f(A[(size_t)(mb + r) * K + n]);
        outB[(size_t)(mb + r) * K + n] = f2b(tt * fmaxf(av, 0.f) + (1.f - tt) * orig);
      }
    }
  }
}

// ---------------------------------------------------------------------------
// K4: LSTM input projection via MFMA. BM=128, BN=128, BK=64, 4 waves 2x2.
// W is PRE-PERMUTED to gate-last row order (row u*4+g), so the natural
// coalesced write produces xg[(t*128+seq)*1024 + dir*512 + u*4 + g].
// ---------------------------------------------------------------------------
__global__ __launch_bounds__(256) void k_pgemm(
    const bf16* __restrict__ A, int K,
    const bf16* __restrict__ W,
    const float* __restrict__ bfw, const float* __restrict__ bbw,
    bf16* __restrict__ xg) {
  __shared__ __align__(16) short As[128 * 64];
  __shared__ __align__(16) short Bs[128 * 64];
  int tid = threadIdx.x;
  int w = tid >> 6, l = tid & 63;
  int m0 = blockIdx.x * 128, n0 = blockIdx.y * 128;
  int wr = w >> 1, wc = w & 1;
  int lr = l >> 3, lc = l & 7;
  f32x4 acc[4][4];
#pragma unroll
  for (int i = 0; i < 4; ++i)
#pragma unroll
    for (int j = 0; j < 4; ++j) acc[i][j] = (f32x4)0.f;

  for (int kc = 0; kc < K; kc += 64) {
    __syncthreads();
#pragma unroll
    for (int i = 0; i < 4; ++i) {
      int r = w * 32 + i * 8;
      gl_lds16(A + (size_t)(m0 + r + lr) * K + kc + lc * 8, &As[r * 64]);
      gl_lds16(W + (size_t)(n0 + r + lr) * K + kc + lc * 8, &Bs[r * 64]);
    }
    __syncthreads();
#pragma unroll
    for (int kf = 0; kf < 2; ++kf) {
      short8 af[4], bfr[4];
#pragma unroll
      for (int mt = 0; mt < 4; ++mt)
        af[mt] = *(const short8*)&As[(wr * 64 + mt * 16 + (l & 15)) * 64 + kf * 32 + (l >> 4) * 8];
#pragma unroll
      for (int nt = 0; nt < 4; ++nt)
        bfr[nt] = *(const short8*)&Bs[(wc * 64 + nt * 16 + (l & 15)) * 64 + kf * 32 + (l >> 4) * 8];
#pragma unroll
      for (int mt = 0; mt < 4; ++mt)
#pragma unroll
        for (int nt = 0; nt < 4; ++nt)
          acc[mt][nt] = __builtin_amdgcn_mfma_f32_16x16x32_bf16(af[mt], bfr[nt], acc[mt][nt], 0, 0, 0);
    }
  }
#pragma unroll
  for (int nt = 0; nt < 4; ++nt) {
    int n = n0 + wc * 64 + nt * 16 + (l & 15);
    int nn = n & 511;
    float bv = ((n < 512) ? bfw : bbw)[(nn & 3) * 128 + (nn >> 2)];
#pragma unroll
    for (int mt = 0; mt < 4; ++mt) {
      int mb = m0 + wr * 64 + mt * 16 + (l >> 4) * 4;
#pragma unroll
      for (int r = 0; r < 4; ++r) {
        int row = mb + r;                                  // seq-major: seq*512+t
        int rp = ((row & 511) << 7) | (row >> 9);          // time-major: t*128+seq
        xg[((size_t)rp << 10) + n] = f2b(acc[mt][nt][r] + bv);
      }
    }
  }
}

// ---------------------------------------------------------------------------
// K5: LSTM recurrence as per-step batched MFMA GEMM.  v3.1.
// Grid 64 = (dir 0..1) x (32 groups of 4 seqs). 512 threads = 8 waves (2/SIMD).
// Wave w owns u-chunk [w*16,w*16+16) for all 4 gates: 16 MFMA/step, wf=64 VGPR.
// B-fragment read from HT[l&3] -> MFMA col c carries seq (c&3). Lane l's own
// acc holds z for (u=(l>>4)*4+((l>>2)&3), s=l&3): 3 cndmask/gate, no shuffles.
// HT stride 160 shorts (320B): b128 start-bank = (16s+4lk)%32 -> 2-way max.
// xg gate-last: one uint2/lane/step, prefetch distance 2. 1 barrier per step.
// ---------------------------------------------------------------------------
__global__ __launch_bounds__(512, 2) void k_rec3(
    const bf16* __restrict__ xg,
    const bf16* __restrict__ whhF, const bf16* __restrict__ whhB,
    bf16* __restrict__ out) {
  constexpr int HS = 160;   // HT row stride in shorts
  int blk = blockIdx.x;
  int dir = blk >> 5;
  int seq0 = (blk & 31) * 4;
  const short* whhs = (const short*)(dir ? whhB : whhF);
  const bool rev = (dir == 1);
  int tid = threadIdx.x;
  int w = tid >> 6, l = tid & 63;
  int ln = l & 15, lk = l >> 4;
  int s = l & 3;
  int r = (l >> 2) & 3;
  int ul = lk * 4 + r;            // my u within wave chunk (0..15)
  int u = w * 16 + ul;            // my u (0..127)
  int seq = seq0 + s;

  // whh A-fragments in registers: wf[g][kk], row = g*128 + w*16 + ln
  short8 wf[4][4];
#pragma unroll
  for (int g = 0; g < 4; ++g)
#pragma unroll
    for (int kk = 0; kk < 4; ++kk)
      wf[g][kk] = *(const short8*)&whhs[(size_t)(g * 128 + w * 16 + ln) * 128 + kk * 32 + lk * 8];

  __shared__ __align__(16) short HT[2][4][HS];
  for (int i = tid; i < 2 * 4 * HS; i += 512) ((short*)HT)[i] = 0;

  float c = 0.f;

  const bf16* xbase = xg + (size_t)seq * 1024 + dir * 512 + u * 4;
  bf16* obase = out + (size_t)seq * 131072 + (size_t)dir * 128 + u;

  uint2 xA, xB;
  {
    int p0 = rev ? 511 : 0, p1 = rev ? 510 : 1;
    xA = *(const uint2*)(xbase + ((size_t)p0 << 17));
    xB = *(const uint2*)(xbase + ((size_t)p1 << 17));
  }
  __syncthreads();

  auto do_step = [&](int tphys, int tpref, const short* RB, short* WB, uint2& x) {
    // B-fragments: col c of B = h[seq c&3]  (broadcast read of rows 0..3)
    short8 b0 = *(const short8*)&RB[s * HS + 0  + lk * 8];
    short8 b1 = *(const short8*)&RB[s * HS + 32 + lk * 8];
    short8 b2 = *(const short8*)&RB[s * HS + 64 + lk * 8];
    short8 b3 = *(const short8*)&RB[s * HS + 96 + lk * 8];
    uint2 xc = x;
    x = *(const uint2*)(xbase + ((size_t)tpref << 17));   // prefetch t+2
    // Z = whh @ h : 16 MFMAs (4 independent chains of depth 4)
    f32x4 a[4];
#pragma unroll
    for (int g = 0; g < 4; ++g) a[g] = (f32x4)0.f;
#pragma unroll
    for (int g = 0; g < 4; ++g) a[g] = __builtin_amdgcn_mfma_f32_16x16x32_bf16(wf[g][0], b0, a[g], 0, 0, 0);
#pragma unroll
    for (int g = 0; g < 4; ++g) a[g] = __builtin_amdgcn_mfma_f32_16x16x32_bf16(wf[g][1], b1, a[g], 0, 0, 0);
#pragma unroll
    for (int g = 0; g < 4; ++g) a[g] = __builtin_amdgcn_mfma_f32_16x16x32_bf16(wf[g][2], b2, a[g], 0, 0, 0);
#pragma unroll
    for (int g = 0; g < 4; ++g) a[g] = __builtin_amdgcn_mfma_f32_16x16x32_bf16(wf[g][3], b3, a[g], 0, 0, 0);
    // in-lane select: z[g] = a[g][r]
    float z[4];
#pragma unroll
    for (int g = 0; g < 4; ++g) {
      float v01 = (r & 1) ? a[g][1] : a[g][0];
      float v23 = (r & 1) ? a[g][3] : a[g][2];
      z[g] = (r & 2) ? v23 : v01;
    }
    float xi = __uint_as_float(xc.x << 16);
    float xf = __uint_as_float(xc.x & 0xffff0000u);
    float xm = __uint_as_float(xc.y << 16);
    float xo = __uint_as_float(xc.y & 0xffff0000u);
    float ig = sig_(z[0] + xi), fg = sig_(z[1] + xf);
    float gv = tanh_(z[2] + xm), og = sig_(z[3] + xo);
    c = fmaf(fg, c, ig * gv);
    float h = og * tanh_(c);
    bf16 hb = f2b(h);
    *(short*)&WB[s * HS + u] = *(short*)&hb;          // h -> HT[nxt] row s
    *(bf16*)(obase + (size_t)tphys * 256) = hb;       // h -> global
  };

  for (int t = 0; t < kS; t += 2) {
    int ta = rev ? 511 - t : t;
    int tb = rev ? 510 - t : t + 1;
    int pa = (t + 2 < kS) ? t + 2 : kS - 1;
    int pb = (t + 3 < kS) ? t + 3 : kS - 1;
    int tpa = rev ? 511 - pa : pa;
    int tpb = rev ? 511 - pb : pb;
    do_step(ta, tpa, &HT[0][0][0], &HT[1][0][0], xA);
    __syncthreads();
    do_step(tb, tpb, &HT[1][0][0], &HT[0][0][0], xB);
    __syncthreads();
  }
}

// ---------------------------------------------------------------------------
// K6: classifier + char mask. out1 bf16 -> em fp32 (or NEG)
// ---------------------------------------------------------------------------
__global__ __launch_bounds__(256) void k_cls(
    const bf16* __restrict__ out1, const float* __restrict__ cls_w,
    const float* __restrict__ cls_b, const int* __restrict__ x,
    float* __restrict__ em) {
  __shared__ float W[17 * 256];
  __shared__ float part[64 * 4 * 17];
  int tid = threadIdx.x;
  for (int i = tid; i < 17 * 256; i += 256) W[i] = cls_w[i];
  __syncthreads();
  int r = tid >> 2, q = tid & 3;
  size_t row = (size_t)blockIdx.x * 64 + r;
  float acc[17];
#pragma unroll
  for (int j = 0; j < 17; ++j) acc[j] = 0.f;
  const uint4* a4p = (const uint4*)(out1 + row * 256 + q * 64);
  for (int i = 0; i < 8; ++i) {
    float f8[8]; unpack8(a4p[i], f8);
#pragma unroll
    for (int j = 0; j < 17; ++j) {
      const float* wr = &W[j * 256 + q * 64 + i * 8];
#pragma unroll
      for (int e = 0; e < 8; ++e) acc[j] = fmaf(f8[e], wr[e], acc[j]);
    }
  }
#pragma unroll
  for (int j = 0; j < 17; ++j) part[(r * 4 + q) * 17 + j] = acc[j];
  __syncthreads();
  for (int idx = tid; idx < 64 * 17; idx += 256) {
    int rr = idx / 17, j = idx % 17;
    size_t row2 = (size_t)blockIdx.x * 64 + rr;
    float v = part[(rr * 4 + 0) * 17 + j] + part[(rr * 4 + 1) * 17 + j] +
              part[(rr * 4 + 2) * 17 + j] + part[(rr * 4 + 3) * 17 + j] + cls_b[j];
    em[row2 * 17 + j] = (x[row2] != 0) ? v : -1e9f;
  }
}

// ---------------------------------------------------------------------------
// K7: CRF loss per sequence (1 wave / block). res[b] = logZ - score
// ---------------------------------------------------------------------------
__global__ __launch_bounds__(64) void k_crf(
    const float* __restrict__ em, const int* __restrict__ tags,
    const float* __restrict__ mask, const float* __restrict__ trans,
    const float* __restrict__ start_t, const float* __restrict__ end_t,
    float* __restrict__ res) {
  int b = blockIdx.x;
  int lane = threadIdx.x;
  const float* emB = em + (size_t)b * kS * 17;
  const int* tg = tags + b * kS;
  const float* mk = mask + b * kS;

  float tcol[17];
  if (lane < 17) {
#pragma unroll
    for (int i = 0; i < 17; ++i) tcol[i] = trans[i * 17 + lane];
  }
  float sc = 0.f, msum = 0.f;
  for (int t = lane; t < kS; t += 64) msum += mk[t];
  for (int t = 1 + lane; t < kS; t += 64)
    sc += (trans[tg[t - 1] * 17 + tg[t]] + emB[(size_t)t * 17 + tg[t]]) * mk[t];
#pragma unroll
  for (int o = 32; o; o >>= 1) { sc += __shfl_xor(sc, o); msum += __shfl_xor(msum, o); }

  __shared__ float al[17];
  if (lane < 17) al[lane] = start_t[lane] + emB[lane];
  __syncthreads();
  for (int t = 1; t < kS; ++t) {
    float nxt = 0.f;
    if (lane < 17) {
      float v[17]; float mx = -3.4e38f;
#pragma unroll
      for (int i = 0; i < 17; ++i) { v[i] = al[i] + tcol[i]; mx = fmaxf(mx, v[i]); }
      float s = 0.f;
#pragma unroll
      for (int i = 0; i < 17; ++i) s += __expf(v[i] - mx);
      float m = mk[t];
      nxt = (mx + __logf(s) + emB[(size_t)t * 17 + lane]) * m + al[lane] * (1.f - m);
    }
    __syncthreads();
    if (lane < 17) al[lane] = nxt;
    __syncthreads();
  }
  float val = (lane < 17) ? al[lane] + end_t[lane] : -3.4e38f;
  float mx = val;
#pragma unroll
  for (int o = 32; o; o >>= 1) mx = fmaxf(mx, __shfl_xor(mx, o));
  float s = (lane < 17) ? __expf(val - mx) : 0.f;
#pragma unroll
  for (int o = 32; o; o >>= 1) s += __shfl_xor(s, o);
  float logZ = mx + __logf(s);
  if (lane == 0) {
    float score = sc + start_t[tg[0]] + emB[tg[0]];
    int last_real = (int)(msum + 0.5f) - 1;
    if (last_real >= 0) score += end_t[tg[last_real]];
    res[b] = logZ - score;
  }
}

// K8: deterministic mean over 128 sequences -> d_out[0]
__global__ void k_loss(const float* __restrict__ res, float* __restrict__ out) {
  __shared__ float s[128];
  int tid = threadIdx.x;
  s[tid] = res[tid];
  __syncthreads();
  for (int off = 64; off; off >>= 1) {
    if (tid < off) s[tid] += s[tid + off];
    __syncthreads();
  }
  if (tid == 0) out[0] = s[0] / 128.f;
}

}  // namespace

extern "C" void kernel_launch(void* const* d_in, const int* in_sizes, int n_in,
                              void* d_out, int out_size, void* d_ws, size_t ws_size,
                              hipStream_t stream) {
  (void)in_sizes; (void)n_in; (void)out_size; (void)ws_size;
  const int*   x       = (const int*)  d_in[0];
  const int*   tags    = (const int*)  d_in[1];
  const float* mask    = (const float*)d_in[2];
  const float* emb     = (const float*)d_in[3];
  const float* cw3     = (const float*)d_in[4];
  const float* cb3     = (const float*)d_in[5];
  const float* cw5     = (const float*)d_in[6];
  const float* cb5     = (const float*)d_in[7];
  const float* cw7     = (const float*)d_in[8];
  const float* cb7     = (const float*)d_in[9];
  const float* hw_w    = (const float*)d_in[10];
  const float* hw_b    = (const float*)d_in[11];
  const float* hwg_w   = (const float*)d_in[12];
  const float* hwg_b   = (const float*)d_in[13];
  const float* wih0f   = (const float*)d_in[14];
  const float* whh0f   = (const float*)d_in[15];
  const float* b0f     = (const float*)d_in[16];
  const float* wih0b   = (const float*)d_in[17];
  const float* whh0b   = (const float*)d_in[18];
  const float* b0b     = (const float*)d_in[19];
  const float* wih1f   = (const float*)d_in[20];
  const float* whh1f   = (const float*)d_in[21];
  const float* b1f     = (const float*)d_in[22];
  const float* wih1b   = (const float*)d_in[23];
  const float* whh1b   = (const float*)d_in[24];
  const float* b1b     = (const float*)d_in[25];
  const float* cls_w   = (const float*)d_in[26];
  const float* cls_b   = (const float*)d_in[27];
  const float* trans   = (const float*)d_in[28];
  const float* start_t = (const float*)d_in[29];
  const float* end_t   = (const float*)d_in[30];

  // Workspace layout. tbl fp32 | bf16 weights | bf16 activations. ~210 MB.
  char* ws = (char*)d_ws;
  const size_t OFF_W0 = 393216;                            // tbl is [0, 372KB)
  const size_t OFF_W1 = OFF_W0 + (size_t)1024 * 192 * 2;
  const size_t OFF_WA = OFF_W1 + (size_t)1024 * 256 * 2;
  const size_t OFF_WG = OFF_WA + (size_t)192 * 192 * 2;
  const size_t OFF_WH = OFF_WG + (size_t)192 * 192 * 2;    // 4x whh bf16 (512KB)
  const size_t OFF_A  = OFF_WH + (size_t)4 * 512 * 128 * 2;
  const size_t SZ_A   = (size_t)kM * 192 * 2;              // 24 MB
  const size_t OFF_B  = OFF_A + SZ_A;
  const size_t OFF_O0 = OFF_B + SZ_A;                      // out0 bf16 (32MB); em fp32 later
  const size_t OFF_XG = OFF_O0 + (size_t)kM * 256 * 2;     // xg bf16 dual (128MB)
  float* tbl  = (float*)ws;
  bf16*  W0b  = (bf16*)(ws + OFF_W0);
  bf16*  W1b  = (bf16*)(ws + OFF_W1);
  bf16*  WAb  = (bf16*)(ws + OFF_WA);
  bf16*  WGb  = (bf16*)(ws + OFF_WG);
  bf16*  WHb  = (bf16*)(ws + OFF_WH);
  bf16*  bufA = (bf16*)(ws + OFF_A);
  bf16*  bufB = (bf16*)(ws + OFF_B);
  bf16*  out0 = (bf16*)(ws + OFF_O0);
  bf16*  out1 = (bf16*)(ws + OFF_A);                       // bufA/bufB dead by rec1
  bf16*  xg   = (bf16*)(ws + OFF_XG);
  float* em   = (float*)(ws + OFF_O0);                     // out0 dead after proj1
  float* resv = (float*)(ws + OFF_O0 + (size_t)kM * 17 * 4);

  // weight conversion prepass (wih gets gate-last row permutation)
  k_w2bp<<<384, 256, 0, stream>>>(wih0f, W0b, 192);
  k_w2bp<<<384, 256, 0, stream>>>(wih0b, W0b + 512 * 192, 192);
  k_w2bp<<<512, 256, 0, stream>>>(wih1f, W1b, 256);
  k_w2bp<<<512, 256, 0, stream>>>(wih1b, W1b + 512 * 256, 256);
  k_w2b<<<144, 256, 0, stream>>>(hw_w, WAb, 192 * 192);
  k_w2b<<<144, 256, 0, stream>>>(hwg_w, WGb, 192 * 192);
  k_w2b<<<256, 256, 0, stream>>>(whh0f, WHb + 0 * 65536, 512 * 128);
  k_w2b<<<256, 256, 0, stream>>>(whh0b, WHb + 1 * 65536, 512 * 128);
  k_w2b<<<256, 256, 0, stream>>>(whh1f, WHb + 2 * 65536, 512 * 128);
  k_w2b<<<256, 256, 0, stream>>>(whh1b, WHb + 3 * 65536, 512 * 128);

  k_table<<<15 * 97, 64, 0, stream>>>(emb, cw3, cw5, cw7, tbl);
  k_conv<<<kB * (kS / 64), 192, 0, stream>>>(x, tbl, cb3, cb5, cb7, bufA);
  k_hw<<<dim3(kM / 128, 3), 256, 0, stream>>>(bufA, WAb, hw_b, WGb, hwg_b, bufB);

  k_pgemm<<<dim3(kM / 128, 8), 256, 0, stream>>>(bufB, 192, W0b, b0f, b0b, xg);
  k_rec3<<<64, 512, 0, stream>>>(xg, WHb + 0 * 65536, WHb + 1 * 65536, out0);
  k_pgemm<<<dim3(kM / 128, 8), 256, 0, stream>>>(out0, 256, W1b, b1f, b1b, xg);
  k_rec3<<<64, 512, 0, stream>>>(xg, WHb + 2 * 65536, WHb + 3 * 65536, out1);

  k_cls<<<kM / 64, 256, 0, stream>>>(out1, cls_w, cls_b, x, em);
  k_crf<<<kB, 64, 0, stream>>>(em, tags, mask, trans, start_t, end_t, resv);
  k_loss<<<1, 128, 0, stream>>>(resv, (float*)d_out);
}

// Round 9
// 1089.737 us; speedup vs baseline: 1.1717x; 1.0290x over previous
//
#include <hip/hip_runtime.h>
#include <hip/hip_bf16.h>
#include <cstdint>
#include <cstddef>

namespace {

constexpr int kB = 128;
constexpr int kS = 512;
constexpr int kM = kB * kS;   // 65536 rows

typedef __hip_bfloat16 bf16;
typedef __attribute__((ext_vector_type(8))) short short8;
typedef __attribute__((ext_vector_type(4))) float f32x4;
typedef __attribute__((ext_vector_type(4))) unsigned int u32x4;

__device__ __forceinline__ float sig_(float x) {
  return __builtin_amdgcn_rcpf(1.f + __expf(-x));
}
__device__ __forceinline__ float tanh_(float x) {
  return 1.f - 2.f * __builtin_amdgcn_rcpf(__expf(2.f * x) + 1.f);
}
__device__ __forceinline__ float b2f(bf16 h) { return __bfloat162float(h); }
__device__ __forceinline__ bf16 f2b(float f) { return __float2bfloat16(f); }

// unpack 8 bf16 (one uint4) -> 8 floats
__device__ __forceinline__ void unpack8(uint4 v, float* o) {
  o[0] = __uint_as_float(v.x << 16); o[1] = __uint_as_float(v.x & 0xffff0000u);
  o[2] = __uint_as_float(v.y << 16); o[3] = __uint_as_float(v.y & 0xffff0000u);
  o[4] = __uint_as_float(v.z << 16); o[5] = __uint_as_float(v.z & 0xffff0000u);
  o[6] = __uint_as_float(v.w << 16); o[7] = __uint_as_float(v.w & 0xffff0000u);
}

__device__ __forceinline__ void gl_lds16(const void* g, void* l) {
  __builtin_amdgcn_global_load_lds((const __attribute__((address_space(1))) void*)g,
                                   (__attribute__((address_space(3))) void*)l, 16, 0, 0);
}

// ---------------------------------------------------------------------------
// K0: fused weight prep. Regions by blockIdx:
//  [0,384)    wih0f -> W0b          (K=192, gate-last row perm)
//  [384,768)  wih0b -> W0b+98304
//  [768,1280) wih1f -> W1b          (K=256, perm)
//  [1280,1792) wih1b -> W1b+131072
//  [1792,1936) hw_w -> WAb   [1936,2080) hwg_w -> WGb   (linear)
//  [2080,2336)+256*i whh_i -> WHb+i*65536                (linear)
// ---------------------------------------------------------------------------
__global__ void k_wprep(const float* __restrict__ wih0f, const float* __restrict__ wih0b,
                        const float* __restrict__ wih1f, const float* __restrict__ wih1b,
                        const float* __restrict__ hw_w, const float* __restrict__ hwg_w,
                        const float* __restrict__ whh0f, const float* __restrict__ whh0b,
                        const float* __restrict__ whh1f, const float* __restrict__ whh1b,
                        bf16* __restrict__ W0b, bf16* __restrict__ W1b,
                        bf16* __restrict__ WAb, bf16* __restrict__ WGb,
                        bf16* __restrict__ WHb) {
  int b = blockIdx.x, t = threadIdx.x;
  if (b < 768) {
    const float* s = (b < 384) ? wih0f : wih0b;
    bf16* d = W0b + (b < 384 ? 0 : 98304);
    int i = (b & 383) * 256 + t;
    int n = i / 192, k = i - n * 192;
    d[i] = f2b(s[((n & 3) * 128 + (n >> 2)) * 192 + k]);
  } else if (b < 1792) {
    int bb = b - 768;
    const float* s = (bb < 512) ? wih1f : wih1b;
    bf16* d = W1b + (bb < 512 ? 0 : 131072);
    int i = (bb & 511) * 256 + t;
    int n = i >> 8, k = i & 255;
    d[i] = f2b(s[((n & 3) * 128 + (n >> 2)) * 256 + k]);
  } else if (b < 2080) {
    int bb = b - 1792;
    const float* s = (bb < 144) ? hw_w : hwg_w;
    bf16* d = (bb < 144) ? WAb : WGb;
    int i = (bb % 144) * 256 + t;
    d[i] = f2b(s[i]);
  } else {
    int bb = b - 2080;
    int which = bb >> 8;
    const float* s = (which == 0) ? whh0f : (which == 1) ? whh0b : (which == 2) ? whh1f : whh1b;
    int i = (bb & 255) * 256 + t;
    WHb[which * 65536 + i] = f2b(s[i]);
  }
}

// ---------------------------------------------------------------------------
// K1: per-tap char projection table (fp32, 372KB)
// ---------------------------------------------------------------------------
__global__ void k_table(const float* __restrict__ emb,
                        const float* __restrict__ cw3,
                        const float* __restrict__ cw5,
                        const float* __restrict__ cw7,
                        float* __restrict__ tbl) {
  int e = blockIdx.x;           // 0..15*97-1
  int tap = e / 97, ch = e % 97;
  int f = threadIdx.x;          // 0..63
  const float* w; int kk, dk;
  if (tap < 3)      { w = cw3; kk = 3; dk = tap; }
  else if (tap < 8) { w = cw5; kk = 5; dk = tap - 3; }
  else              { w = cw7; kk = 7; dk = tap - 8; }
  const float* er = emb + ch * 128;
  float s = 0.f;
  for (int c = 0; c < 128; ++c) s = fmaf(er[c], w[(f * 128 + c) * kk + dk], s);
  tbl[(size_t)e * 64 + f] = s;
}

// ---------------------------------------------------------------------------
// K2: conv via table gathers + bias + relu -> bf16 (B*S, 192)
// ---------------------------------------------------------------------------
__global__ void k_conv(const int* __restrict__ x, const float* __restrict__ tbl,
                       const float* __restrict__ cb3, const float* __restrict__ cb5,
                       const float* __restrict__ cb7, bf16* __restrict__ outA) {
  __shared__ int chs[70];
  int b = blockIdx.x >> 3;
  int s0 = (blockIdx.x & 7) << 6;
  int tid = threadIdx.x;
  if (tid < 70) {
    int g = s0 - 3 + tid;
    chs[tid] = (g >= 0 && g < kS) ? x[b * kS + g] : 0;   // char 0 => zero row
  }
  __syncthreads();
  int wv = tid >> 6;
  int f = tid & 63;
  int ntap, tap0, half; const float* cb;
  if (wv == 0)      { ntap = 3; tap0 = 0; half = 1; cb = cb3; }
  else if (wv == 1) { ntap = 5; tap0 = 3; half = 2; cb = cb5; }
  else              { ntap = 7; tap0 = 8; half = 3; cb = cb7; }
  float bias = cb[f];
  for (int p = 0; p < 64; ++p) {
    float acc = bias;
    for (int dk = 0; dk < ntap; ++dk) {
      int c = chs[p + 3 - half + dk];
      acc += tbl[(size_t)((tap0 + dk) * 97 + c) * 64 + f];
    }
    outA[(size_t)(b * kS + s0 + p) * 192 + wv * 64 + f] = f2b(fmaxf(acc, 0.f));
  }
}

// ---------------------------------------------------------------------------
// K3: highway via MFMA, fused dual GEMM (Wa and Wg in one pass).
// ---------------------------------------------------------------------------
__global__ __launch_bounds__(256) void k_hw(
    const bf16* __restrict__ A,
    const bf16* __restrict__ Wa, const float* __restrict__ Ba,
    const bf16* __restrict__ Wg, const float* __restrict__ Bg,
    bf16* __restrict__ outB) {
  __shared__ __align__(16) short As[128 * 64];
  __shared__ __align__(16) short Was[64 * 64];
  __shared__ __align__(16) short Wgs[64 * 64];
  constexpr int K = 192;
  int tid = threadIdx.x;
  int w = tid >> 6, l = tid & 63;
  int m0 = blockIdx.x * 128, n0 = blockIdx.y * 64;
  int wr = w >> 1, wc = w & 1;
  int lr = l >> 3, lc = l & 7;
  f32x4 accA[4][2], accG[4][2];
#pragma unroll
  for (int i = 0; i < 4; ++i)
#pragma unroll
    for (int j = 0; j < 2; ++j) { accA[i][j] = (f32x4)0.f; accG[i][j] = (f32x4)0.f; }

  for (int kc = 0; kc < K; kc += 64) {
    __syncthreads();
#pragma unroll
    for (int i = 0; i < 4; ++i) {
      int r = w * 32 + i * 8;
      gl_lds16(A + (size_t)(m0 + r + lr) * K + kc + lc * 8, &As[r * 64]);
    }
#pragma unroll
    for (int i = 0; i < 2; ++i) {
      int r = w * 16 + i * 8;
      gl_lds16(Wa + (size_t)(n0 + r + lr) * K + kc + lc * 8, &Was[r * 64]);
      gl_lds16(Wg + (size_t)(n0 + r + lr) * K + kc + lc * 8, &Wgs[r * 64]);
    }
    __syncthreads();
#pragma unroll
    for (int kf = 0; kf < 2; ++kf) {
      short8 af[4], ba[2], bg[2];
#pragma unroll
      for (int mt = 0; mt < 4; ++mt)
        af[mt] = *(const short8*)&As[(wr * 64 + mt * 16 + (l & 15)) * 64 + kf * 32 + (l >> 4) * 8];
#pragma unroll
      for (int nt = 0; nt < 2; ++nt) {
        int rn = (wc * 32 + nt * 16 + (l & 15)) * 64 + kf * 32 + (l >> 4) * 8;
        ba[nt] = *(const short8*)&Was[rn];
        bg[nt] = *(const short8*)&Wgs[rn];
      }
#pragma unroll
      for (int mt = 0; mt < 4; ++mt)
#pragma unroll
        for (int nt = 0; nt < 2; ++nt) {
          accA[mt][nt] = __builtin_amdgcn_mfma_f32_16x16x32_bf16(af[mt], ba[nt], accA[mt][nt], 0, 0, 0);
          accG[mt][nt] = __builtin_amdgcn_mfma_f32_16x16x32_bf16(af[mt], bg[nt], accG[mt][nt], 0, 0, 0);
        }
    }
  }
#pragma unroll
  for (int nt = 0; nt < 2; ++nt) {
    int n = n0 + wc * 32 + nt * 16 + (l & 15);
    float bav = Ba[n], bgv = Bg[n];
#pragma unroll
    for (int mt = 0; mt < 4; ++mt) {
      int mb = m0 + wr * 64 + mt * 16 + (l >> 4) * 4;
#pragma unroll
      for (int r = 0; r < 4; ++r) {
        float av = accA[mt][nt][r] + bav;
        float gv = accG[mt][nt][r] + bgv;
        float tt = sig_(gv);
        float orig = b2f(A[(size_t)(mb + r) * K + n]);
        outB[(size_t)(mb + r) * K + n] = f2b(tt * fmaxf(av, 0.f) + (1.f - tt) * orig);
      }
    }
  }
}

// ---------------------------------------------------------------------------
// K4: LSTM input projection via MFMA. BM=128, BN=128, BK=64, 4 waves 2x2.
// W is PRE-PERMUTED to gate-last row order (row u*4+g), so the natural
// coalesced write produces xg[(t*128+seq)*1024 + dir*512 + u*4 + g].
// ---------------------------------------------------------------------------
__global__ __launch_bounds__(256) void k_pgemm(
    const bf16* __restrict__ A, int K,
    const bf16* __restrict__ W,
    const float* __restrict__ bfw, const float* __restrict__ bbw,
    bf16* __restrict__ xg) {
  __shared__ __align__(16) short As[128 * 64];
  __shared__ __align__(16) short Bs[128 * 64];
  int tid = threadIdx.x;
  int w = tid >> 6, l = tid & 63;
  int m0 = blockIdx.x * 128, n0 = blockIdx.y * 128;
  int wr = w >> 1, wc = w & 1;
  int lr = l >> 3, lc = l & 7;
  f32x4 acc[4][4];
#pragma unroll
  for (int i = 0; i < 4; ++i)
#pragma unroll
    for (int j = 0; j < 4; ++j) acc[i][j] = (f32x4)0.f;

  for (int kc = 0; kc < K; kc += 64) {
    __syncthreads();
#pragma unroll
    for (int i = 0; i < 4; ++i) {
      int r = w * 32 + i * 8;
      gl_lds16(A + (size_t)(m0 + r + lr) * K + kc + lc * 8, &As[r * 64]);
      gl_lds16(W + (size_t)(n0 + r + lr) * K + kc + lc * 8, &Bs[r * 64]);
    }
    __syncthreads();
#pragma unroll
    for (int kf = 0; kf < 2; ++kf) {
      short8 af[4], bfr[4];
#pragma unroll
      for (int mt = 0; mt < 4; ++mt)
        af[mt] = *(const short8*)&As[(wr * 64 + mt * 16 + (l & 15)) * 64 + kf * 32 + (l >> 4) * 8];
#pragma unroll
      for (int nt = 0; nt < 4; ++nt)
        bfr[nt] = *(const short8*)&Bs[(wc * 64 + nt * 16 + (l & 15)) * 64 + kf * 32 + (l >> 4) * 8];
#pragma unroll
      for (int mt = 0; mt < 4; ++mt)
#pragma unroll
        for (int nt = 0; nt < 4; ++nt)
          acc[mt][nt] = __builtin_amdgcn_mfma_f32_16x16x32_bf16(af[mt], bfr[nt], acc[mt][nt], 0, 0, 0);
    }
  }
#pragma unroll
  for (int nt = 0; nt < 4; ++nt) {
    int n = n0 + wc * 64 + nt * 16 + (l & 15);
    int nn = n & 511;
    float bv = ((n < 512) ? bfw : bbw)[(nn & 3) * 128 + (nn >> 2)];
#pragma unroll
    for (int mt = 0; mt < 4; ++mt) {
      int mb = m0 + wr * 64 + mt * 16 + (l >> 4) * 4;
#pragma unroll
      for (int r = 0; r < 4; ++r) {
        int row = mb + r;                                  // seq-major: seq*512+t
        int rp = ((row & 511) << 7) | (row >> 9);          // time-major: t*128+seq
        xg[((size_t)rp << 10) + n] = f2b(acc[mt][nt][r] + bv);
      }
    }
  }
}

// ---------------------------------------------------------------------------
// K5: LSTM recurrence as per-step batched MFMA GEMM.  v4.
// Same mapping as v3.1 (4 seqs/block, 8 waves, 1 cell/lane, HT stride 160).
// NEW: (a) amdgpu_waves_per_eu(2,2) pins occupancy -> 256-VGPR budget, stops
// the allocator's occupancy-chasing; (b) weight fragments laundered through
// opaque asm so they CANNOT be rematerialized from global each step;
// (c) split-K: 2 independent depth-2 MFMA chains per gate + vector add.
// ---------------------------------------------------------------------------
__global__ __attribute__((amdgpu_waves_per_eu(2, 2))) __launch_bounds__(512)
void k_rec4(
    const bf16* __restrict__ xg,
    const bf16* __restrict__ whhF, const bf16* __restrict__ whhB,
    bf16* __restrict__ out) {
  constexpr int HS = 160;   // HT row stride in shorts
  int blk = blockIdx.x;
  int dir = blk >> 5;
  int seq0 = (blk & 31) * 4;
  const short* whhs = (const short*)(dir ? whhB : whhF);
  const bool rev = (dir == 1);
  int tid = threadIdx.x;
  int w = tid >> 6, l = tid & 63;
  int ln = l & 15, lk = l >> 4;
  int s = l & 3;
  int r = (l >> 2) & 3;
  int u = w * 16 + lk * 4 + r;    // my u (0..127)
  int seq = seq0 + s;

  // whh A-fragments, forced register-resident via opaque asm identity.
  u32x4 wfu[4][4];
#pragma unroll
  for (int g = 0; g < 4; ++g)
#pragma unroll
    for (int kk = 0; kk < 4; ++kk) {
      wfu[g][kk] = *(const u32x4*)&whhs[(size_t)(g * 128 + w * 16 + ln) * 128 + kk * 32 + lk * 8];
      asm volatile("" : "+v"(wfu[g][kk]));
    }

  __shared__ __align__(16) short HT[2][4][HS];
  for (int i = tid; i < 2 * 4 * HS; i += 512) ((short*)HT)[i] = 0;

  float c = 0.f;

  const bf16* xbase = xg + (size_t)seq * 1024 + dir * 512 + u * 4;
  bf16* obase = out + (size_t)seq * 131072 + (size_t)dir * 128 + u;

  uint2 xA, xB;
  {
    int p0 = rev ? 511 : 0, p1 = rev ? 510 : 1;
    xA = *(const uint2*)(xbase + ((size_t)p0 << 17));
    xB = *(const uint2*)(xbase + ((size_t)p1 << 17));
  }
  __syncthreads();

  auto do_step = [&](int tphys, int tpref, const short* RB, short* WB, uint2& x) {
    // B-fragments: col c of B = h[seq c&3]  (broadcast read of rows 0..3)
    short8 b0 = *(const short8*)&RB[s * HS + 0  + lk * 8];
    short8 b1 = *(const short8*)&RB[s * HS + 32 + lk * 8];
    short8 b2 = *(const short8*)&RB[s * HS + 64 + lk * 8];
    short8 b3 = *(const short8*)&RB[s * HS + 96 + lk * 8];
    uint2 xc = x;
    x = *(const uint2*)(xbase + ((size_t)tpref << 17));   // prefetch t+2
    // Z = whh @ h : split-K, 8 independent chains of depth 2
    f32x4 alo[4], ahi[4];
#pragma unroll
    for (int g = 0; g < 4; ++g) {
      alo[g] = __builtin_amdgcn_mfma_f32_16x16x32_bf16(
          __builtin_bit_cast(short8, wfu[g][0]), b0, (f32x4)0.f, 0, 0, 0);
      ahi[g] = __builtin_amdgcn_mfma_f32_16x16x32_bf16(
          __builtin_bit_cast(short8, wfu[g][2]), b2, (f32x4)0.f, 0, 0, 0);
    }
#pragma unroll
    for (int g = 0; g < 4; ++g) {
      alo[g] = __builtin_amdgcn_mfma_f32_16x16x32_bf16(
          __builtin_bit_cast(short8, wfu[g][1]), b1, alo[g], 0, 0, 0);
      ahi[g] = __builtin_amdgcn_mfma_f32_16x16x32_bf16(
          __builtin_bit_cast(short8, wfu[g][3]), b3, ahi[g], 0, 0, 0);
    }
    // in-lane select: z[g] = (alo+ahi)[g][r]
    float z[4];
#pragma unroll
    for (int g = 0; g < 4; ++g) {
      f32x4 a = alo[g] + ahi[g];
      float v01 = (r & 1) ? a[1] : a[0];
      float v23 = (r & 1) ? a[3] : a[2];
      z[g] = (r & 2) ? v23 : v01;
    }
    float xi = __uint_as_float(xc.x << 16);
    float xf = __uint_as_float(xc.x & 0xffff0000u);
    float xm = __uint_as_float(xc.y << 16);
    float xo = __uint_as_float(xc.y & 0xffff0000u);
    float ig = sig_(z[0] + xi), fg = sig_(z[1] + xf);
    float gv = tanh_(z[2] + xm), og = sig_(z[3] + xo);
    c = fmaf(fg, c, ig * gv);
    float h = og * tanh_(c);
    bf16 hb = f2b(h);
    *(short*)&WB[s * HS + u] = *(short*)&hb;          // h -> HT[nxt] row s
    *(bf16*)(obase + (size_t)tphys * 256) = hb;       // h -> global
  };

  for (int t = 0; t < kS; t += 2) {
    int ta = rev ? 511 - t : t;
    int tb = rev ? 510 - t : t + 1;
    int pa = (t + 2 < kS) ? t + 2 : kS - 1;
    int pb = (t + 3 < kS) ? t + 3 : kS - 1;
    int tpa = rev ? 511 - pa : pa;
    int tpb = rev ? 511 - pb : pb;
    do_step(ta, tpa, &HT[0][0][0], &HT[1][0][0], xA);
    __syncthreads();
    do_step(tb, tpb, &HT[1][0][0], &HT[0][0][0], xB);
    __syncthreads();
  }
}

// ---------------------------------------------------------------------------
// K6: classifier + char mask. out1 bf16 -> em fp32 (or NEG)
// ---------------------------------------------------------------------------
__global__ __launch_bounds__(256) void k_cls(
    const bf16* __restrict__ out1, const float* __restrict__ cls_w,
    const float* __restrict__ cls_b, const int* __restrict__ x,
    float* __restrict__ em) {
  __shared__ float W[17 * 256];
  __shared__ float part[64 * 4 * 17];
  int tid = threadIdx.x;
  for (int i = tid; i < 17 * 256; i += 256) W[i] = cls_w[i];
  __syncthreads();
  int r = tid >> 2, q = tid & 3;
  size_t row = (size_t)blockIdx.x * 64 + r;
  float acc[17];
#pragma unroll
  for (int j = 0; j < 17; ++j) acc[j] = 0.f;
  const uint4* a4p = (const uint4*)(out1 + row * 256 + q * 64);
  for (int i = 0; i < 8; ++i) {
    float f8[8]; unpack8(a4p[i], f8);
#pragma unroll
    for (int j = 0; j < 17; ++j) {
      const float* wr = &W[j * 256 + q * 64 + i * 8];
#pragma unroll
      for (int e = 0; e < 8; ++e) acc[j] = fmaf(f8[e], wr[e], acc[j]);
    }
  }
#pragma unroll
  for (int j = 0; j < 17; ++j) part[(r * 4 + q) * 17 + j] = acc[j];
  __syncthreads();
  for (int idx = tid; idx < 64 * 17; idx += 256) {
    int rr = idx / 17, j = idx % 17;
    size_t row2 = (size_t)blockIdx.x * 64 + rr;
    float v = part[(rr * 4 + 0) * 17 + j] + part[(rr * 4 + 1) * 17 + j] +
              part[(rr * 4 + 2) * 17 + j] + part[(rr * 4 + 3) * 17 + j] + cls_b[j];
    em[row2 * 17 + j] = (x[row2] != 0) ? v : -1e9f;
  }
}

// ---------------------------------------------------------------------------
// K7: CRF loss per sequence (1 wave / block). res[b] = logZ - score
// ---------------------------------------------------------------------------
__global__ __launch_bounds__(64) void k_crf(
    const float* __restrict__ em, const int* __restrict__ tags,
    const float* __restrict__ mask, const float* __restrict__ trans,
    const float* __restrict__ start_t, const float* __restrict__ end_t,
    float* __restrict__ res) {
  int b = blockIdx.x;
  int lane = threadIdx.x;
  const float* emB = em + (size_t)b * kS * 17;
  const int* tg = tags + b * kS;
  const float* mk = mask + b * kS;

  float tcol[17];
  if (lane < 17) {
#pragma unroll
    for (int i = 0; i < 17; ++i) tcol[i] = trans[i * 17 + lane];
  }
  float sc = 0.f, msum = 0.f;
  for (int t = lane; t < kS; t += 64) msum += mk[t];
  for (int t = 1 + lane; t < kS; t += 64)
    sc += (trans[tg[t - 1] * 17 + tg[t]] + emB[(size_t)t * 17 + tg[t]]) * mk[t];
#pragma unroll
  for (int o = 32; o; o >>= 1) { sc += __shfl_xor(sc, o); msum += __shfl_xor(msum, o); }

  __shared__ float al[17];
  if (lane < 17) al[lane] = start_t[lane] + emB[lane];
  __syncthreads();
  for (int t = 1; t < kS; ++t) {
    float nxt = 0.f;
    if (lane < 17) {
      float v[17]; float mx = -3.4e38f;
#pragma unroll
      for (int i = 0; i < 17; ++i) { v[i] = al[i] + tcol[i]; mx = fmaxf(mx, v[i]); }
      float s = 0.f;
#pragma unroll
      for (int i = 0; i < 17; ++i) s += __expf(v[i] - mx);
      float m = mk[t];
      nxt = (mx + __logf(s) + emB[(size_t)t * 17 + lane]) * m + al[lane] * (1.f - m);
    }
    __syncthreads();
    if (lane < 17) al[lane] = nxt;
    __syncthreads();
  }
  float val = (lane < 17) ? al[lane] + end_t[lane] : -3.4e38f;
  float mx = val;
#pragma unroll
  for (int o = 32; o; o >>= 1) mx = fmaxf(mx, __shfl_xor(mx, o));
  float s = (lane < 17) ? __expf(val - mx) : 0.f;
#pragma unroll
  for (int o = 32; o; o >>= 1) s += __shfl_xor(s, o);
  float logZ = mx + __logf(s);
  if (lane == 0) {
    float score = sc + start_t[tg[0]] + emB[tg[0]];
    int last_real = (int)(msum + 0.5f) - 1;
    if (last_real >= 0) score += end_t[tg[last_real]];
    res[b] = logZ - score;
  }
}

// K8: deterministic mean over 128 sequences -> d_out[0]
__global__ void k_loss(const float* __restrict__ res, float* __restrict__ out) {
  __shared__ float s[128];
  int tid = threadIdx.x;
  s[tid] = res[tid];
  __syncthreads();
  for (int off = 64; off; off >>= 1) {
    if (tid < off) s[tid] += s[tid + off];
    __syncthreads();
  }
  if (tid == 0) out[0] = s[0] / 128.f;
}

}  // namespace

extern "C" void kernel_launch(void* const* d_in, const int* in_sizes, int n_in,
                              void* d_out, int out_size, void* d_ws, size_t ws_size,
                              hipStream_t stream) {
  (void)in_sizes; (void)n_in; (void)out_size; (void)ws_size;
  const int*   x       = (const int*)  d_in[0];
  const int*   tags    = (const int*)  d_in[1];
  const float* mask    = (const float*)d_in[2];
  const float* emb     = (const float*)d_in[3];
  const float* cw3     = (const float*)d_in[4];
  const float* cb3     = (const float*)d_in[5];
  const float* cw5     = (const float*)d_in[6];
  const float* cb5     = (const float*)d_in[7];
  const float* cw7     = (const float*)d_in[8];
  const float* cb7     = (const float*)d_in[9];
  const float* hw_w    = (const float*)d_in[10];
  const float* hw_b    = (const float*)d_in[11];
  const float* hwg_w   = (const float*)d_in[12];
  const float* hwg_b   = (const float*)d_in[13];
  const float* wih0f   = (const float*)d_in[14];
  const float* whh0f   = (const float*)d_in[15];
  const float* b0f     = (const float*)d_in[16];
  const float* wih0b   = (const float*)d_in[17];
  const float* whh0b   = (const float*)d_in[18];
  const float* b0b     = (const float*)d_in[19];
  const float* wih1f   = (const float*)d_in[20];
  const float* whh1f   = (const float*)d_in[21];
  const float* b1f     = (const float*)d_in[22];
  const float* wih1b   = (const float*)d_in[23];
  const float* whh1b   = (const float*)d_in[24];
  const float* b1b     = (const float*)d_in[25];
  const float* cls_w   = (const float*)d_in[26];
  const float* cls_b   = (const float*)d_in[27];
  const float* trans   = (const float*)d_in[28];
  const float* start_t = (const float*)d_in[29];
  const float* end_t   = (const float*)d_in[30];

  // Workspace layout. tbl fp32 | bf16 weights | bf16 activations. ~210 MB.
  char* ws = (char*)d_ws;
  const size_t OFF_W0 = 393216;                            // tbl is [0, 372KB)
  const size_t OFF_W1 = OFF_W0 + (size_t)1024 * 192 * 2;
  const size_t OFF_WA = OFF_W1 + (size_t)1024 * 256 * 2;
  const size_t OFF_WG = OFF_WA + (size_t)192 * 192 * 2;
  const size_t OFF_WH = OFF_WG + (size_t)192 * 192 * 2;    // 4x whh bf16 (512KB)
  const size_t OFF_A  = OFF_WH + (size_t)4 * 512 * 128 * 2;
  const size_t SZ_A   = (size_t)kM * 192 * 2;              // 24 MB
  const size_t OFF_B  = OFF_A + SZ_A;
  const size_t OFF_O0 = OFF_B + SZ_A;                      // out0 bf16 (32MB); em fp32 later
  const size_t OFF_XG = OFF_O0 + (size_t)kM * 256 * 2;     // xg bf16 dual (128MB)
  float* tbl  = (float*)ws;
  bf16*  W0b  = (bf16*)(ws + OFF_W0);
  bf16*  W1b  = (bf16*)(ws + OFF_W1);
  bf16*  WAb  = (bf16*)(ws + OFF_WA);
  bf16*  WGb  = (bf16*)(ws + OFF_WG);
  bf16*  WHb  = (bf16*)(ws + OFF_WH);
  bf16*  bufA = (bf16*)(ws + OFF_A);
  bf16*  bufB = (bf16*)(ws + OFF_B);
  bf16*  out0 = (bf16*)(ws + OFF_O0);
  bf16*  out1 = (bf16*)(ws + OFF_A);                       // bufA/bufB dead by rec1
  bf16*  xg   = (bf16*)(ws + OFF_XG);
  float* em   = (float*)(ws + OFF_O0);                     // out0 dead after proj1
  float* resv = (float*)(ws + OFF_O0 + (size_t)kM * 17 * 4);

  // fused weight conversion prepass (wih gets gate-last row permutation)
  k_wprep<<<3104, 256, 0, stream>>>(wih0f, wih0b, wih1f, wih1b, hw_w, hwg_w,
                                    whh0f, whh0b, whh1f, whh1b,
                                    W0b, W1b, WAb, WGb, WHb);

  k_table<<<15 * 97, 64, 0, stream>>>(emb, cw3, cw5, cw7, tbl);
  k_conv<<<kB * (kS / 64), 192, 0, stream>>>(x, tbl, cb3, cb5, cb7, bufA);
  k_hw<<<dim3(kM / 128, 3), 256, 0, stream>>>(bufA, WAb, hw_b, WGb, hwg_b, bufB);

  k_pgemm<<<dim3(kM / 128, 8), 256, 0, stream>>>(bufB, 192, W0b, b0f, b0b, xg);
  k_rec4<<<64, 512, 0, stream>>>(xg, WHb + 0 * 65536, WHb + 1 * 65536, out0);
  k_pgemm<<<dim3(kM / 128, 8), 256, 0, stream>>>(out0, 256, W1b, b1f, b1b, xg);
  k_rec4<<<64, 512, 0, stream>>>(xg, WHb + 2 * 65536, WHb + 3 * 65536, out1);

  k_cls<<<kM / 64, 256, 0, stream>>>(out1, cls_w, cls_b, x, em);
  k_crf<<<kB, 64, 0, stream>>>(em, tags, mask, trans, start_t, end_t, resv);
  k_loss<<<1, 128, 0, stream>>>(resv, (float*)d_out);
}

// Round 11
// 1081.307 us; speedup vs baseline: 1.1808x; 1.0078x over previous
//
#include <hip/hip_runtime.h>
#include <hip/hip_bf16.h>
#include <cstdint>
#include <cstddef>

namespace {

constexpr int kB = 128;
constexpr int kS = 512;
constexpr int kM = kB * kS;   // 65536 rows

typedef __hip_bfloat16 bf16;
typedef __attribute__((ext_vector_type(8))) short short8;
typedef __attribute__((ext_vector_type(4))) float f32x4;
typedef __attribute__((ext_vector_type(4))) unsigned int u32x4;

__device__ __forceinline__ float sig_(float x) {
  return __builtin_amdgcn_rcpf(1.f + __expf(-x));
}
__device__ __forceinline__ float tanh_(float x) {
  return 1.f - 2.f * __builtin_amdgcn_rcpf(__expf(2.f * x) + 1.f);
}
__device__ __forceinline__ float b2f(bf16 h) { return __bfloat162float(h); }
__device__ __forceinline__ bf16 f2b(float f) { return __float2bfloat16(f); }

// unpack 8 bf16 (one uint4) -> 8 floats
__device__ __forceinline__ void unpack8(uint4 v, float* o) {
  o[0] = __uint_as_float(v.x << 16); o[1] = __uint_as_float(v.x & 0xffff0000u);
  o[2] = __uint_as_float(v.y << 16); o[3] = __uint_as_float(v.y & 0xffff0000u);
  o[4] = __uint_as_float(v.z << 16); o[5] = __uint_as_float(v.z & 0xffff0000u);
  o[6] = __uint_as_float(v.w << 16); o[7] = __uint_as_float(v.w & 0xffff0000u);
}

__device__ __forceinline__ void gl_lds16(const void* g, void* l) {
  __builtin_amdgcn_global_load_lds((const __attribute__((address_space(1))) void*)g,
                                   (__attribute__((address_space(3))) void*)l, 16, 0, 0);
}

// Barrier that waits ONLY on LDS ops (lgkmcnt), NOT on outstanding global
// loads/stores (vmcnt). __syncthreads() drains vmcnt(0), which serializes the
// per-step xg prefetch's full HBM latency into every recurrence step.
// LDS producer->consumer ordering (h write -> h read) is preserved by
// lgkmcnt(0) before s_barrier. Global loads crossing the barrier are consumed
// only by the issuing thread (compiler inserts vmcnt waits at use); global
// stores are drained at end-of-kernel.
__device__ __forceinline__ void fast_barrier() {
  __builtin_amdgcn_sched_barrier(0);
  asm volatile("s_waitcnt lgkmcnt(0)" ::: "memory");
  __builtin_amdgcn_s_barrier();
  __builtin_amdgcn_sched_barrier(0);
}

// ---------------------------------------------------------------------------
// K0: fused weight prep. Regions by blockIdx:
//  [0,384)    wih0f -> W0b          (K=192, gate-last row perm)
//  [384,768)  wih0b -> W0b+98304
//  [768,1280) wih1f -> W1b          (K=256, perm)
//  [1280,1792) wih1b -> W1b+131072
//  [1792,1936) hw_w -> WAb   [1936,2080) hwg_w -> WGb   (linear)
//  [2080,2336)+256*i whh_i -> WHb+i*65536                (linear)
// ---------------------------------------------------------------------------
__global__ void k_wprep(const float* __restrict__ wih0f, const float* __restrict__ wih0b,
                        const float* __restrict__ wih1f, const float* __restrict__ wih1b,
                        const float* __restrict__ hw_w, const float* __restrict__ hwg_w,
                        const float* __restrict__ whh0f, const float* __restrict__ whh0b,
                        const float* __restrict__ whh1f, const float* __restrict__ whh1b,
                        bf16* __restrict__ W0b, bf16* __restrict__ W1b,
                        bf16* __restrict__ WAb, bf16* __restrict__ WGb,
                        bf16* __restrict__ WHb) {
  int b = blockIdx.x, t = threadIdx.x;
  if (b < 768) {
    const float* s = (b < 384) ? wih0f : wih0b;
    bf16* d = W0b + (b < 384 ? 0 : 98304);
    int i = (b & 383) * 256 + t;
    int n = i / 192, k = i - n * 192;
    d[i] = f2b(s[((n & 3) * 128 + (n >> 2)) * 192 + k]);
  } else if (b < 1792) {
    int bb = b - 768;
    const float* s = (bb < 512) ? wih1f : wih1b;
    bf16* d = W1b + (bb < 512 ? 0 : 131072);
    int i = (bb & 511) * 256 + t;
    int n = i >> 8, k = i & 255;
    d[i] = f2b(s[((n & 3) * 128 + (n >> 2)) * 256 + k]);
  } else if (b < 2080) {
    int bb = b - 1792;
    const float* s = (bb < 144) ? hw_w : hwg_w;
    bf16* d = (bb < 144) ? WAb : WGb;
    int i = (bb % 144) * 256 + t;
    d[i] = f2b(s[i]);
  } else {
    int bb = b - 2080;
    int which = bb >> 8;
    const float* s = (which == 0) ? whh0f : (which == 1) ? whh0b : (which == 2) ? whh1f : whh1b;
    int i = (bb & 255) * 256 + t;
    WHb[which * 65536 + i] = f2b(s[i]);
  }
}

// ---------------------------------------------------------------------------
// K1: per-tap char projection table (fp32, 372KB)
// ---------------------------------------------------------------------------
__global__ void k_table(const float* __restrict__ emb,
                        const float* __restrict__ cw3,
                        const float* __restrict__ cw5,
                        const float* __restrict__ cw7,
                        float* __restrict__ tbl) {
  int e = blockIdx.x;           // 0..15*97-1
  int tap = e / 97, ch = e % 97;
  int f = threadIdx.x;          // 0..63
  const float* w; int kk, dk;
  if (tap < 3)      { w = cw3; kk = 3; dk = tap; }
  else if (tap < 8) { w = cw5; kk = 5; dk = tap - 3; }
  else              { w = cw7; kk = 7; dk = tap - 8; }
  const float* er = emb + ch * 128;
  float s = 0.f;
  for (int c = 0; c < 128; ++c) s = fmaf(er[c], w[(f * 128 + c) * kk + dk], s);
  tbl[(size_t)e * 64 + f] = s;
}

// ---------------------------------------------------------------------------
// K2: conv via table gathers + bias + relu -> bf16 (B*S, 192)
// ---------------------------------------------------------------------------
__global__ void k_conv(const int* __restrict__ x, const float* __restrict__ tbl,
                       const float* __restrict__ cb3, const float* __restrict__ cb5,
                       const float* __restrict__ cb7, bf16* __restrict__ outA) {
  __shared__ int chs[70];
  int b = blockIdx.x >> 3;
  int s0 = (blockIdx.x & 7) << 6;
  int tid = threadIdx.x;
  if (tid < 70) {
    int g = s0 - 3 + tid;
    chs[tid] = (g >= 0 && g < kS) ? x[b * kS + g] : 0;   // char 0 => zero row
  }
  __syncthreads();
  int wv = tid >> 6;
  int f = tid & 63;
  int ntap, tap0, half; const float* cb;
  if (wv == 0)      { ntap = 3; tap0 = 0; half = 1; cb = cb3; }
  else if (wv == 1) { ntap = 5; tap0 = 3; half = 2; cb = cb5; }
  else              { ntap = 7; tap0 = 8; half = 3; cb = cb7; }
  float bias = cb[f];
  for (int p = 0; p < 64; ++p) {
    float acc = bias;
    for (int dk = 0; dk < ntap; ++dk) {
      int c = chs[p + 3 - half + dk];
      acc += tbl[(size_t)((tap0 + dk) * 97 + c) * 64 + f];
    }
    outA[(size_t)(b * kS + s0 + p) * 192 + wv * 64 + f] = f2b(fmaxf(acc, 0.f));
  }
}

// ---------------------------------------------------------------------------
// K3: highway via MFMA, fused dual GEMM (Wa and Wg in one pass).
// ---------------------------------------------------------------------------
__global__ __launch_bounds__(256) void k_hw(
    const bf16* __restrict__ A,
    const bf16* __restrict__ Wa, const float* __restrict__ Ba,
    const bf16* __restrict__ Wg, const float* __restrict__ Bg,
    bf16* __restrict__ outB) {
  __shared__ __align__(16) short As[128 * 64];
  __shared__ __align__(16) short Was[64 * 64];
  __shared__ __align__(16) short Wgs[64 * 64];
  constexpr int K = 192;
  int tid = threadIdx.x;
  int w = tid >> 6, l = tid & 63;
  int m0 = blockIdx.x * 128, n0 = blockIdx.y * 64;
  int wr = w >> 1, wc = w & 1;
  int lr = l >> 3, lc = l & 7;
  f32x4 accA[4][2], accG[4][2];
#pragma unroll
  for (int i = 0; i < 4; ++i)
#pragma unroll
    for (int j = 0; j < 2; ++j) { accA[i][j] = (f32x4)0.f; accG[i][j] = (f32x4)0.f; }

  for (int kc = 0; kc < K; kc += 64) {
    __syncthreads();
#pragma unroll
    for (int i = 0; i < 4; ++i) {
      int r = w * 32 + i * 8;
      gl_lds16(A + (size_t)(m0 + r + lr) * K + kc + lc * 8, &As[r * 64]);
    }
#pragma unroll
    for (int i = 0; i < 2; ++i) {
      int r = w * 16 + i * 8;
      gl_lds16(Wa + (size_t)(n0 + r + lr) * K + kc + lc * 8, &Was[r * 64]);
      gl_lds16(Wg + (size_t)(n0 + r + lr) * K + kc + lc * 8, &Wgs[r * 64]);
    }
    __syncthreads();
#pragma unroll
    for (int kf = 0; kf < 2; ++kf) {
      short8 af[4], ba[2], bg[2];
#pragma unroll
      for (int mt = 0; mt < 4; ++mt)
        af[mt] = *(const short8*)&As[(wr * 64 + mt * 16 + (l & 15)) * 64 + kf * 32 + (l >> 4) * 8];
#pragma unroll
      for (int nt = 0; nt < 2; ++nt) {
        int rn = (wc * 32 + nt * 16 + (l & 15)) * 64 + kf * 32 + (l >> 4) * 8;
        ba[nt] = *(const short8*)&Was[rn];
        bg[nt] = *(const short8*)&Wgs[rn];
      }
#pragma unroll
      for (int mt = 0; mt < 4; ++mt)
#pragma unroll
        for (int nt = 0; nt < 2; ++nt) {
          accA[mt][nt] = __builtin_amdgcn_mfma_f32_16x16x32_bf16(af[mt], ba[nt], accA[mt][nt], 0, 0, 0);
          accG[mt][nt] = __builtin_amdgcn_mfma_f32_16x16x32_bf16(af[mt], bg[nt], accG[mt][nt], 0, 0, 0);
        }
    }
  }
#pragma unroll
  for (int nt = 0; nt < 2; ++nt) {
    int n = n0 + wc * 32 + nt * 16 + (l & 15);
    float bav = Ba[n], bgv = Bg[n];
#pragma unroll
    for (int mt = 0; mt < 4; ++mt) {
      int mb = m0 + wr * 64 + mt * 16 + (l >> 4) * 4;
#pragma unroll
      for (int r = 0; r < 4; ++r) {
        float av = accA[mt][nt][r] + bav;
        float gv = accG[mt][nt][r] + bgv;
        float tt = sig_(gv);
        float orig = b2f(A[(size_t)(mb + r) * K + n]);
        outB[(size_t)(mb + r) * K + n] = f2b(tt * fmaxf(av, 0.f) + (1.f - tt) * orig);
      }
    }
  }
}

// ---------------------------------------------------------------------------
// K4: LSTM input projection via MFMA. BM=128, BN=128, BK=64, 4 waves 2x2.
// W is PRE-PERMUTED to gate-last row order (row u*4+g), so the natural
// coalesced write produces xg[(t*128+seq)*1024 + dir*512 + u*4 + g].
// ---------------------------------------------------------------------------
__global__ __launch_bounds__(256) void k_pgemm(
    const bf16* __restrict__ A, int K,
    const bf16* __restrict__ W,
    const float* __restrict__ bfw, const float* __restrict__ bbw,
    bf16* __restrict__ xg) {
  __shared__ __align__(16) short As[128 * 64];
  __shared__ __align__(16) short Bs[128 * 64];
  int tid = threadIdx.x;
  int w = tid >> 6, l = tid & 63;
  int m0 = blockIdx.x * 128, n0 = blockIdx.y * 128;
  int wr = w >> 1, wc = w & 1;
  int lr = l >> 3, lc = l & 7;
  f32x4 acc[4][4];
#pragma unroll
  for (int i = 0; i < 4; ++i)
#pragma unroll
    for (int j = 0; j < 4; ++j) acc[i][j] = (f32x4)0.f;

  for (int kc = 0; kc < K; kc += 64) {
    __syncthreads();
#pragma unroll
    for (int i = 0; i < 4; ++i) {
      int r = w * 32 + i * 8;
      gl_lds16(A + (size_t)(m0 + r + lr) * K + kc + lc * 8, &As[r * 64]);
      gl_lds16(W + (size_t)(n0 + r + lr) * K + kc + lc * 8, &Bs[r * 64]);
    }
    __syncthreads();
#pragma unroll
    for (int kf = 0; kf < 2; ++kf) {
      short8 af[4], bfr[4];
#pragma unroll
      for (int mt = 0; mt < 4; ++mt)
        af[mt] = *(const short8*)&As[(wr * 64 + mt * 16 + (l & 15)) * 64 + kf * 32 + (l >> 4) * 8];
#pragma unroll
      for (int nt = 0; nt < 4; ++nt)
        bfr[nt] = *(const short8*)&Bs[(wc * 64 + nt * 16 + (l & 15)) * 64 + kf * 32 + (l >> 4) * 8];
#pragma unroll
      for (int mt = 0; mt < 4; ++mt)
#pragma unroll
        for (int nt = 0; nt < 4; ++nt)
          acc[mt][nt] = __builtin_amdgcn_mfma_f32_16x16x32_bf16(af[mt], bfr[nt], acc[mt][nt], 0, 0, 0);
    }
  }
#pragma unroll
  for (int nt = 0; nt < 4; ++nt) {
    int n = n0 + wc * 64 + nt * 16 + (l & 15);
    int nn = n & 511;
    float bv = ((n < 512) ? bfw : bbw)[(nn & 3) * 128 + (nn >> 2)];
#pragma unroll
    for (int mt = 0; mt < 4; ++mt) {
      int mb = m0 + wr * 64 + mt * 16 + (l >> 4) * 4;
#pragma unroll
      for (int r = 0; r < 4; ++r) {
        int row = mb + r;                                  // seq-major: seq*512+t
        int rp = ((row & 511) << 7) | (row >> 9);          // time-major: t*128+seq
        xg[((size_t)rp << 10) + n] = f2b(acc[mt][nt][r] + bv);
      }
    }
  }
}

// ---------------------------------------------------------------------------
// K5: LSTM recurrence as per-step batched MFMA GEMM.  v5.
// Mapping identical to v4 (4 seqs/block, 8 waves, 1 cell/lane, HT stride 160,
// pinned waves_per_eu(2,2), laundered weights, split-K MFMA).
// NEW: in-loop barriers are fast_barrier() (lgkmcnt-only drain). The previous
// __syncthreads drained vmcnt(0), serializing the xg prefetch's full HBM
// latency (~900 cyc) into EVERY step — the dominant cost at 1420 cyc/step.
// ---------------------------------------------------------------------------
__global__ __attribute__((amdgpu_waves_per_eu(2, 2))) __launch_bounds__(512)
void k_rec5(
    const bf16* __restrict__ xg,
    const bf16* __restrict__ whhF, const bf16* __restrict__ whhB,
    bf16* __restrict__ out) {
  constexpr int HS = 160;   // HT row stride in shorts
  int blk = blockIdx.x;
  int dir = blk >> 5;
  int seq0 = (blk & 31) * 4;
  const short* whhs = (const short*)(dir ? whhB : whhF);
  const bool rev = (dir == 1);
  int tid = threadIdx.x;
  int w = tid >> 6, l = tid & 63;
  int ln = l & 15, lk = l >> 4;
  int s = l & 3;
  int r = (l >> 2) & 3;
  int u = w * 16 + lk * 4 + r;    // my u (0..127)
  int seq = seq0 + s;

  // whh A-fragments, forced register-resident via opaque asm identity.
  u32x4 wfu[4][4];
#pragma unroll
  for (int g = 0; g < 4; ++g)
#pragma unroll
    for (int kk = 0; kk < 4; ++kk) {
      wfu[g][kk] = *(const u32x4*)&whhs[(size_t)(g * 128 + w * 16 + ln) * 128 + kk * 32 + lk * 8];
      asm volatile("" : "+v"(wfu[g][kk]));
    }

  __shared__ __align__(16) short HT[2][4][HS];
  for (int i = tid; i < 2 * 4 * HS; i += 512) ((short*)HT)[i] = 0;

  float c = 0.f;

  const bf16* xbase = xg + (size_t)seq * 1024 + dir * 512 + u * 4;
  bf16* obase = out + (size_t)seq * 131072 + (size_t)dir * 128 + u;

  uint2 xA, xB;
  {
    int p0 = rev ? 511 : 0, p1 = rev ? 510 : 1;
    xA = *(const uint2*)(xbase + ((size_t)p0 << 17));
    xB = *(const uint2*)(xbase + ((size_t)p1 << 17));
  }
  __syncthreads();

  auto do_step = [&](int tphys, int tpref, const short* RB, short* WB, uint2& x) {
    // B-fragments: col c of B = h[seq c&3]  (broadcast read of rows 0..3)
    short8 b0 = *(const short8*)&RB[s * HS + 0  + lk * 8];
    short8 b1 = *(const short8*)&RB[s * HS + 32 + lk * 8];
    short8 b2 = *(const short8*)&RB[s * HS + 64 + lk * 8];
    short8 b3 = *(const short8*)&RB[s * HS + 96 + lk * 8];
    uint2 xc = x;
    x = *(const uint2*)(xbase + ((size_t)tpref << 17));   // prefetch t+2
    // Z = whh @ h : split-K, 8 independent chains of depth 2
    f32x4 alo[4], ahi[4];
#pragma unroll
    for (int g = 0; g < 4; ++g) {
      alo[g] = __builtin_amdgcn_mfma_f32_16x16x32_bf16(
          __builtin_bit_cast(short8, wfu[g][0]), b0, (f32x4)0.f, 0, 0, 0);
      ahi[g] = __builtin_amdgcn_mfma_f32_16x16x32_bf16(
          __builtin_bit_cast(short8, wfu[g][2]), b2, (f32x4)0.f, 0, 0, 0);
    }
#pragma unroll
    for (int g = 0; g < 4; ++g) {
      alo[g] = __builtin_amdgcn_mfma_f32_16x16x32_bf16(
          __builtin_bit_cast(short8, wfu[g][1]), b1, alo[g], 0, 0, 0);
      ahi[g] = __builtin_amdgcn_mfma_f32_16x16x32_bf16(
          __builtin_bit_cast(short8, wfu[g][3]), b3, ahi[g], 0, 0, 0);
    }
    // in-lane select: z[g] = (alo+ahi)[g][r]
    float z[4];
#pragma unroll
    for (int g = 0; g < 4; ++g) {
      f32x4 a = alo[g] + ahi[g];
      float v01 = (r & 1) ? a[1] : a[0];
      float v23 = (r & 1) ? a[3] : a[2];
      z[g] = (r & 2) ? v23 : v01;
    }
    float xi = __uint_as_float(xc.x << 16);
    float xf = __uint_as_float(xc.x & 0xffff0000u);
    float xm = __uint_as_float(xc.y << 16);
    float xo = __uint_as_float(xc.y & 0xffff0000u);
    float ig = sig_(z[0] + xi), fg = sig_(z[1] + xf);
    float gv = tanh_(z[2] + xm), og = sig_(z[3] + xo);
    c = fmaf(fg, c, ig * gv);
    float h = og * tanh_(c);
    bf16 hb = f2b(h);
    *(short*)&WB[s * HS + u] = *(short*)&hb;          // h -> HT[nxt] row s
    *(bf16*)(obase + (size_t)tphys * 256) = hb;       // h -> global
  };

  for (int t = 0; t < kS; t += 2) {
    int ta = rev ? 511 - t : t;
    int tb = rev ? 510 - t : t + 1;
    int pa = (t + 2 < kS) ? t + 2 : kS - 1;
    int pb = (t + 3 < kS) ? t + 3 : kS - 1;
    int tpa = rev ? 511 - pa : pa;
    int tpb = rev ? 511 - pb : pb;
    do_step(ta, tpa, &HT[0][0][0], &HT[1][0][0], xA);
    fast_barrier();
    do_step(tb, tpb, &HT[1][0][0], &HT[0][0][0], xB);
    fast_barrier();
  }
}

// ---------------------------------------------------------------------------
// K6: classifier + char mask. out1 bf16 -> em fp32 (or NEG)
// ---------------------------------------------------------------------------
__global__ __launch_bounds__(256) void k_cls(
    const bf16* __restrict__ out1, const float* __restrict__ cls_w,
    const float* __restrict__ cls_b, const int* __restrict__ x,
    float* __restrict__ em) {
  __shared__ float W[17 * 256];
  __shared__ float part[64 * 4 * 17];
  int tid = threadIdx.x;
  for (int i = tid; i < 17 * 256; i += 256) W[i] = cls_w[i];
  __syncthreads();
  int r = tid >> 2, q = tid & 3;
  size_t row = (size_t)blockIdx.x * 64 + r;
  float acc[17];
#pragma unroll
  for (int j = 0; j < 17; ++j) acc[j] = 0.f;
  const uint4* a4p = (const uint4*)(out1 + row * 256 + q * 64);
  for (int i = 0; i < 8; ++i) {
    float f8[8]; unpack8(a4p[i], f8);
#pragma unroll
    for (int j = 0; j < 17; ++j) {
      const float* wr = &W[j * 256 + q * 64 + i * 8];
#pragma unroll
      for (int e = 0; e < 8; ++e) acc[j] = fmaf(f8[e], wr[e], acc[j]);
    }
  }
#pragma unroll
  for (int j = 0; j < 17; ++j) part[(r * 4 + q) * 17 + j] = acc[j];
  __syncthreads();
  for (int idx = tid; idx < 64 * 17; idx += 256) {
    int rr = idx / 17, j = idx % 17;
    size_t row2 = (size_t)blockIdx.x * 64 + rr;
    float v = part[(rr * 4 + 0) * 17 + j] + part[(rr * 4 + 1) * 17 + j] +
              part[(rr * 4 + 2) * 17 + j] + part[(rr * 4 + 3) * 17 + j] + cls_b[j];
    em[row2 * 17 + j] = (x[row2] != 0) ? v : -1e9f;
  }
}

// ---------------------------------------------------------------------------
// K7: CRF loss per sequence (1 wave / block). res[b] = logZ - score
// ---------------------------------------------------------------------------
__global__ __launch_bounds__(64) void k_crf(
    const float* __restrict__ em, const int* __restrict__ tags,
    const float* __restrict__ mask, const float* __restrict__ trans,
    const float* __restrict__ start_t, const float* __restrict__ end_t,
    float* __restrict__ res) {
  int b = blockIdx.x;
  int lane = threadIdx.x;
  const float* emB = em + (size_t)b * kS * 17;
  const int* tg = tags + b * kS;
  const float* mk = mask + b * kS;

  float tcol[17];
  if (lane < 17) {
#pragma unroll
    for (int i = 0; i < 17; ++i) tcol[i] = trans[i * 17 + lane];
  }
  float sc = 0.f, msum = 0.f;
  for (int t = lane; t < kS; t += 64) msum += mk[t];
  for (int t = 1 + lane; t < kS; t += 64)
    sc += (trans[tg[t - 1] * 17 + tg[t]] + emB[(size_t)t * 17 + tg[t]]) * mk[t];
#pragma unroll
  for (int o = 32; o; o >>= 1) { sc += __shfl_xor(sc, o); msum += __shfl_xor(msum, o); }

  __shared__ float al[17];
  if (lane < 17) al[lane] = start_t[lane] + emB[lane];
  __syncthreads();
  for (int t = 1; t < kS; ++t) {
    float nxt = 0.f;
    if (lane < 17) {
      float v[17]; float mx = -3.4e38f;
#pragma unroll
      for (int i = 0; i < 17; ++i) { v[i] = al[i] + tcol[i]; mx = fmaxf(mx, v[i]); }
      float s = 0.f;
#pragma unroll
      for (int i = 0; i < 17; ++i) s += __expf(v[i] - mx);
      float m = mk[t];
      nxt = (mx + __logf(s) + emB[(size_t)t * 17 + lane]) * m + al[lane] * (1.f - m);
    }
    __syncthreads();
    if (lane < 17) al[lane] = nxt;
    __syncthreads();
  }
  float val = (lane < 17) ? al[lane] + end_t[lane] : -3.4e38f;
  float mx = val;
#pragma unroll
  for (int o = 32; o; o >>= 1) mx = fmaxf(mx, __shfl_xor(mx, o));
  float s = (lane < 17) ? __expf(val - mx) : 0.f;
#pragma unroll
  for (int o = 32; o; o >>= 1) s += __shfl_xor(s, o);
  float logZ = mx + __logf(s);
  if (lane == 0) {
    float score = sc + start_t[tg[0]] + emB[tg[0]];
    int last_real = (int)(msum + 0.5f) - 1;
    if (last_real >= 0) score += end_t[tg[last_real]];
    res[b] = logZ - score;
  }
}

// K8: deterministic mean over 128 sequences -> d_out[0]
__global__ void k_loss(const float* __restrict__ res, float* __restrict__ out) {
  __shared__ float s[128];
  int tid = threadIdx.x;
  s[tid] = res[tid];
  __syncthreads();
  for (int off = 64; off; off >>= 1) {
    if (tid < off) s[tid] += s[tid + off];
    __syncthreads();
  }
  if (tid == 0) out[0] = s[0] / 128.f;
}

}  // namespace

extern "C" void kernel_launch(void* const* d_in, const int* in_sizes, int n_in,
                              void* d_out, int out_size, void* d_ws, size_t ws_size,
                              hipStream_t stream) {
  (void)in_sizes; (void)n_in; (void)out_size; (void)ws_size;
  const int*   x       = (const int*)  d_in[0];
  const int*   tags    = (const int*)  d_in[1];
  const float* mask    = (const float*)d_in[2];
  const float* emb     = (const float*)d_in[3];
  const float* cw3     = (const float*)d_in[4];
  const float* cb3     = (const float*)d_in[5];
  const float* cw5     = (const float*)d_in[6];
  const float* cb5     = (const float*)d_in[7];
  const float* cw7     = (const float*)d_in[8];
  const float* cb7     = (const float*)d_in[9];
  const float* hw_w    = (const float*)d_in[10];
  const float* hw_b    = (const float*)d_in[11];
  const float* hwg_w   = (const float*)d_in[12];
  const float* hwg_b   = (const float*)d_in[13];
  const float* wih0f   = (const float*)d_in[14];
  const float* whh0f   = (const float*)d_in[15];
  const float* b0f     = (const float*)d_in[16];
  const float* wih0b   = (const float*)d_in[17];
  const float* whh0b   = (const float*)d_in[18];
  const float* b0b     = (const float*)d_in[19];
  const float* wih1f   = (const float*)d_in[20];
  const float* whh1f   = (const float*)d_in[21];
  const float* b1f     = (const float*)d_in[22];
  const float* wih1b   = (const float*)d_in[23];
  const float* whh1b   = (const float*)d_in[24];
  const float* b1b     = (const float*)d_in[25];
  const float* cls_w   = (const float*)d_in[26];
  const float* cls_b   = (const float*)d_in[27];
  const float* trans   = (const float*)d_in[28];
  const float* start_t = (const float*)d_in[29];
  const float* end_t   = (const float*)d_in[30];

  // Workspace layout. tbl fp32 | bf16 weights | bf16 activations. ~210 MB.
  char* ws = (char*)d_ws;
  const size_t OFF_W0 = 393216;                            // tbl is [0, 372KB)
  const size_t OFF_W1 = OFF_W0 + (size_t)1024 * 192 * 2;
  const size_t OFF_WA = OFF_W1 + (size_t)1024 * 256 * 2;
  const size_t OFF_WG = OFF_WA + (size_t)192 * 192 * 2;
  const size_t OFF_WH = OFF_WG + (size_t)192 * 192 * 2;    // 4x whh bf16 (512KB)
  const size_t OFF_A  = OFF_WH + (size_t)4 * 512 * 128 * 2;
  const size_t SZ_A   = (size_t)kM * 192 * 2;              // 24 MB
  const size_t OFF_B  = OFF_A + SZ_A;
  const size_t OFF_O0 = OFF_B + SZ_A;                      // out0 bf16 (32MB); em fp32 later
  const size_t OFF_XG = OFF_O0 + (size_t)kM * 256 * 2;     // xg bf16 dual (128MB)
  float* tbl  = (float*)ws;
  bf16*  W0b  = (bf16*)(ws + OFF_W0);
  bf16*  W1b  = (bf16*)(ws + OFF_W1);
  bf16*  WAb  = (bf16*)(ws + OFF_WA);
  bf16*  WGb  = (bf16*)(ws + OFF_WG);
  bf16*  WHb  = (bf16*)(ws + OFF_WH);
  bf16*  bufA = (bf16*)(ws + OFF_A);
  bf16*  bufB = (bf16*)(ws + OFF_B);
  bf16*  out0 = (bf16*)(ws + OFF_O0);
  bf16*  out1 = (bf16*)(ws + OFF_A);                       // bufA/bufB dead by rec1
  bf16*  xg   = (bf16*)(ws + OFF_XG);
  float* em   = (float*)(ws + OFF_O0);                     // out0 dead after proj1
  float* resv = (float*)(ws + OFF_O0 + (size_t)kM * 17 * 4);

  // fused weight conversion prepass (wih gets gate-last row permutation)
  k_wprep<<<3104, 256, 0, stream>>>(wih0f, wih0b, wih1f, wih1b, hw_w, hwg_w,
                                    whh0f, whh0b, whh1f, whh1b,
                                    W0b, W1b, WAb, WGb, WHb);

  k_table<<<15 * 97, 64, 0, stream>>>(emb, cw3, cw5, cw7, tbl);
  k_conv<<<kB * (kS / 64), 192, 0, stream>>>(x, tbl, cb3, cb5, cb7, bufA);
  k_hw<<<dim3(kM / 128, 3), 256, 0, stream>>>(bufA, WAb, hw_b, WGb, hwg_b, bufB);

  k_pgemm<<<dim3(kM / 128, 8), 256, 0, stream>>>(bufB, 192, W0b, b0f, b0b, xg);
  k_rec5<<<64, 512, 0, stream>>>(xg, WHb + 0 * 65536, WHb + 1 * 65536, out0);
  k_pgemm<<<dim3(kM / 128, 8), 256, 0, stream>>>(out0, 256, W1b, b1f, b1b, xg);
  k_rec5<<<64, 512, 0, stream>>>(xg, WHb + 2 * 65536, WHb + 3 * 65536, out1);

  k_cls<<<kM / 64, 256, 0, stream>>>(out1, cls_w, cls_b, x, em);
  k_crf<<<kB, 64, 0, stream>>>(em, tags, mask, trans, start_t, end_t, resv);
  k_loss<<<1, 128, 0, stream>>>(resv, (float*)d_out);
}

// Round 13
// 1001.097 us; speedup vs baseline: 1.2754x; 1.0801x over previous
//
#include <hip/hip_runtime.h>
#include <hip/hip_bf16.h>
#include <cstdint>
#include <cstddef>

namespace {

constexpr int kB = 128;
constexpr int kS = 512;
constexpr int kM = kB * kS;   // 65536 rows

typedef __hip_bfloat16 bf16;
typedef __attribute__((ext_vector_type(8))) short short8;
typedef __attribute__((ext_vector_type(4))) float f32x4;
typedef __attribute__((ext_vector_type(4))) unsigned int u32x4;

__device__ __forceinline__ float sig_(float x) {
  return __builtin_amdgcn_rcpf(1.f + __expf(-x));
}
__device__ __forceinline__ float tanh_(float x) {
  return 1.f - 2.f * __builtin_amdgcn_rcpf(__expf(2.f * x) + 1.f);
}
__device__ __forceinline__ float b2f(bf16 h) { return __bfloat162float(h); }
__device__ __forceinline__ bf16 f2b(float f) { return __float2bfloat16(f); }

// unpack 8 bf16 (one uint4) -> 8 floats
__device__ __forceinline__ void unpack8(uint4 v, float* o) {
  o[0] = __uint_as_float(v.x << 16); o[1] = __uint_as_float(v.x & 0xffff0000u);
  o[2] = __uint_as_float(v.y << 16); o[3] = __uint_as_float(v.y & 0xffff0000u);
  o[4] = __uint_as_float(v.z << 16); o[5] = __uint_as_float(v.z & 0xffff0000u);
  o[6] = __uint_as_float(v.w << 16); o[7] = __uint_as_float(v.w & 0xffff0000u);
}

__device__ __forceinline__ void gl_lds16(const void* g, void* l) {
  __builtin_amdgcn_global_load_lds((const __attribute__((address_space(1))) void*)g,
                                   (__attribute__((address_space(3))) void*)l, 16, 0, 0);
}

// lgkmcnt-only barrier (no vmcnt drain). Proven correct in round 11.
__device__ __forceinline__ void fast_barrier() {
  __builtin_amdgcn_sched_barrier(0);
  asm volatile("s_waitcnt lgkmcnt(0)" ::: "memory");
  __builtin_amdgcn_s_barrier();
  __builtin_amdgcn_sched_barrier(0);
}

// ---------------------------------------------------------------------------
// K0: fused weight prep. Regions by blockIdx:
//  [0,384)    wih0f -> W0b          (K=192, gate-last row perm)
//  [384,768)  wih0b -> W0b+98304
//  [768,1280) wih1f -> W1b          (K=256, perm)
//  [1280,1792) wih1b -> W1b+131072
//  [1792,1936) hw_w -> WAb   [1936,2080) hwg_w -> WGb   (linear)
//  [2080,2336)+256*i whh_i -> WHb+i*65536                (linear)
// ---------------------------------------------------------------------------
__global__ void k_wprep(const float* __restrict__ wih0f, const float* __restrict__ wih0b,
                        const float* __restrict__ wih1f, const float* __restrict__ wih1b,
                        const float* __restrict__ hw_w, const float* __restrict__ hwg_w,
                        const float* __restrict__ whh0f, const float* __restrict__ whh0b,
                        const float* __restrict__ whh1f, const float* __restrict__ whh1b,
                        bf16* __restrict__ W0b, bf16* __restrict__ W1b,
                        bf16* __restrict__ WAb, bf16* __restrict__ WGb,
                        bf16* __restrict__ WHb) {
  int b = blockIdx.x, t = threadIdx.x;
  if (b < 768) {
    const float* s = (b < 384) ? wih0f : wih0b;
    bf16* d = W0b + (b < 384 ? 0 : 98304);
    int i = (b & 383) * 256 + t;
    int n = i / 192, k = i - n * 192;
    d[i] = f2b(s[((n & 3) * 128 + (n >> 2)) * 192 + k]);
  } else if (b < 1792) {
    int bb = b - 768;
    const float* s = (bb < 512) ? wih1f : wih1b;
    bf16* d = W1b + (bb < 512 ? 0 : 131072);
    int i = (bb & 511) * 256 + t;
    int n = i >> 8, k = i & 255;
    d[i] = f2b(s[((n & 3) * 128 + (n >> 2)) * 256 + k]);
  } else if (b < 2080) {
    int bb = b - 1792;
    const float* s = (bb < 144) ? hw_w : hwg_w;
    bf16* d = (bb < 144) ? WAb : WGb;
    int i = (bb % 144) * 256 + t;
    d[i] = f2b(s[i]);
  } else {
    int bb = b - 2080;
    int which = bb >> 8;
    const float* s = (which == 0) ? whh0f : (which == 1) ? whh0b : (which == 2) ? whh1f : whh1b;
    int i = (bb & 255) * 256 + t;
    WHb[which * 65536 + i] = f2b(s[i]);
  }
}

// ---------------------------------------------------------------------------
// K1: per-tap char projection table (fp32, 372KB)
// ---------------------------------------------------------------------------
__global__ void k_table(const float* __restrict__ emb,
                        const float* __restrict__ cw3,
                        const float* __restrict__ cw5,
                        const float* __restrict__ cw7,
                        float* __restrict__ tbl) {
  int e = blockIdx.x;           // 0..15*97-1
  int tap = e / 97, ch = e % 97;
  int f = threadIdx.x;          // 0..63
  const float* w; int kk, dk;
  if (tap < 3)      { w = cw3; kk = 3; dk = tap; }
  else if (tap < 8) { w = cw5; kk = 5; dk = tap - 3; }
  else              { w = cw7; kk = 7; dk = tap - 8; }
  const float* er = emb + ch * 128;
  float s = 0.f;
  for (int c = 0; c < 128; ++c) s = fmaf(er[c], w[(f * 128 + c) * kk + dk], s);
  tbl[(size_t)e * 64 + f] = s;
}

// ---------------------------------------------------------------------------
// K2: conv via table gathers + bias + relu -> bf16 (B*S, 192)
// ---------------------------------------------------------------------------
__global__ void k_conv(const int* __restrict__ x, const float* __restrict__ tbl,
                       const float* __restrict__ cb3, const float* __restrict__ cb5,
                       const float* __restrict__ cb7, bf16* __restrict__ outA) {
  __shared__ int chs[70];
  int b = blockIdx.x >> 3;
  int s0 = (blockIdx.x & 7) << 6;
  int tid = threadIdx.x;
  if (tid < 70) {
    int g = s0 - 3 + tid;
    chs[tid] = (g >= 0 && g < kS) ? x[b * kS + g] : 0;   // char 0 => zero row
  }
  __syncthreads();
  int wv = tid >> 6;
  int f = tid & 63;
  int ntap, tap0, half; const float* cb;
  if (wv == 0)      { ntap = 3; tap0 = 0; half = 1; cb = cb3; }
  else if (wv == 1) { ntap = 5; tap0 = 3; half = 2; cb = cb5; }
  else              { ntap = 7; tap0 = 8; half = 3; cb = cb7; }
  float bias = cb[f];
  for (int p = 0; p < 64; ++p) {
    float acc = bias;
    for (int dk = 0; dk < ntap; ++dk) {
      int c = chs[p + 3 - half + dk];
      acc += tbl[(size_t)((tap0 + dk) * 97 + c) * 64 + f];
    }
    outA[(size_t)(b * kS + s0 + p) * 192 + wv * 64 + f] = f2b(fmaxf(acc, 0.f));
  }
}

// ---------------------------------------------------------------------------
// K3: highway via MFMA, fused dual GEMM (Wa and Wg in one pass).
// ---------------------------------------------------------------------------
__global__ __launch_bounds__(256) void k_hw(
    const bf16* __restrict__ A,
    const bf16* __restrict__ Wa, const float* __restrict__ Ba,
    const bf16* __restrict__ Wg, const float* __restrict__ Bg,
    bf16* __restrict__ outB) {
  __shared__ __align__(16) short As[128 * 64];
  __shared__ __align__(16) short Was[64 * 64];
  __shared__ __align__(16) short Wgs[64 * 64];
  constexpr int K = 192;
  int tid = threadIdx.x;
  int w = tid >> 6, l = tid & 63;
  int m0 = blockIdx.x * 128, n0 = blockIdx.y * 64;
  int wr = w >> 1, wc = w & 1;
  int lr = l >> 3, lc = l & 7;
  f32x4 accA[4][2], accG[4][2];
#pragma unroll
  for (int i = 0; i < 4; ++i)
#pragma unroll
    for (int j = 0; j < 2; ++j) { accA[i][j] = (f32x4)0.f; accG[i][j] = (f32x4)0.f; }

  for (int kc = 0; kc < K; kc += 64) {
    __syncthreads();
#pragma unroll
    for (int i = 0; i < 4; ++i) {
      int r = w * 32 + i * 8;
      gl_lds16(A + (size_t)(m0 + r + lr) * K + kc + lc * 8, &As[r * 64]);
    }
#pragma unroll
    for (int i = 0; i < 2; ++i) {
      int r = w * 16 + i * 8;
      gl_lds16(Wa + (size_t)(n0 + r + lr) * K + kc + lc * 8, &Was[r * 64]);
      gl_lds16(Wg + (size_t)(n0 + r + lr) * K + kc + lc * 8, &Wgs[r * 64]);
    }
    __syncthreads();
#pragma unroll
    for (int kf = 0; kf < 2; ++kf) {
      short8 af[4], ba[2], bg[2];
#pragma unroll
      for (int mt = 0; mt < 4; ++mt)
        af[mt] = *(const short8*)&As[(wr * 64 + mt * 16 + (l & 15)) * 64 + kf * 32 + (l >> 4) * 8];
#pragma unroll
      for (int nt = 0; nt < 2; ++nt) {
        int rn = (wc * 32 + nt * 16 + (l & 15)) * 64 + kf * 32 + (l >> 4) * 8;
        ba[nt] = *(const short8*)&Was[rn];
        bg[nt] = *(const short8*)&Wgs[rn];
      }
#pragma unroll
      for (int mt = 0; mt < 4; ++mt)
#pragma unroll
        for (int nt = 0; nt < 2; ++nt) {
          accA[mt][nt] = __builtin_amdgcn_mfma_f32_16x16x32_bf16(af[mt], ba[nt], accA[mt][nt], 0, 0, 0);
          accG[mt][nt] = __builtin_amdgcn_mfma_f32_16x16x32_bf16(af[mt], bg[nt], accG[mt][nt], 0, 0, 0);
        }
    }
  }
#pragma unroll
  for (int nt = 0; nt < 2; ++nt) {
    int n = n0 + wc * 32 + nt * 16 + (l & 15);
    float bav = Ba[n], bgv = Bg[n];
#pragma unroll
    for (int mt = 0; mt < 4; ++mt) {
      int mb = m0 + wr * 64 + mt * 16 + (l >> 4) * 4;
#pragma unroll
      for (int r = 0; r < 4; ++r) {
        float av = accA[mt][nt][r] + bav;
        float gv = accG[mt][nt][r] + bgv;
        float tt = sig_(gv);
        float orig = b2f(A[(size_t)(mb + r) * K + n]);
        outB[(size_t)(mb + r) * K + n] = f2b(tt * fmaxf(av, 0.f) + (1.f - tt) * orig);
      }
    }
  }
}

// ---------------------------------------------------------------------------
// K4: LSTM input projection via MFMA. BM=128, BN=128, BK=64, 4 waves 2x2.
// W is PRE-PERMUTED to gate-last row order (row u*4+g), so the natural
// coalesced write produces xg[(t*128+seq)*1024 + dir*512 + u*4 + g].
// ---------------------------------------------------------------------------
__global__ __launch_bounds__(256) void k_pgemm(
    const bf16* __restrict__ A, int K,
    const bf16* __restrict__ W,
    const float* __restrict__ bfw, const float* __restrict__ bbw,
    bf16* __restrict__ xg) {
  __shared__ __align__(16) short As[128 * 64];
  __shared__ __align__(16) short Bs[128 * 64];
  int tid = threadIdx.x;
  int w = tid >> 6, l = tid & 63;
  int m0 = blockIdx.x * 128, n0 = blockIdx.y * 128;
  int wr = w >> 1, wc = w & 1;
  int lr = l >> 3, lc = l & 7;
  f32x4 acc[4][4];
#pragma unroll
  for (int i = 0; i < 4; ++i)
#pragma unroll
    for (int j = 0; j < 4; ++j) acc[i][j] = (f32x4)0.f;

  for (int kc = 0; kc < K; kc += 64) {
    __syncthreads();
#pragma unroll
    for (int i = 0; i < 4; ++i) {
      int r = w * 32 + i * 8;
      gl_lds16(A + (size_t)(m0 + r + lr) * K + kc + lc * 8, &As[r * 64]);
      gl_lds16(W + (size_t)(n0 + r + lr) * K + kc + lc * 8, &Bs[r * 64]);
    }
    __syncthreads();
#pragma unroll
    for (int kf = 0; kf < 2; ++kf) {
      short8 af[4], bfr[4];
#pragma unroll
      for (int mt = 0; mt < 4; ++mt)
        af[mt] = *(const short8*)&As[(wr * 64 + mt * 16 + (l & 15)) * 64 + kf * 32 + (l >> 4) * 8];
#pragma unroll
      for (int nt = 0; nt < 4; ++nt)
        bfr[nt] = *(const short8*)&Bs[(wc * 64 + nt * 16 + (l & 15)) * 64 + kf * 32 + (l >> 4) * 8];
#pragma unroll
      for (int mt = 0; mt < 4; ++mt)
#pragma unroll
        for (int nt = 0; nt < 4; ++nt)
          acc[mt][nt] = __builtin_amdgcn_mfma_f32_16x16x32_bf16(af[mt], bfr[nt], acc[mt][nt], 0, 0, 0);
    }
  }
#pragma unroll
  for (int nt = 0; nt < 4; ++nt) {
    int n = n0 + wc * 64 + nt * 16 + (l & 15);
    int nn = n & 511;
    float bv = ((n < 512) ? bfw : bbw)[(nn & 3) * 128 + (nn >> 2)];
#pragma unroll
    for (int mt = 0; mt < 4; ++mt) {
      int mb = m0 + wr * 64 + mt * 16 + (l >> 4) * 4;
#pragma unroll
      for (int r = 0; r < 4; ++r) {
        int row = mb + r;                                  // seq-major: seq*512+t
        int rp = ((row & 511) << 7) | (row >> 9);          // time-major: t*128+seq
        xg[((size_t)rp << 10) + n] = f2b(acc[mt][nt][r] + bv);
      }
    }
  }
}

// ---------------------------------------------------------------------------
// K5: LSTM recurrence as per-step batched MFMA GEMM.  v6.
// Round-11 profile: per-ACTIVE-CU VALUBusy 49% + MfmaUtil 36% => issue-bound
// on 64 CUs. Fix = spread over more CUs with less issue per SIMD:
// Grid 128 = (dir 0..1) x (64 pairs of seqs). 256 threads = 4 waves, 1/SIMD.
// B-replication 8x: MFMA col c carries seq (c&1); B-frag read from HT[l&1]
// (8 distinct 16B addrs covering all 32 banks -> conflict-free).
// Wave w owns u in [w*32, w*32+32) x 4 gates = 8 M-tiles x 4 K = 32 MFMA/step
// (8 independent depth-4 chains). Weights 32 short8 = 128 VGPR (laundered).
// Lane bijection: seq = l&1, u_local = ((l>>1)&1)*16 + (l>>4)*4 + ((l>>2)&3)
// -> 1 cell/lane, selects via cndmask (ut then r), no cross-lane ops.
// ---------------------------------------------------------------------------
__global__ __attribute__((amdgpu_waves_per_eu(1, 1))) __launch_bounds__(256)
void k_rec6(
    const bf16* __restrict__ xg,
    const bf16* __restrict__ whhF, const bf16* __restrict__ whhB,
    bf16* __restrict__ out) {
  constexpr int HS = 160;   // HT row stride in shorts
  int blk = blockIdx.x;
  int dir = blk >> 6;
  int seq0 = (blk & 63) * 2;
  const short* whhs = (const short*)(dir ? whhB : whhF);
  const bool rev = (dir == 1);
  int tid = threadIdx.x;
  int w = tid >> 6, l = tid & 63;
  int ln = l & 15, lk = l >> 4;
  int s = l & 1;                   // my seq (0/1)
  int ut = (l >> 1) & 1;           // my u-subtile
  int r = (l >> 2) & 3;            // my acc row within subtile row-group
  int ul = ut * 16 + lk * 4 + r;   // my u within wave chunk (0..31)
  int u = w * 32 + ul;             // my u (0..127)
  int seq = seq0 + s;

  // whh A-fragments, register-resident. wf[g][ut][kk]: rows g*128+w*32+ut*16+ln
  u32x4 wfu[4][2][4];
#pragma unroll
  for (int g = 0; g < 4; ++g)
#pragma unroll
    for (int t2 = 0; t2 < 2; ++t2)
#pragma unroll
      for (int kk = 0; kk < 4; ++kk) {
        wfu[g][t2][kk] = *(const u32x4*)&whhs[(size_t)(g * 128 + w * 32 + t2 * 16 + ln) * 128 + kk * 32 + lk * 8];
        asm volatile("" : "+v"(wfu[g][t2][kk]));
      }

  __shared__ __align__(16) short HT[2][2][HS];
  for (int i = tid; i < 2 * 2 * HS; i += 256) ((short*)HT)[i] = 0;

  float c = 0.f;

  const bf16* xbase = xg + (size_t)seq * 1024 + dir * 512 + u * 4;
  bf16* obase = out + (size_t)seq * 131072 + (size_t)dir * 128 + u;

  uint2 xA, xB;
  {
    int p0 = rev ? 511 : 0, p1 = rev ? 510 : 1;
    xA = *(const uint2*)(xbase + ((size_t)p0 << 17));
    xB = *(const uint2*)(xbase + ((size_t)p1 << 17));
  }
  __syncthreads();

  auto do_step = [&](int tphys, int tpref, const short* RB, short* WB, uint2& x) {
    // B-fragments: col c of B = h[seq c&1]  (broadcast read of rows 0..1)
    short8 b0 = *(const short8*)&RB[s * HS + 0  + lk * 8];
    short8 b1 = *(const short8*)&RB[s * HS + 32 + lk * 8];
    short8 b2 = *(const short8*)&RB[s * HS + 64 + lk * 8];
    short8 b3 = *(const short8*)&RB[s * HS + 96 + lk * 8];
    uint2 xc = x;
    x = *(const uint2*)(xbase + ((size_t)tpref << 17));   // prefetch t+2
    // Z = whh @ h : 8 independent depth-4 MFMA chains
    f32x4 acc[4][2];
#pragma unroll
    for (int g = 0; g < 4; ++g) { acc[g][0] = (f32x4)0.f; acc[g][1] = (f32x4)0.f; }
#pragma unroll
    for (int g = 0; g < 4; ++g)
#pragma unroll
      for (int t2 = 0; t2 < 2; ++t2) {
        acc[g][t2] = __builtin_amdgcn_mfma_f32_16x16x32_bf16(
            __builtin_bit_cast(short8, wfu[g][t2][0]), b0, acc[g][t2], 0, 0, 0);
        acc[g][t2] = __builtin_amdgcn_mfma_f32_16x16x32_bf16(
            __builtin_bit_cast(short8, wfu[g][t2][1]), b1, acc[g][t2], 0, 0, 0);
        acc[g][t2] = __builtin_amdgcn_mfma_f32_16x16x32_bf16(
            __builtin_bit_cast(short8, wfu[g][t2][2]), b2, acc[g][t2], 0, 0, 0);
        acc[g][t2] = __builtin_amdgcn_mfma_f32_16x16x32_bf16(
            __builtin_bit_cast(short8, wfu[g][t2][3]), b3, acc[g][t2], 0, 0, 0);
      }
    // in-lane select: z[g] = acc[g][ut][r]
    float z[4];
#pragma unroll
    for (int g = 0; g < 4; ++g) {
      f32x4 a0 = acc[g][0], a1 = acc[g][1];
      float p01 = (r & 1) ? a0[1] : a0[0];
      float p23 = (r & 1) ? a0[3] : a0[2];
      float v0 = (r & 2) ? p23 : p01;
      float q01 = (r & 1) ? a1[1] : a1[0];
      float q23 = (r & 1) ? a1[3] : a1[2];
      float v1 = (r & 2) ? q23 : q01;
      z[g] = ut ? v1 : v0;
    }
    float xi = __uint_as_float(xc.x << 16);
    float xf = __uint_as_float(xc.x & 0xffff0000u);
    float xm = __uint_as_float(xc.y << 16);
    float xo = __uint_as_float(xc.y & 0xffff0000u);
    float ig = sig_(z[0] + xi), fg = sig_(z[1] + xf);
    float gv = tanh_(z[2] + xm), og = sig_(z[3] + xo);
    c = fmaf(fg, c, ig * gv);
    float h = og * tanh_(c);
    bf16 hb = f2b(h);
    *(short*)&WB[s * HS + u] = *(short*)&hb;          // h -> HT[nxt] row s
    *(bf16*)(obase + (size_t)tphys * 256) = hb;       // h -> global
  };

  for (int t = 0; t < kS; t += 2) {
    int ta = rev ? 511 - t : t;
    int tb = rev ? 510 - t : t + 1;
    int pa = (t + 2 < kS) ? t + 2 : kS - 1;
    int pb = (t + 3 < kS) ? t + 3 : kS - 1;
    int tpa = rev ? 511 - pa : pa;
    int tpb = rev ? 511 - pb : pb;
    do_step(ta, tpa, &HT[0][0][0], &HT[1][0][0], xA);
    fast_barrier();
    do_step(tb, tpb, &HT[1][0][0], &HT[0][0][0], xB);
    fast_barrier();
  }
}

// ---------------------------------------------------------------------------
// K6: classifier + char mask. out1 bf16 -> em fp32 (or NEG)
// ---------------------------------------------------------------------------
__global__ __launch_bounds__(256) void k_cls(
    const bf16* __restrict__ out1, const float* __restrict__ cls_w,
    const float* __restrict__ cls_b, const int* __restrict__ x,
    float* __restrict__ em) {
  __shared__ float W[17 * 256];
  __shared__ float part[64 * 4 * 17];
  int tid = threadIdx.x;
  for (int i = tid; i < 17 * 256; i += 256) W[i] = cls_w[i];
  __syncthreads();
  int r = tid >> 2, q = tid & 3;
  size_t row = (size_t)blockIdx.x * 64 + r;
  float acc[17];
#pragma unroll
  for (int j = 0; j < 17; ++j) acc[j] = 0.f;
  const uint4* a4p = (const uint4*)(out1 + row * 256 + q * 64);
  for (int i = 0; i < 8; ++i) {
    float f8[8]; unpack8(a4p[i], f8);
#pragma unroll
    for (int j = 0; j < 17; ++j) {
      const float* wr = &W[j * 256 + q * 64 + i * 8];
#pragma unroll
      for (int e = 0; e < 8; ++e) acc[j] = fmaf(f8[e], wr[e], acc[j]);
    }
  }
#pragma unroll
  for (int j = 0; j < 17; ++j) part[(r * 4 + q) * 17 + j] = acc[j];
  __syncthreads();
  for (int idx = tid; idx < 64 * 17; idx += 256) {
    int rr = idx / 17, j = idx % 17;
    size_t row2 = (size_t)blockIdx.x * 64 + rr;
    float v = part[(rr * 4 + 0) * 17 + j] + part[(rr * 4 + 1) * 17 + j] +
              part[(rr * 4 + 2) * 17 + j] + part[(rr * 4 + 3) * 17 + j] + cls_b[j];
    em[row2 * 17 + j] = (x[row2] != 0) ? v : -1e9f;
  }
}

// ---------------------------------------------------------------------------
// K7: CRF loss per sequence (1 wave / block). res[b] = logZ - score
// ---------------------------------------------------------------------------
__global__ __launch_bounds__(64) void k_crf(
    const float* __restrict__ em, const int* __restrict__ tags,
    const float* __restrict__ mask, const float* __restrict__ trans,
    const float* __restrict__ start_t, const float* __restrict__ end_t,
    float* __restrict__ res) {
  int b = blockIdx.x;
  int lane = threadIdx.x;
  const float* emB = em + (size_t)b * kS * 17;
  const int* tg = tags + b * kS;
  const float* mk = mask + b * kS;

  float tcol[17];
  if (lane < 17) {
#pragma unroll
    for (int i = 0; i < 17; ++i) tcol[i] = trans[i * 17 + lane];
  }
  float sc = 0.f, msum = 0.f;
  for (int t = lane; t < kS; t += 64) msum += mk[t];
  for (int t = 1 + lane; t < kS; t += 64)
    sc += (trans[tg[t - 1] * 17 + tg[t]] + emB[(size_t)t * 17 + tg[t]]) * mk[t];
#pragma unroll
  for (int o = 32; o; o >>= 1) { sc += __shfl_xor(sc, o); msum += __shfl_xor(msum, o); }

  __shared__ float al[17];
  if (lane < 17) al[lane] = start_t[lane] + emB[lane];
  __syncthreads();
  for (int t = 1; t < kS; ++t) {
    float nxt = 0.f;
    if (lane < 17) {
      float v[17]; float mx = -3.4e38f;
#pragma unroll
      for (int i = 0; i < 17; ++i) { v[i] = al[i] + tcol[i]; mx = fmaxf(mx, v[i]); }
      float s = 0.f;
#pragma unroll
      for (int i = 0; i < 17; ++i) s += __expf(v[i] - mx);
      float m = mk[t];
      nxt = (mx + __logf(s) + emB[(size_t)t * 17 + lane]) * m + al[lane] * (1.f - m);
    }
    __syncthreads();
    if (lane < 17) al[lane] = nxt;
    __syncthreads();
  }
  float val = (lane < 17) ? al[lane] + end_t[lane] : -3.4e38f;
  float mx = val;
#pragma unroll
  for (int o = 32; o; o >>= 1) mx = fmaxf(mx, __shfl_xor(mx, o));
  float s = (lane < 17) ? __expf(val - mx) : 0.f;
#pragma unroll
  for (int o = 32; o; o >>= 1) s += __shfl_xor(s, o);
  float logZ = mx + __logf(s);
  if (lane == 0) {
    float score = sc + start_t[tg[0]] + emB[tg[0]];
    int last_real = (int)(msum + 0.5f) - 1;
    if (last_real >= 0) score += end_t[tg[last_real]];
    res[b] = logZ - score;
  }
}

// K8: deterministic mean over 128 sequences -> d_out[0]
__global__ void k_loss(const float* __restrict__ res, float* __restrict__ out) {
  __shared__ float s[128];
  int tid = threadIdx.x;
  s[tid] = res[tid];
  __syncthreads();
  for (int off = 64; off; off >>= 1) {
    if (tid < off) s[tid] += s[tid + off];
    __syncthreads();
  }
  if (tid == 0) out[0] = s[0] / 128.f;
}

}  // namespace

extern "C" void kernel_launch(void* const* d_in, const int* in_sizes, int n_in,
                              void* d_out, int out_size, void* d_ws, size_t ws_size,
                              hipStream_t stream) {
  (void)in_sizes; (void)n_in; (void)out_size; (void)ws_size;
  const int*   x       = (const int*)  d_in[0];
  const int*   tags    = (const int*)  d_in[1];
  const float* mask    = (const float*)d_in[2];
  const float* emb     = (const float*)d_in[3];
  const float* cw3     = (const float*)d_in[4];
  const float* cb3     = (const float*)d_in[5];
  const float* cw5     = (const float*)d_in[6];
  const float* cb5     = (const float*)d_in[7];
  const float* cw7     = (const float*)d_in[8];
  const float* cb7     = (const float*)d_in[9];
  const float* hw_w    = (const float*)d_in[10];
  const float* hw_b    = (const float*)d_in[11];
  const float* hwg_w   = (const float*)d_in[12];
  const float* hwg_b   = (const float*)d_in[13];
  const float* wih0f   = (const float*)d_in[14];
  const float* whh0f   = (const float*)d_in[15];
  const float* b0f     = (const float*)d_in[16];
  const float* wih0b   = (const float*)d_in[17];
  const float* whh0b   = (const float*)d_in[18];
  const float* b0b     = (const float*)d_in[19];
  const float* wih1f   = (const float*)d_in[20];
  const float* whh1f   = (const float*)d_in[21];
  const float* b1f     = (const float*)d_in[22];
  const float* wih1b   = (const float*)d_in[23];
  const float* whh1b   = (const float*)d_in[24];
  const float* b1b     = (const float*)d_in[25];
  const float* cls_w   = (const float*)d_in[26];
  const float* cls_b   = (const float*)d_in[27];
  const float* trans   = (const float*)d_in[28];
  const float* start_t = (const float*)d_in[29];
  const float* end_t   = (const float*)d_in[30];

  // Workspace layout. tbl fp32 | bf16 weights | bf16 activations. ~210 MB.
  char* ws = (char*)d_ws;
  const size_t OFF_W0 = 393216;                            // tbl is [0, 372KB)
  const size_t OFF_W1 = OFF_W0 + (size_t)1024 * 192 * 2;
  const size_t OFF_WA = OFF_W1 + (size_t)1024 * 256 * 2;
  const size_t OFF_WG = OFF_WA + (size_t)192 * 192 * 2;
  const size_t OFF_WH = OFF_WG + (size_t)192 * 192 * 2;    // 4x whh bf16 (512KB)
  const size_t OFF_A  = OFF_WH + (size_t)4 * 512 * 128 * 2;
  const size_t SZ_A   = (size_t)kM * 192 * 2;              // 24 MB
  const size_t OFF_B  = OFF_A + SZ_A;
  const size_t OFF_O0 = OFF_B + SZ_A;                      // out0 bf16 (32MB); em fp32 later
  const size_t OFF_XG = OFF_O0 + (size_t)kM * 256 * 2;     // xg bf16 dual (128MB)
  float* tbl  = (float*)ws;
  bf16*  W0b  = (bf16*)(ws + OFF_W0);
  bf16*  W1b  = (bf16*)(ws + OFF_W1);
  bf16*  WAb  = (bf16*)(ws + OFF_WA);
  bf16*  WGb  = (bf16*)(ws + OFF_WG);
  bf16*  WHb  = (bf16*)(ws + OFF_WH);
  bf16*  bufA = (bf16*)(ws + OFF_A);
  bf16*  bufB = (bf16*)(ws + OFF_B);
  bf16*  out0 = (bf16*)(ws + OFF_O0);
  bf16*  out1 = (bf16*)(ws + OFF_A);                       // bufA/bufB dead by rec1
  bf16*  xg   = (bf16*)(ws + OFF_XG);
  float* em   = (float*)(ws + OFF_O0);                     // out0 dead after proj1
  float* resv = (float*)(ws + OFF_O0 + (size_t)kM * 17 * 4);

  // fused weight conversion prepass (wih gets gate-last row permutation)
  k_wprep<<<3104, 256, 0, stream>>>(wih0f, wih0b, wih1f, wih1b, hw_w, hwg_w,
                                    whh0f, whh0b, whh1f, whh1b,
                                    W0b, W1b, WAb, WGb, WHb);

  k_table<<<15 * 97, 64, 0, stream>>>(emb, cw3, cw5, cw7, tbl);
  k_conv<<<kB * (kS / 64), 192, 0, stream>>>(x, tbl, cb3, cb5, cb7, bufA);
  k_hw<<<dim3(kM / 128, 3), 256, 0, stream>>>(bufA, WAb, hw_b, WGb, hwg_b, bufB);

  k_pgemm<<<dim3(kM / 128, 8), 256, 0, stream>>>(bufB, 192, W0b, b0f, b0b, xg);
  k_rec6<<<128, 256, 0, stream>>>(xg, WHb + 0 * 65536, WHb + 1 * 65536, out0);
  k_pgemm<<<dim3(kM / 128, 8), 256, 0, stream>>>(out0, 256, W1b, b1f, b1b, xg);
  k_rec6<<<128, 256, 0, stream>>>(xg, WHb + 2 * 65536, WHb + 3 * 65536, out1);

  k_cls<<<kM / 64, 256, 0, stream>>>(out1, cls_w, cls_b, x, em);
  k_crf<<<kB, 64, 0, stream>>>(em, tags, mask, trans, start_t, end_t, resv);
  k_loss<<<1, 128, 0, stream>>>(resv, (float*)d_out);
}

// Round 14
// 985.100 us; speedup vs baseline: 1.2961x; 1.0162x over previous
//
#include <hip/hip_runtime.h>
#include <hip/hip_bf16.h>
#include <cstdint>
#include <cstddef>

namespace {

constexpr int kB = 128;
constexpr int kS = 512;
constexpr int kM = kB * kS;   // 65536 rows

typedef __hip_bfloat16 bf16;
typedef __attribute__((ext_vector_type(8))) short short8;
typedef __attribute__((ext_vector_type(4))) float f32x4;
typedef __attribute__((ext_vector_type(4))) unsigned int u32x4;

__device__ __forceinline__ float sig_(float x) {
  return __builtin_amdgcn_rcpf(1.f + __expf(-x));
}
__device__ __forceinline__ float tanh_(float x) {
  return 1.f - 2.f * __builtin_amdgcn_rcpf(__expf(2.f * x) + 1.f);
}
__device__ __forceinline__ float b2f(bf16 h) { return __bfloat162float(h); }
__device__ __forceinline__ bf16 f2b(float f) { return __float2bfloat16(f); }

// unpack 8 bf16 (one uint4) -> 8 floats
__device__ __forceinline__ void unpack8(uint4 v, float* o) {
  o[0] = __uint_as_float(v.x << 16); o[1] = __uint_as_float(v.x & 0xffff0000u);
  o[2] = __uint_as_float(v.y << 16); o[3] = __uint_as_float(v.y & 0xffff0000u);
  o[4] = __uint_as_float(v.z << 16); o[5] = __uint_as_float(v.z & 0xffff0000u);
  o[6] = __uint_as_float(v.w << 16); o[7] = __uint_as_float(v.w & 0xffff0000u);
}

__device__ __forceinline__ void gl_lds16(const void* g, void* l) {
  __builtin_amdgcn_global_load_lds((const __attribute__((address_space(1))) void*)g,
                                   (__attribute__((address_space(3))) void*)l, 16, 0, 0);
}

// lgkmcnt-only barrier (no vmcnt drain). Proven correct rounds 11-13.
__device__ __forceinline__ void fast_barrier() {
  __builtin_amdgcn_sched_barrier(0);
  asm volatile("s_waitcnt lgkmcnt(0)" ::: "memory");
  __builtin_amdgcn_s_barrier();
  __builtin_amdgcn_sched_barrier(0);
}

// ---------------------------------------------------------------------------
// K0: fused weight prep + char projection table. Regions by blockIdx:
//  [0,384)     wih0f -> W0b          (K=192, gate-last row perm)
//  [384,768)   wih0b -> W0b+98304
//  [768,1280)  wih1f -> W1b          (K=256, perm)
//  [1280,1792) wih1b -> W1b+131072
//  [1792,1936) hw_w -> WAb   [1936,2080) hwg_w -> WGb   (linear)
//  [2080,3104) whh_i -> WHb+i*65536  (linear, 256 blocks each)
//  [3104,3468) char table: tbl[(tap*97+ch)*64+f] = sum_c emb[ch][c]*W_k[f][c][dk]
// ---------------------------------------------------------------------------
__global__ void k_wprep(const float* __restrict__ wih0f, const float* __restrict__ wih0b,
                        const float* __restrict__ wih1f, const float* __restrict__ wih1b,
                        const float* __restrict__ hw_w, const float* __restrict__ hwg_w,
                        const float* __restrict__ whh0f, const float* __restrict__ whh0b,
                        const float* __restrict__ whh1f, const float* __restrict__ whh1b,
                        const float* __restrict__ emb, const float* __restrict__ cw3,
                        const float* __restrict__ cw5, const float* __restrict__ cw7,
                        bf16* __restrict__ W0b, bf16* __restrict__ W1b,
                        bf16* __restrict__ WAb, bf16* __restrict__ WGb,
                        bf16* __restrict__ WHb, float* __restrict__ tbl) {
  int b = blockIdx.x, t = threadIdx.x;
  if (b < 768) {
    const float* s = (b < 384) ? wih0f : wih0b;
    bf16* d = W0b + (b < 384 ? 0 : 98304);
    int i = (b & 383) * 256 + t;
    int n = i / 192, k = i - n * 192;
    d[i] = f2b(s[((n & 3) * 128 + (n >> 2)) * 192 + k]);
  } else if (b < 1792) {
    int bb = b - 768;
    const float* s = (bb < 512) ? wih1f : wih1b;
    bf16* d = W1b + (bb < 512 ? 0 : 131072);
    int i = (bb & 511) * 256 + t;
    int n = i >> 8, k = i & 255;
    d[i] = f2b(s[((n & 3) * 128 + (n >> 2)) * 256 + k]);
  } else if (b < 2080) {
    int bb = b - 1792;
    const float* s = (bb < 144) ? hw_w : hwg_w;
    bf16* d = (bb < 144) ? WAb : WGb;
    int i = (bb % 144) * 256 + t;
    d[i] = f2b(s[i]);
  } else if (b < 3104) {
    int bb = b - 2080;
    int which = bb >> 8;
    const float* s = (which == 0) ? whh0f : (which == 1) ? whh0b : (which == 2) ? whh1f : whh1b;
    int i = (bb & 255) * 256 + t;
    WHb[which * 65536 + i] = f2b(s[i]);
  } else {
    int idx = (b - 3104) * 256 + t;         // (e, f) pair: e < 15*97 = 1455
    int e = idx >> 6, f = idx & 63;
    if (e < 15 * 97) {
      int tap = e / 97, ch = e % 97;
      const float* w; int kk, dk;
      if (tap < 3)      { w = cw3; kk = 3; dk = tap; }
      else if (tap < 8) { w = cw5; kk = 5; dk = tap - 3; }
      else              { w = cw7; kk = 7; dk = tap - 8; }
      const float* er = emb + ch * 128;
      float s = 0.f;
      for (int c = 0; c < 128; ++c) s = fmaf(er[c], w[(f * 128 + c) * kk + dk], s);
      tbl[(size_t)e * 64 + f] = s;
    }
  }
}

// ---------------------------------------------------------------------------
// K2: conv via table gathers + bias + relu -> bf16 (B*S, 192)
// ---------------------------------------------------------------------------
__global__ void k_conv(const int* __restrict__ x, const float* __restrict__ tbl,
                       const float* __restrict__ cb3, const float* __restrict__ cb5,
                       const float* __restrict__ cb7, bf16* __restrict__ outA) {
  __shared__ int chs[70];
  int b = blockIdx.x >> 3;
  int s0 = (blockIdx.x & 7) << 6;
  int tid = threadIdx.x;
  if (tid < 70) {
    int g = s0 - 3 + tid;
    chs[tid] = (g >= 0 && g < kS) ? x[b * kS + g] : 0;   // char 0 => zero row
  }
  __syncthreads();
  int wv = tid >> 6;
  int f = tid & 63;
  int ntap, tap0, half; const float* cb;
  if (wv == 0)      { ntap = 3; tap0 = 0; half = 1; cb = cb3; }
  else if (wv == 1) { ntap = 5; tap0 = 3; half = 2; cb = cb5; }
  else              { ntap = 7; tap0 = 8; half = 3; cb = cb7; }
  float bias = cb[f];
  for (int p = 0; p < 64; ++p) {
    float acc = bias;
    for (int dk = 0; dk < ntap; ++dk) {
      int c = chs[p + 3 - half + dk];
      acc += tbl[(size_t)((tap0 + dk) * 97 + c) * 64 + f];
    }
    outA[(size_t)(b * kS + s0 + p) * 192 + wv * 64 + f] = f2b(fmaxf(acc, 0.f));
  }
}

// ---------------------------------------------------------------------------
// K3: highway via MFMA, fused dual GEMM (Wa and Wg in one pass).
// ---------------------------------------------------------------------------
__global__ __launch_bounds__(256) void k_hw(
    const bf16* __restrict__ A,
    const bf16* __restrict__ Wa, const float* __restrict__ Ba,
    const bf16* __restrict__ Wg, const float* __restrict__ Bg,
    bf16* __restrict__ outB) {
  __shared__ __align__(16) short As[128 * 64];
  __shared__ __align__(16) short Was[64 * 64];
  __shared__ __align__(16) short Wgs[64 * 64];
  constexpr int K = 192;
  int tid = threadIdx.x;
  int w = tid >> 6, l = tid & 63;
  int m0 = blockIdx.x * 128, n0 = blockIdx.y * 64;
  int wr = w >> 1, wc = w & 1;
  int lr = l >> 3, lc = l & 7;
  f32x4 accA[4][2], accG[4][2];
#pragma unroll
  for (int i = 0; i < 4; ++i)
#pragma unroll
    for (int j = 0; j < 2; ++j) { accA[i][j] = (f32x4)0.f; accG[i][j] = (f32x4)0.f; }

  for (int kc = 0; kc < K; kc += 64) {
    __syncthreads();
#pragma unroll
    for (int i = 0; i < 4; ++i) {
      int r = w * 32 + i * 8;
      gl_lds16(A + (size_t)(m0 + r + lr) * K + kc + lc * 8, &As[r * 64]);
    }
#pragma unroll
    for (int i = 0; i < 2; ++i) {
      int r = w * 16 + i * 8;
      gl_lds16(Wa + (size_t)(n0 + r + lr) * K + kc + lc * 8, &Was[r * 64]);
      gl_lds16(Wg + (size_t)(n0 + r + lr) * K + kc + lc * 8, &Wgs[r * 64]);
    }
    __syncthreads();
#pragma unroll
    for (int kf = 0; kf < 2; ++kf) {
      short8 af[4], ba[2], bg[2];
#pragma unroll
      for (int mt = 0; mt < 4; ++mt)
        af[mt] = *(const short8*)&As[(wr * 64 + mt * 16 + (l & 15)) * 64 + kf * 32 + (l >> 4) * 8];
#pragma unroll
      for (int nt = 0; nt < 2; ++nt) {
        int rn = (wc * 32 + nt * 16 + (l & 15)) * 64 + kf * 32 + (l >> 4) * 8;
        ba[nt] = *(const short8*)&Was[rn];
        bg[nt] = *(const short8*)&Wgs[rn];
      }
#pragma unroll
      for (int mt = 0; mt < 4; ++mt)
#pragma unroll
        for (int nt = 0; nt < 2; ++nt) {
          accA[mt][nt] = __builtin_amdgcn_mfma_f32_16x16x32_bf16(af[mt], ba[nt], accA[mt][nt], 0, 0, 0);
          accG[mt][nt] = __builtin_amdgcn_mfma_f32_16x16x32_bf16(af[mt], bg[nt], accG[mt][nt], 0, 0, 0);
        }
    }
  }
#pragma unroll
  for (int nt = 0; nt < 2; ++nt) {
    int n = n0 + wc * 32 + nt * 16 + (l & 15);
    float bav = Ba[n], bgv = Bg[n];
#pragma unroll
    for (int mt = 0; mt < 4; ++mt) {
      int mb = m0 + wr * 64 + mt * 16 + (l >> 4) * 4;
#pragma unroll
      for (int r = 0; r < 4; ++r) {
        float av = accA[mt][nt][r] + bav;
        float gv = accG[mt][nt][r] + bgv;
        float tt = sig_(gv);
        float orig = b2f(A[(size_t)(mb + r) * K + n]);
        outB[(size_t)(mb + r) * K + n] = f2b(tt * fmaxf(av, 0.f) + (1.f - tt) * orig);
      }
    }
  }
}

// ---------------------------------------------------------------------------
// K4: LSTM input projection via MFMA. BM=128, BN=128, BK=64, 4 waves 2x2.
// W is PRE-PERMUTED to gate-last row order (row u*4+g), so the natural
// coalesced write produces xg[(t*128+seq)*1024 + dir*512 + u*4 + g].
// ---------------------------------------------------------------------------
__global__ __launch_bounds__(256) void k_pgemm(
    const bf16* __restrict__ A, int K,
    const bf16* __restrict__ W,
    const float* __restrict__ bfw, const float* __restrict__ bbw,
    bf16* __restrict__ xg) {
  __shared__ __align__(16) short As[128 * 64];
  __shared__ __align__(16) short Bs[128 * 64];
  int tid = threadIdx.x;
  int w = tid >> 6, l = tid & 63;
  int m0 = blockIdx.x * 128, n0 = blockIdx.y * 128;
  int wr = w >> 1, wc = w & 1;
  int lr = l >> 3, lc = l & 7;
  f32x4 acc[4][4];
#pragma unroll
  for (int i = 0; i < 4; ++i)
#pragma unroll
    for (int j = 0; j < 4; ++j) acc[i][j] = (f32x4)0.f;

  for (int kc = 0; kc < K; kc += 64) {
    __syncthreads();
#pragma unroll
    for (int i = 0; i < 4; ++i) {
      int r = w * 32 + i * 8;
      gl_lds16(A + (size_t)(m0 + r + lr) * K + kc + lc * 8, &As[r * 64]);
      gl_lds16(W + (size_t)(n0 + r + lr) * K + kc + lc * 8, &Bs[r * 64]);
    }
    __syncthreads();
#pragma unroll
    for (int kf = 0; kf < 2; ++kf) {
      short8 af[4], bfr[4];
#pragma unroll
      for (int mt = 0; mt < 4; ++mt)
        af[mt] = *(const short8*)&As[(wr * 64 + mt * 16 + (l & 15)) * 64 + kf * 32 + (l >> 4) * 8];
#pragma unroll
      for (int nt = 0; nt < 4; ++nt)
        bfr[nt] = *(const short8*)&Bs[(wc * 64 + nt * 16 + (l & 15)) * 64 + kf * 32 + (l >> 4) * 8];
#pragma unroll
      for (int mt = 0; mt < 4; ++mt)
#pragma unroll
        for (int nt = 0; nt < 4; ++nt)
          acc[mt][nt] = __builtin_amdgcn_mfma_f32_16x16x32_bf16(af[mt], bfr[nt], acc[mt][nt], 0, 0, 0);
    }
  }
#pragma unroll
  for (int nt = 0; nt < 4; ++nt) {
    int n = n0 + wc * 64 + nt * 16 + (l & 15);
    int nn = n & 511;
    float bv = ((n < 512) ? bfw : bbw)[(nn & 3) * 128 + (nn >> 2)];
#pragma unroll
    for (int mt = 0; mt < 4; ++mt) {
      int mb = m0 + wr * 64 + mt * 16 + (l >> 4) * 4;
#pragma unroll
      for (int r = 0; r < 4; ++r) {
        int row = mb + r;                                  // seq-major: seq*512+t
        int rp = ((row & 511) << 7) | (row >> 9);          // time-major: t*128+seq
        xg[((size_t)rp << 10) + n] = f2b(acc[mt][nt][r] + bv);
      }
    }
  }
}

// ---------------------------------------------------------------------------
// K5: LSTM recurrence as per-step batched MFMA GEMM.  v6 (unchanged; at its
// structural plateau: 32 MFMA/SIMD/step @ ~16cyc low-occupancy + 10 trans +
// ~350 VALU per step is conserved across all tried mappings).
// ---------------------------------------------------------------------------
__global__ __attribute__((amdgpu_waves_per_eu(1, 1))) __launch_bounds__(256)
void k_rec6(
    const bf16* __restrict__ xg,
    const bf16* __restrict__ whhF, const bf16* __restrict__ whhB,
    bf16* __restrict__ out) {
  constexpr int HS = 160;   // HT row stride in shorts
  int blk = blockIdx.x;
  int dir = blk >> 6;
  int seq0 = (blk & 63) * 2;
  const short* whhs = (const short*)(dir ? whhB : whhF);
  const bool rev = (dir == 1);
  int tid = threadIdx.x;
  int w = tid >> 6, l = tid & 63;
  int ln = l & 15, lk = l >> 4;
  int s = l & 1;                   // my seq (0/1)
  int ut = (l >> 1) & 1;           // my u-subtile
  int r = (l >> 2) & 3;            // my acc row within subtile row-group
  int ul = ut * 16 + lk * 4 + r;   // my u within wave chunk (0..31)
  int u = w * 32 + ul;             // my u (0..127)
  int seq = seq0 + s;

  // whh A-fragments, register-resident. wf[g][ut][kk]: rows g*128+w*32+ut*16+ln
  u32x4 wfu[4][2][4];
#pragma unroll
  for (int g = 0; g < 4; ++g)
#pragma unroll
    for (int t2 = 0; t2 < 2; ++t2)
#pragma unroll
      for (int kk = 0; kk < 4; ++kk) {
        wfu[g][t2][kk] = *(const u32x4*)&whhs[(size_t)(g * 128 + w * 32 + t2 * 16 + ln) * 128 + kk * 32 + lk * 8];
        asm volatile("" : "+v"(wfu[g][t2][kk]));
      }

  __shared__ __align__(16) short HT[2][2][HS];
  for (int i = tid; i < 2 * 2 * HS; i += 256) ((short*)HT)[i] = 0;

  float c = 0.f;

  const bf16* xbase = xg + (size_t)seq * 1024 + dir * 512 + u * 4;
  bf16* obase = out + (size_t)seq * 131072 + (size_t)dir * 128 + u;

  uint2 xA, xB;
  {
    int p0 = rev ? 511 : 0, p1 = rev ? 510 : 1;
    xA = *(const uint2*)(xbase + ((size_t)p0 << 17));
    xB = *(const uint2*)(xbase + ((size_t)p1 << 17));
  }
  __syncthreads();

  auto do_step = [&](int tphys, int tpref, const short* RB, short* WB, uint2& x) {
    // B-fragments: col c of B = h[seq c&1]  (broadcast read of rows 0..1)
    short8 b0 = *(const short8*)&RB[s * HS + 0  + lk * 8];
    short8 b1 = *(const short8*)&RB[s * HS + 32 + lk * 8];
    short8 b2 = *(const short8*)&RB[s * HS + 64 + lk * 8];
    short8 b3 = *(const short8*)&RB[s * HS + 96 + lk * 8];
    uint2 xc = x;
    x = *(const uint2*)(xbase + ((size_t)tpref << 17));   // prefetch t+2
    // Z = whh @ h : 8 independent depth-4 MFMA chains
    f32x4 acc[4][2];
#pragma unroll
    for (int g = 0; g < 4; ++g) { acc[g][0] = (f32x4)0.f; acc[g][1] = (f32x4)0.f; }
#pragma unroll
    for (int g = 0; g < 4; ++g)
#pragma unroll
      for (int t2 = 0; t2 < 2; ++t2) {
        acc[g][t2] = __builtin_amdgcn_mfma_f32_16x16x32_bf16(
            __builtin_bit_cast(short8, wfu[g][t2][0]), b0, acc[g][t2], 0, 0, 0);
        acc[g][t2] = __builtin_amdgcn_mfma_f32_16x16x32_bf16(
            __builtin_bit_cast(short8, wfu[g][t2][1]), b1, acc[g][t2], 0, 0, 0);
        acc[g][t2] = __builtin_amdgcn_mfma_f32_16x16x32_bf16(
            __builtin_bit_cast(short8, wfu[g][t2][2]), b2, acc[g][t2], 0, 0, 0);
        acc[g][t2] = __builtin_amdgcn_mfma_f32_16x16x32_bf16(
            __builtin_bit_cast(short8, wfu[g][t2][3]), b3, acc[g][t2], 0, 0, 0);
      }
    // in-lane select: z[g] = acc[g][ut][r]
    float z[4];
#pragma unroll
    for (int g = 0; g < 4; ++g) {
      f32x4 a0 = acc[g][0], a1 = acc[g][1];
      float p01 = (r & 1) ? a0[1] : a0[0];
      float p23 = (r & 1) ? a0[3] : a0[2];
      float v0 = (r & 2) ? p23 : p01;
      float q01 = (r & 1) ? a1[1] : a1[0];
      float q23 = (r & 1) ? a1[3] : a1[2];
      float v1 = (r & 2) ? q23 : q01;
      z[g] = ut ? v1 : v0;
    }
    float xi = __uint_as_float(xc.x << 16);
    float xf = __uint_as_float(xc.x & 0xffff0000u);
    float xm = __uint_as_float(xc.y << 16);
    float xo = __uint_as_float(xc.y & 0xffff0000u);
    float ig = sig_(z[0] + xi), fg = sig_(z[1] + xf);
    float gv = tanh_(z[2] + xm), og = sig_(z[3] + xo);
    c = fmaf(fg, c, ig * gv);
    float h = og * tanh_(c);
    bf16 hb = f2b(h);
    *(short*)&WB[s * HS + u] = *(short*)&hb;          // h -> HT[nxt] row s
    *(bf16*)(obase + (size_t)tphys * 256) = hb;       // h -> global
  };

  for (int t = 0; t < kS; t += 2) {
    int ta = rev ? 511 - t : t;
    int tb = rev ? 510 - t : t + 1;
    int pa = (t + 2 < kS) ? t + 2 : kS - 1;
    int pb = (t + 3 < kS) ? t + 3 : kS - 1;
    int tpa = rev ? 511 - pa : pa;
    int tpb = rev ? 511 - pb : pb;
    do_step(ta, tpa, &HT[0][0][0], &HT[1][0][0], xA);
    fast_barrier();
    do_step(tb, tpb, &HT[1][0][0], &HT[0][0][0], xB);
    fast_barrier();
  }
}

// ---------------------------------------------------------------------------
// K6: classifier + char mask. out1 bf16 -> em fp32 (or NEG)
// ---------------------------------------------------------------------------
__global__ __launch_bounds__(256) void k_cls(
    const bf16* __restrict__ out1, const float* __restrict__ cls_w,
    const float* __restrict__ cls_b, const int* __restrict__ x,
    float* __restrict__ em) {
  __shared__ float W[17 * 256];
  __shared__ float part[64 * 4 * 17];
  int tid = threadIdx.x;
  for (int i = tid; i < 17 * 256; i += 256) W[i] = cls_w[i];
  __syncthreads();
  int r = tid >> 2, q = tid & 3;
  size_t row = (size_t)blockIdx.x * 64 + r;
  float acc[17];
#pragma unroll
  for (int j = 0; j < 17; ++j) acc[j] = 0.f;
  const uint4* a4p = (const uint4*)(out1 + row * 256 + q * 64);
  for (int i = 0; i < 8; ++i) {
    float f8[8]; unpack8(a4p[i], f8);
#pragma unroll
    for (int j = 0; j < 17; ++j) {
      const float* wr = &W[j * 256 + q * 64 + i * 8];
#pragma unroll
      for (int e = 0; e < 8; ++e) acc[j] = fmaf(f8[e], wr[e], acc[j]);
    }
  }
#pragma unroll
  for (int j = 0; j < 17; ++j) part[(r * 4 + q) * 17 + j] = acc[j];
  __syncthreads();
  for (int idx = tid; idx < 64 * 17; idx += 256) {
    int rr = idx / 17, j = idx % 17;
    size_t row2 = (size_t)blockIdx.x * 64 + rr;
    float v = part[(rr * 4 + 0) * 17 + j] + part[(rr * 4 + 1) * 17 + j] +
              part[(rr * 4 + 2) * 17 + j] + part[(rr * 4 + 3) * 17 + j] + cls_b[j];
    em[row2 * 17 + j] = (x[row2] != 0) ? v : -1e9f;
  }
}

// ---------------------------------------------------------------------------
// K7: CRF loss per sequence (1 wave / block).  v2.
// Forward-recursion trans count halved: tag j is split over lane pair
// (2j, 2j+1); each lane handles 9 (or 8) source-tags i, combined via
// shfl_xor(1). 9 exp + 1 log per t (was 17 + 1). al double-buffered
// (al[2][20], pads at 17..19 = -1e30) -> one barrier per t.
// ---------------------------------------------------------------------------
__global__ __launch_bounds__(64) void k_crf(
    const float* __restrict__ em, const int* __restrict__ tags,
    const float* __restrict__ mask, const float* __restrict__ trans,
    const float* __restrict__ start_t, const float* __restrict__ end_t,
    float* __restrict__ res) {
  int b = blockIdx.x;
  int lane = threadIdx.x;
  const float* emB = em + (size_t)b * kS * 17;
  const int* tg = tags + b * kS;
  const float* mk = mask + b * kS;
  int j = lane >> 1, iq = lane & 1;
  bool actj = (j < 17);

  // my half of the transition column for next-tag j: i = iq*9 + idx
  float tch[9];
#pragma unroll
  for (int idx = 0; idx < 9; ++idx) {
    int i = iq * 9 + idx;
    tch[idx] = (actj && i < 17) ? trans[i * 17 + j] : -1e30f;
  }

  // gold-path score + mask sum (lane-strided, shuffle-reduced)
  float sc = 0.f, msum = 0.f;
  for (int t = lane; t < kS; t += 64) msum += mk[t];
  for (int t = 1 + lane; t < kS; t += 64)
    sc += (trans[tg[t - 1] * 17 + tg[t]] + emB[(size_t)t * 17 + tg[t]]) * mk[t];
#pragma unroll
  for (int o = 32; o; o >>= 1) { sc += __shfl_xor(sc, o); msum += __shfl_xor(msum, o); }

  __shared__ float al[2][20];
  if (lane < 17) al[0][lane] = start_t[lane] + emB[lane];
  if (lane >= 17 && lane < 20) { al[0][lane] = -1e30f; al[1][lane] = -1e30f; }
  __syncthreads();

  int cur = 0;
  for (int t = 1; t < kS; ++t) {
    float v[9];
    float mxh = -3.4e38f;
#pragma unroll
    for (int idx = 0; idx < 9; ++idx) {
      v[idx] = al[cur][iq * 9 + idx] + tch[idx];    // pads make invalid i harmless
      mxh = fmaxf(mxh, v[idx]);
    }
    float mx = fmaxf(mxh, __shfl_xor(mxh, 1));
    float sh = 0.f;
#pragma unroll
    for (int idx = 0; idx < 9; ++idx) sh += __expf(v[idx] - mx);
    float ssum = sh + __shfl_xor(sh, 1);
    if (actj && iq == 0) {
      float m = mk[t];
      float nxt = (mx + __logf(ssum) + emB[(size_t)t * 17 + j]) * m + al[cur][j] * (1.f - m);
      al[cur ^ 1][j] = nxt;
    }
    __syncthreads();
    cur ^= 1;
  }

  float val = (lane < 17) ? al[cur][lane] + end_t[lane] : -3.4e38f;
  float mx = val;
#pragma unroll
  for (int o = 32; o; o >>= 1) mx = fmaxf(mx, __shfl_xor(mx, o));
  float s = (lane < 17) ? __expf(val - mx) : 0.f;
#pragma unroll
  for (int o = 32; o; o >>= 1) s += __shfl_xor(s, o);
  float logZ = mx + __logf(s);
  if (lane == 0) {
    float score = sc + start_t[tg[0]] + emB[tg[0]];
    int last_real = (int)(msum + 0.5f) - 1;
    if (last_real >= 0) score += end_t[tg[last_real]];
    res[b] = logZ - score;
  }
}

// K8: deterministic mean over 128 sequences -> d_out[0]
__global__ void k_loss(const float* __restrict__ res, float* __restrict__ out) {
  __shared__ float s[128];
  int tid = threadIdx.x;
  s[tid] = res[tid];
  __syncthreads();
  for (int off = 64; off; off >>= 1) {
    if (tid < off) s[tid] += s[tid + off];
    __syncthreads();
  }
  if (tid == 0) out[0] = s[0] / 128.f;
}

}  // namespace

extern "C" void kernel_launch(void* const* d_in, const int* in_sizes, int n_in,
                              void* d_out, int out_size, void* d_ws, size_t ws_size,
                              hipStream_t stream) {
  (void)in_sizes; (void)n_in; (void)out_size; (void)ws_size;
  const int*   x       = (const int*)  d_in[0];
  const int*   tags    = (const int*)  d_in[1];
  const float* mask    = (const float*)d_in[2];
  const float* emb     = (const float*)d_in[3];
  const float* cw3     = (const float*)d_in[4];
  const float* cb3     = (const float*)d_in[5];
  const float* cw5     = (const float*)d_in[6];
  const float* cb5     = (const float*)d_in[7];
  const float* cw7     = (const float*)d_in[8];
  const float* cb7     = (const float*)d_in[9];
  const float* hw_w    = (const float*)d_in[10];
  const float* hw_b    = (const float*)d_in[11];
  const float* hwg_w   = (const float*)d_in[12];
  const float* hwg_b   = (const float*)d_in[13];
  const float* wih0f   = (const float*)d_in[14];
  const float* whh0f   = (const float*)d_in[15];
  const float* b0f     = (const float*)d_in[16];
  const float* wih0b   = (const float*)d_in[17];
  const float* whh0b   = (const float*)d_in[18];
  const float* b0b     = (const float*)d_in[19];
  const float* wih1f   = (const float*)d_in[20];
  const float* whh1f   = (const float*)d_in[21];
  const float* b1f     = (const float*)d_in[22];
  const float* wih1b   = (const float*)d_in[23];
  const float* whh1b   = (const float*)d_in[24];
  const float* b1b     = (const float*)d_in[25];
  const float* cls_w   = (const float*)d_in[26];
  const float* cls_b   = (const float*)d_in[27];
  const float* trans   = (const float*)d_in[28];
  const float* start_t = (const float*)d_in[29];
  const float* end_t   = (const float*)d_in[30];

  // Workspace layout. tbl fp32 | bf16 weights | bf16 activations. ~210 MB.
  char* ws = (char*)d_ws;
  const size_t OFF_W0 = 393216;                            // tbl is [0, 372KB)
  const size_t OFF_W1 = OFF_W0 + (size_t)1024 * 192 * 2;
  const size_t OFF_WA = OFF_W1 + (size_t)1024 * 256 * 2;
  const size_t OFF_WG = OFF_WA + (size_t)192 * 192 * 2;
  const size_t OFF_WH = OFF_WG + (size_t)192 * 192 * 2;    // 4x whh bf16 (512KB)
  const size_t OFF_A  = OFF_WH + (size_t)4 * 512 * 128 * 2;
  const size_t SZ_A   = (size_t)kM * 192 * 2;              // 24 MB
  const size_t OFF_B  = OFF_A + SZ_A;
  const size_t OFF_O0 = OFF_B + SZ_A;                      // out0 bf16 (32MB); em fp32 later
  const size_t OFF_XG = OFF_O0 + (size_t)kM * 256 * 2;     // xg bf16 dual (128MB)
  float* tbl  = (float*)ws;
  bf16*  W0b  = (bf16*)(ws + OFF_W0);
  bf16*  W1b  = (bf16*)(ws + OFF_W1);
  bf16*  WAb  = (bf16*)(ws + OFF_WA);
  bf16*  WGb  = (bf16*)(ws + OFF_WG);
  bf16*  WHb  = (bf16*)(ws + OFF_WH);
  bf16*  bufA = (bf16*)(ws + OFF_A);
  bf16*  bufB = (bf16*)(ws + OFF_B);
  bf16*  out0 = (bf16*)(ws + OFF_O0);
  bf16*  out1 = (bf16*)(ws + OFF_A);                       // bufA/bufB dead by rec1
  bf16*  xg   = (bf16*)(ws + OFF_XG);
  float* em   = (float*)(ws + OFF_O0);                     // out0 dead after proj1
  float* resv = (float*)(ws + OFF_O0 + (size_t)kM * 17 * 4);

  // fused weight conversion + char-projection-table prepass
  k_wprep<<<3468, 256, 0, stream>>>(wih0f, wih0b, wih1f, wih1b, hw_w, hwg_w,
                                    whh0f, whh0b, whh1f, whh1b,
                                    emb, cw3, cw5, cw7,
                                    W0b, W1b, WAb, WGb, WHb, tbl);

  k_conv<<<kB * (kS / 64), 192, 0, stream>>>(x, tbl, cb3, cb5, cb7, bufA);
  k_hw<<<dim3(kM / 128, 3), 256, 0, stream>>>(bufA, WAb, hw_b, WGb, hwg_b, bufB);

  k_pgemm<<<dim3(kM / 128, 8), 256, 0, stream>>>(bufB, 192, W0b, b0f, b0b, xg);
  k_rec6<<<128, 256, 0, stream>>>(xg, WHb + 0 * 65536, WHb + 1 * 65536, out0);
  k_pgemm<<<dim3(kM / 128, 8), 256, 0, stream>>>(out0, 256, W1b, b1f, b1b, xg);
  k_rec6<<<128, 256, 0, stream>>>(xg, WHb + 2 * 65536, WHb + 3 * 65536, out1);

  k_cls<<<kM / 64, 256, 0, stream>>>(out1, cls_w, cls_b, x, em);
  k_crf<<<kB, 64, 0, stream>>>(em, tags, mask, trans, start_t, end_t, resv);
  k_loss<<<1, 128, 0, stream>>>(resv, (float*)d_out);
}

// Round 15
// 984.006 us; speedup vs baseline: 1.2976x; 1.0011x over previous
//
#include <hip/hip_runtime.h>
#include <hip/hip_bf16.h>
#include <cstdint>
#include <cstddef>

namespace {

constexpr int kB = 128;
constexpr int kS = 512;
constexpr int kM = kB * kS;   // 65536 rows

typedef __hip_bfloat16 bf16;
typedef __attribute__((ext_vector_type(8))) short short8;
typedef __attribute__((ext_vector_type(4))) float f32x4;
typedef __attribute__((ext_vector_type(4))) unsigned int u32x4;

__device__ __forceinline__ float sig_(float x) {
  return __builtin_amdgcn_rcpf(1.f + __expf(-x));
}
__device__ __forceinline__ float tanh_(float x) {
  return 1.f - 2.f * __builtin_amdgcn_rcpf(__expf(2.f * x) + 1.f);
}
__device__ __forceinline__ float b2f(bf16 h) { return __bfloat162float(h); }
__device__ __forceinline__ bf16 f2b(float f) { return __float2bfloat16(f); }

// unpack 8 bf16 (one uint4) -> 8 floats
__device__ __forceinline__ void unpack8(uint4 v, float* o) {
  o[0] = __uint_as_float(v.x << 16); o[1] = __uint_as_float(v.x & 0xffff0000u);
  o[2] = __uint_as_float(v.y << 16); o[3] = __uint_as_float(v.y & 0xffff0000u);
  o[4] = __uint_as_float(v.z << 16); o[5] = __uint_as_float(v.z & 0xffff0000u);
  o[6] = __uint_as_float(v.w << 16); o[7] = __uint_as_float(v.w & 0xffff0000u);
}

__device__ __forceinline__ void gl_lds16(const void* g, void* l) {
  __builtin_amdgcn_global_load_lds((const __attribute__((address_space(1))) void*)g,
                                   (__attribute__((address_space(3))) void*)l, 16, 0, 0);
}

// lgkmcnt-only barrier (no vmcnt drain). Proven correct rounds 11-14.
__device__ __forceinline__ void fast_barrier() {
  __builtin_amdgcn_sched_barrier(0);
  asm volatile("s_waitcnt lgkmcnt(0)" ::: "memory");
  __builtin_amdgcn_s_barrier();
  __builtin_amdgcn_sched_barrier(0);
}

// ---------------------------------------------------------------------------
// K0: fused weight prep + char projection table. Regions by blockIdx:
//  [0,384)     wih0f -> W0b          (K=192, gate-last row perm)
//  [384,768)   wih0b -> W0b+98304
//  [768,1280)  wih1f -> W1b          (K=256, perm)
//  [1280,1792) wih1b -> W1b+131072
//  [1792,1936) hw_w -> WAb   [1936,2080) hwg_w -> WGb   (linear)
//  [2080,3104) whh_i -> WHb+i*65536  (linear, 256 blocks each)
//  [3104,3468) char table: tbl[(tap*97+ch)*64+f] = sum_c emb[ch][c]*W_k[f][c][dk]
// ---------------------------------------------------------------------------
__global__ void k_wprep(const float* __restrict__ wih0f, const float* __restrict__ wih0b,
                        const float* __restrict__ wih1f, const float* __restrict__ wih1b,
                        const float* __restrict__ hw_w, const float* __restrict__ hwg_w,
                        const float* __restrict__ whh0f, const float* __restrict__ whh0b,
                        const float* __restrict__ whh1f, const float* __restrict__ whh1b,
                        const float* __restrict__ emb, const float* __restrict__ cw3,
                        const float* __restrict__ cw5, const float* __restrict__ cw7,
                        bf16* __restrict__ W0b, bf16* __restrict__ W1b,
                        bf16* __restrict__ WAb, bf16* __restrict__ WGb,
                        bf16* __restrict__ WHb, float* __restrict__ tbl) {
  int b = blockIdx.x, t = threadIdx.x;
  if (b < 768) {
    const float* s = (b < 384) ? wih0f : wih0b;
    bf16* d = W0b + (b < 384 ? 0 : 98304);
    int i = (b & 383) * 256 + t;
    int n = i / 192, k = i - n * 192;
    d[i] = f2b(s[((n & 3) * 128 + (n >> 2)) * 192 + k]);
  } else if (b < 1792) {
    int bb = b - 768;
    const float* s = (bb < 512) ? wih1f : wih1b;
    bf16* d = W1b + (bb < 512 ? 0 : 131072);
    int i = (bb & 511) * 256 + t;
    int n = i >> 8, k = i & 255;
    d[i] = f2b(s[((n & 3) * 128 + (n >> 2)) * 256 + k]);
  } else if (b < 2080) {
    int bb = b - 1792;
    const float* s = (bb < 144) ? hw_w : hwg_w;
    bf16* d = (bb < 144) ? WAb : WGb;
    int i = (bb % 144) * 256 + t;
    d[i] = f2b(s[i]);
  } else if (b < 3104) {
    int bb = b - 2080;
    int which = bb >> 8;
    const float* s = (which == 0) ? whh0f : (which == 1) ? whh0b : (which == 2) ? whh1f : whh1b;
    int i = (bb & 255) * 256 + t;
    WHb[which * 65536 + i] = f2b(s[i]);
  } else {
    int idx = (b - 3104) * 256 + t;         // (e, f) pair: e < 15*97 = 1455
    int e = idx >> 6, f = idx & 63;
    if (e < 15 * 97) {
      int tap = e / 97, ch = e % 97;
      const float* w; int kk, dk;
      if (tap < 3)      { w = cw3; kk = 3; dk = tap; }
      else if (tap < 8) { w = cw5; kk = 5; dk = tap - 3; }
      else              { w = cw7; kk = 7; dk = tap - 8; }
      const float* er = emb + ch * 128;
      float s = 0.f;
      for (int c = 0; c < 128; ++c) s = fmaf(er[c], w[(f * 128 + c) * kk + dk], s);
      tbl[(size_t)e * 64 + f] = s;
    }
  }
}

// ---------------------------------------------------------------------------
// K2: conv via table gathers + bias + relu -> bf16 (B*S, 192)
// ---------------------------------------------------------------------------
__global__ void k_conv(const int* __restrict__ x, const float* __restrict__ tbl,
                       const float* __restrict__ cb3, const float* __restrict__ cb5,
                       const float* __restrict__ cb7, bf16* __restrict__ outA) {
  __shared__ int chs[70];
  int b = blockIdx.x >> 3;
  int s0 = (blockIdx.x & 7) << 6;
  int tid = threadIdx.x;
  if (tid < 70) {
    int g = s0 - 3 + tid;
    chs[tid] = (g >= 0 && g < kS) ? x[b * kS + g] : 0;   // char 0 => zero row
  }
  __syncthreads();
  int wv = tid >> 6;
  int f = tid & 63;
  int ntap, tap0, half; const float* cb;
  if (wv == 0)      { ntap = 3; tap0 = 0; half = 1; cb = cb3; }
  else if (wv == 1) { ntap = 5; tap0 = 3; half = 2; cb = cb5; }
  else              { ntap = 7; tap0 = 8; half = 3; cb = cb7; }
  float bias = cb[f];
  for (int p = 0; p < 64; ++p) {
    float acc = bias;
    for (int dk = 0; dk < ntap; ++dk) {
      int c = chs[p + 3 - half + dk];
      acc += tbl[(size_t)((tap0 + dk) * 97 + c) * 64 + f];
    }
    outA[(size_t)(b * kS + s0 + p) * 192 + wv * 64 + f] = f2b(fmaxf(acc, 0.f));
  }
}

// ---------------------------------------------------------------------------
// K3: highway via MFMA, fused dual GEMM (Wa and Wg in one pass).
// Grid TRANSPOSED: x = N-block (3), y = M-strip (512) so consecutive blocks
// share the A-strip while it is L2-hot.
// ---------------------------------------------------------------------------
__global__ __launch_bounds__(256) void k_hw(
    const bf16* __restrict__ A,
    const bf16* __restrict__ Wa, const float* __restrict__ Ba,
    const bf16* __restrict__ Wg, const float* __restrict__ Bg,
    bf16* __restrict__ outB) {
  __shared__ __align__(16) short As[128 * 64];
  __shared__ __align__(16) short Was[64 * 64];
  __shared__ __align__(16) short Wgs[64 * 64];
  constexpr int K = 192;
  int tid = threadIdx.x;
  int w = tid >> 6, l = tid & 63;
  int m0 = blockIdx.y * 128, n0 = blockIdx.x * 64;
  int wr = w >> 1, wc = w & 1;
  int lr = l >> 3, lc = l & 7;
  f32x4 accA[4][2], accG[4][2];
#pragma unroll
  for (int i = 0; i < 4; ++i)
#pragma unroll
    for (int j = 0; j < 2; ++j) { accA[i][j] = (f32x4)0.f; accG[i][j] = (f32x4)0.f; }

  for (int kc = 0; kc < K; kc += 64) {
    __syncthreads();
#pragma unroll
    for (int i = 0; i < 4; ++i) {
      int r = w * 32 + i * 8;
      gl_lds16(A + (size_t)(m0 + r + lr) * K + kc + lc * 8, &As[r * 64]);
    }
#pragma unroll
    for (int i = 0; i < 2; ++i) {
      int r = w * 16 + i * 8;
      gl_lds16(Wa + (size_t)(n0 + r + lr) * K + kc + lc * 8, &Was[r * 64]);
      gl_lds16(Wg + (size_t)(n0 + r + lr) * K + kc + lc * 8, &Wgs[r * 64]);
    }
    __syncthreads();
#pragma unroll
    for (int kf = 0; kf < 2; ++kf) {
      short8 af[4], ba[2], bg[2];
#pragma unroll
      for (int mt = 0; mt < 4; ++mt)
        af[mt] = *(const short8*)&As[(wr * 64 + mt * 16 + (l & 15)) * 64 + kf * 32 + (l >> 4) * 8];
#pragma unroll
      for (int nt = 0; nt < 2; ++nt) {
        int rn = (wc * 32 + nt * 16 + (l & 15)) * 64 + kf * 32 + (l >> 4) * 8;
        ba[nt] = *(const short8*)&Was[rn];
        bg[nt] = *(const short8*)&Wgs[rn];
      }
#pragma unroll
      for (int mt = 0; mt < 4; ++mt)
#pragma unroll
        for (int nt = 0; nt < 2; ++nt) {
          accA[mt][nt] = __builtin_amdgcn_mfma_f32_16x16x32_bf16(af[mt], ba[nt], accA[mt][nt], 0, 0, 0);
          accG[mt][nt] = __builtin_amdgcn_mfma_f32_16x16x32_bf16(af[mt], bg[nt], accG[mt][nt], 0, 0, 0);
        }
    }
  }
#pragma unroll
  for (int nt = 0; nt < 2; ++nt) {
    int n = n0 + wc * 32 + nt * 16 + (l & 15);
    float bav = Ba[n], bgv = Bg[n];
#pragma unroll
    for (int mt = 0; mt < 4; ++mt) {
      int mb = m0 + wr * 64 + mt * 16 + (l >> 4) * 4;
#pragma unroll
      for (int r = 0; r < 4; ++r) {
        float av = accA[mt][nt][r] + bav;
        float gv = accG[mt][nt][r] + bgv;
        float tt = sig_(gv);
        float orig = b2f(A[(size_t)(mb + r) * K + n]);
        outB[(size_t)(mb + r) * K + n] = f2b(tt * fmaxf(av, 0.f) + (1.f - tt) * orig);
      }
    }
  }
}

// ---------------------------------------------------------------------------
// K4: LSTM input projection via MFMA. BM=128, BN=128, BK=64, 4 waves 2x2.
// W PRE-PERMUTED to gate-last row order. Grid TRANSPOSED: x = N-block (8),
// y = M-strip (512) for A-strip L2 locality across consecutive blocks.
// ---------------------------------------------------------------------------
__global__ __launch_bounds__(256) void k_pgemm(
    const bf16* __restrict__ A, int K,
    const bf16* __restrict__ W,
    const float* __restrict__ bfw, const float* __restrict__ bbw,
    bf16* __restrict__ xg) {
  __shared__ __align__(16) short As[128 * 64];
  __shared__ __align__(16) short Bs[128 * 64];
  int tid = threadIdx.x;
  int w = tid >> 6, l = tid & 63;
  int m0 = blockIdx.y * 128, n0 = blockIdx.x * 128;
  int wr = w >> 1, wc = w & 1;
  int lr = l >> 3, lc = l & 7;
  f32x4 acc[4][4];
#pragma unroll
  for (int i = 0; i < 4; ++i)
#pragma unroll
    for (int j = 0; j < 4; ++j) acc[i][j] = (f32x4)0.f;

  for (int kc = 0; kc < K; kc += 64) {
    __syncthreads();
#pragma unroll
    for (int i = 0; i < 4; ++i) {
      int r = w * 32 + i * 8;
      gl_lds16(A + (size_t)(m0 + r + lr) * K + kc + lc * 8, &As[r * 64]);
      gl_lds16(W + (size_t)(n0 + r + lr) * K + kc + lc * 8, &Bs[r * 64]);
    }
    __syncthreads();
#pragma unroll
    for (int kf = 0; kf < 2; ++kf) {
      short8 af[4], bfr[4];
#pragma unroll
      for (int mt = 0; mt < 4; ++mt)
        af[mt] = *(const short8*)&As[(wr * 64 + mt * 16 + (l & 15)) * 64 + kf * 32 + (l >> 4) * 8];
#pragma unroll
      for (int nt = 0; nt < 4; ++nt)
        bfr[nt] = *(const short8*)&Bs[(wc * 64 + nt * 16 + (l & 15)) * 64 + kf * 32 + (l >> 4) * 8];
#pragma unroll
      for (int mt = 0; mt < 4; ++mt)
#pragma unroll
        for (int nt = 0; nt < 4; ++nt)
          acc[mt][nt] = __builtin_amdgcn_mfma_f32_16x16x32_bf16(af[mt], bfr[nt], acc[mt][nt], 0, 0, 0);
    }
  }
#pragma unroll
  for (int nt = 0; nt < 4; ++nt) {
    int n = n0 + wc * 64 + nt * 16 + (l & 15);
    int nn = n & 511;
    float bv = ((n < 512) ? bfw : bbw)[(nn & 3) * 128 + (nn >> 2)];
#pragma unroll
    for (int mt = 0; mt < 4; ++mt) {
      int mb = m0 + wr * 64 + mt * 16 + (l >> 4) * 4;
#pragma unroll
      for (int r = 0; r < 4; ++r) {
        int row = mb + r;                                  // seq-major: seq*512+t
        int rp = ((row & 511) << 7) | (row >> 9);          // time-major: t*128+seq
        xg[((size_t)rp << 10) + n] = f2b(acc[mt][nt][r] + bv);
      }
    }
  }
}

// ---------------------------------------------------------------------------
// K5: LSTM recurrence as per-step batched MFMA GEMM.  v6 (unchanged; at its
// structural plateau: 32 MFMA/SIMD/step + 10 trans + ~350 VALU per step is
// conserved across all tried mappings).
// ---------------------------------------------------------------------------
__global__ __attribute__((amdgpu_waves_per_eu(1, 1))) __launch_bounds__(256)
void k_rec6(
    const bf16* __restrict__ xg,
    const bf16* __restrict__ whhF, const bf16* __restrict__ whhB,
    bf16* __restrict__ out) {
  constexpr int HS = 160;   // HT row stride in shorts
  int blk = blockIdx.x;
  int dir = blk >> 6;
  int seq0 = (blk & 63) * 2;
  const short* whhs = (const short*)(dir ? whhB : whhF);
  const bool rev = (dir == 1);
  int tid = threadIdx.x;
  int w = tid >> 6, l = tid & 63;
  int ln = l & 15, lk = l >> 4;
  int s = l & 1;                   // my seq (0/1)
  int ut = (l >> 1) & 1;           // my u-subtile
  int r = (l >> 2) & 3;            // my acc row within subtile row-group
  int ul = ut * 16 + lk * 4 + r;   // my u within wave chunk (0..31)
  int u = w * 32 + ul;             // my u (0..127)
  int seq = seq0 + s;

  // whh A-fragments, register-resident. wf[g][ut][kk]: rows g*128+w*32+ut*16+ln
  u32x4 wfu[4][2][4];
#pragma unroll
  for (int g = 0; g < 4; ++g)
#pragma unroll
    for (int t2 = 0; t2 < 2; ++t2)
#pragma unroll
      for (int kk = 0; kk < 4; ++kk) {
        wfu[g][t2][kk] = *(const u32x4*)&whhs[(size_t)(g * 128 + w * 32 + t2 * 16 + ln) * 128 + kk * 32 + lk * 8];
        asm volatile("" : "+v"(wfu[g][t2][kk]));
      }

  __shared__ __align__(16) short HT[2][2][HS];
  for (int i = tid; i < 2 * 2 * HS; i += 256) ((short*)HT)[i] = 0;

  float c = 0.f;

  const bf16* xbase = xg + (size_t)seq * 1024 + dir * 512 + u * 4;
  bf16* obase = out + (size_t)seq * 131072 + (size_t)dir * 128 + u;

  uint2 xA, xB;
  {
    int p0 = rev ? 511 : 0, p1 = rev ? 510 : 1;
    xA = *(const uint2*)(xbase + ((size_t)p0 << 17));
    xB = *(const uint2*)(xbase + ((size_t)p1 << 17));
  }
  __syncthreads();

  auto do_step = [&](int tphys, int tpref, const short* RB, short* WB, uint2& x) {
    // B-fragments: col c of B = h[seq c&1]  (broadcast read of rows 0..1)
    short8 b0 = *(const short8*)&RB[s * HS + 0  + lk * 8];
    short8 b1 = *(const short8*)&RB[s * HS + 32 + lk * 8];
    short8 b2 = *(const short8*)&RB[s * HS + 64 + lk * 8];
    short8 b3 = *(const short8*)&RB[s * HS + 96 + lk * 8];
    uint2 xc = x;
    x = *(const uint2*)(xbase + ((size_t)tpref << 17));   // prefetch t+2
    // Z = whh @ h : 8 independent depth-4 MFMA chains
    f32x4 acc[4][2];
#pragma unroll
    for (int g = 0; g < 4; ++g) { acc[g][0] = (f32x4)0.f; acc[g][1] = (f32x4)0.f; }
#pragma unroll
    for (int g = 0; g < 4; ++g)
#pragma unroll
      for (int t2 = 0; t2 < 2; ++t2) {
        acc[g][t2] = __builtin_amdgcn_mfma_f32_16x16x32_bf16(
            __builtin_bit_cast(short8, wfu[g][t2][0]), b0, acc[g][t2], 0, 0, 0);
        acc[g][t2] = __builtin_amdgcn_mfma_f32_16x16x32_bf16(
            __builtin_bit_cast(short8, wfu[g][t2][1]), b1, acc[g][t2], 0, 0, 0);
        acc[g][t2] = __builtin_amdgcn_mfma_f32_16x16x32_bf16(
            __builtin_bit_cast(short8, wfu[g][t2][2]), b2, acc[g][t2], 0, 0, 0);
        acc[g][t2] = __builtin_amdgcn_mfma_f32_16x16x32_bf16(
            __builtin_bit_cast(short8, wfu[g][t2][3]), b3, acc[g][t2], 0, 0, 0);
      }
    // in-lane select: z[g] = acc[g][ut][r]
    float z[4];
#pragma unroll
    for (int g = 0; g < 4; ++g) {
      f32x4 a0 = acc[g][0], a1 = acc[g][1];
      float p01 = (r & 1) ? a0[1] : a0[0];
      float p23 = (r & 1) ? a0[3] : a0[2];
      float v0 = (r & 2) ? p23 : p01;
      float q01 = (r & 1) ? a1[1] : a1[0];
      float q23 = (r & 1) ? a1[3] : a1[2];
      float v1 = (r & 2) ? q23 : q01;
      z[g] = ut ? v1 : v0;
    }
    float xi = __uint_as_float(xc.x << 16);
    float xf = __uint_as_float(xc.x & 0xffff0000u);
    float xm = __uint_as_float(xc.y << 16);
    float xo = __uint_as_float(xc.y & 0xffff0000u);
    float ig = sig_(z[0] + xi), fg = sig_(z[1] + xf);
    float gv = tanh_(z[2] + xm), og = sig_(z[3] + xo);
    c = fmaf(fg, c, ig * gv);
    float h = og * tanh_(c);
    bf16 hb = f2b(h);
    *(short*)&WB[s * HS + u] = *(short*)&hb;          // h -> HT[nxt] row s
    *(bf16*)(obase + (size_t)tphys * 256) = hb;       // h -> global
  };

  for (int t = 0; t < kS; t += 2) {
    int ta = rev ? 511 - t : t;
    int tb = rev ? 510 - t : t + 1;
    int pa = (t + 2 < kS) ? t + 2 : kS - 1;
    int pb = (t + 3 < kS) ? t + 3 : kS - 1;
    int tpa = rev ? 511 - pa : pa;
    int tpb = rev ? 511 - pb : pb;
    do_step(ta, tpa, &HT[0][0][0], &HT[1][0][0], xA);
    fast_barrier();
    do_step(tb, tpb, &HT[1][0][0], &HT[0][0][0], xB);
    fast_barrier();
  }
}

// ---------------------------------------------------------------------------
// K6: classifier + char mask, 128 rows/block (W-load amortized over 2 halves).
// ---------------------------------------------------------------------------
__global__ __launch_bounds__(256) void k_cls(
    const bf16* __restrict__ out1, const float* __restrict__ cls_w,
    const float* __restrict__ cls_b, const int* __restrict__ x,
    float* __restrict__ em) {
  __shared__ float W[17 * 256];
  __shared__ float part[64 * 4 * 17];
  int tid = threadIdx.x;
  for (int i = tid; i < 17 * 256; i += 256) W[i] = cls_w[i];
  __syncthreads();
  int r = tid >> 2, q = tid & 3;
  for (int half = 0; half < 2; ++half) {
    size_t row = (size_t)blockIdx.x * 128 + half * 64 + r;
    float acc[17];
#pragma unroll
    for (int j = 0; j < 17; ++j) acc[j] = 0.f;
    const uint4* a4p = (const uint4*)(out1 + row * 256 + q * 64);
    for (int i = 0; i < 8; ++i) {
      float f8[8]; unpack8(a4p[i], f8);
#pragma unroll
      for (int j = 0; j < 17; ++j) {
        const float* wr = &W[j * 256 + q * 64 + i * 8];
#pragma unroll
        for (int e = 0; e < 8; ++e) acc[j] = fmaf(f8[e], wr[e], acc[j]);
      }
    }
#pragma unroll
    for (int j = 0; j < 17; ++j) part[(r * 4 + q) * 17 + j] = acc[j];
    __syncthreads();
    for (int idx = tid; idx < 64 * 17; idx += 256) {
      int rr = idx / 17, j = idx % 17;
      size_t row2 = (size_t)blockIdx.x * 128 + half * 64 + rr;
      float v = part[(rr * 4 + 0) * 17 + j] + part[(rr * 4 + 1) * 17 + j] +
                part[(rr * 4 + 2) * 17 + j] + part[(rr * 4 + 3) * 17 + j] + cls_b[j];
      em[row2 * 17 + j] = (x[row2] != 0) ? v : -1e9f;
    }
    __syncthreads();
  }
}

// ---------------------------------------------------------------------------
// K7: CRF loss per sequence (1 wave / block).  v2 (lane-pair split logsumexp).
// ---------------------------------------------------------------------------
__global__ __launch_bounds__(64) void k_crf(
    const float* __restrict__ em, const int* __restrict__ tags,
    const float* __restrict__ mask, const float* __restrict__ trans,
    const float* __restrict__ start_t, const float* __restrict__ end_t,
    float* __restrict__ res) {
  int b = blockIdx.x;
  int lane = threadIdx.x;
  const float* emB = em + (size_t)b * kS * 17;
  const int* tg = tags + b * kS;
  const float* mk = mask + b * kS;
  int j = lane >> 1, iq = lane & 1;
  bool actj = (j < 17);

  float tch[9];
#pragma unroll
  for (int idx = 0; idx < 9; ++idx) {
    int i = iq * 9 + idx;
    tch[idx] = (actj && i < 17) ? trans[i * 17 + j] : -1e30f;
  }

  float sc = 0.f, msum = 0.f;
  for (int t = lane; t < kS; t += 64) msum += mk[t];
  for (int t = 1 + lane; t < kS; t += 64)
    sc += (trans[tg[t - 1] * 17 + tg[t]] + emB[(size_t)t * 17 + tg[t]]) * mk[t];
#pragma unroll
  for (int o = 32; o; o >>= 1) { sc += __shfl_xor(sc, o); msum += __shfl_xor(msum, o); }

  __shared__ float al[2][20];
  if (lane < 17) al[0][lane] = start_t[lane] + emB[lane];
  if (lane >= 17 && lane < 20) { al[0][lane] = -1e30f; al[1][lane] = -1e30f; }
  __syncthreads();

  int cur = 0;
  for (int t = 1; t < kS; ++t) {
    float v[9];
    float mxh = -3.4e38f;
#pragma unroll
    for (int idx = 0; idx < 9; ++idx) {
      v[idx] = al[cur][iq * 9 + idx] + tch[idx];
      mxh = fmaxf(mxh, v[idx]);
    }
    float mx = fmaxf(mxh, __shfl_xor(mxh, 1));
    float sh = 0.f;
#pragma unroll
    for (int idx = 0; idx < 9; ++idx) sh += __expf(v[idx] - mx);
    float ssum = sh + __shfl_xor(sh, 1);
    if (actj && iq == 0) {
      float m = mk[t];
      float nxt = (mx + __logf(ssum) + emB[(size_t)t * 17 + j]) * m + al[cur][j] * (1.f - m);
      al[cur ^ 1][j] = nxt;
    }
    __syncthreads();
    cur ^= 1;
  }

  float val = (lane < 17) ? al[cur][lane] + end_t[lane] : -3.4e38f;
  float mx = val;
#pragma unroll
  for (int o = 32; o; o >>= 1) mx = fmaxf(mx, __shfl_xor(mx, o));
  float s = (lane < 17) ? __expf(val - mx) : 0.f;
#pragma unroll
  for (int o = 32; o; o >>= 1) s += __shfl_xor(s, o);
  float logZ = mx + __logf(s);
  if (lane == 0) {
    float score = sc + start_t[tg[0]] + emB[tg[0]];
    int last_real = (int)(msum + 0.5f) - 1;
    if (last_real >= 0) score += end_t[tg[last_real]];
    res[b] = logZ - score;
  }
}

// K8: deterministic mean over 128 sequences -> d_out[0]
__global__ void k_loss(const float* __restrict__ res, float* __restrict__ out) {
  __shared__ float s[128];
  int tid = threadIdx.x;
  s[tid] = res[tid];
  __syncthreads();
  for (int off = 64; off; off >>= 1) {
    if (tid < off) s[tid] += s[tid + off];
    __syncthreads();
  }
  if (tid == 0) out[0] = s[0] / 128.f;
}

}  // namespace

extern "C" void kernel_launch(void* const* d_in, const int* in_sizes, int n_in,
                              void* d_out, int out_size, void* d_ws, size_t ws_size,
                              hipStream_t stream) {
  (void)in_sizes; (void)n_in; (void)out_size; (void)ws_size;
  const int*   x       = (const int*)  d_in[0];
  const int*   tags    = (const int*)  d_in[1];
  const float* mask    = (const float*)d_in[2];
  const float* emb     = (const float*)d_in[3];
  const float* cw3     = (const float*)d_in[4];
  const float* cb3     = (const float*)d_in[5];
  const float* cw5     = (const float*)d_in[6];
  const float* cb5     = (const float*)d_in[7];
  const float* cw7     = (const float*)d_in[8];
  const float* cb7     = (const float*)d_in[9];
  const float* hw_w    = (const float*)d_in[10];
  const float* hw_b    = (const float*)d_in[11];
  const float* hwg_w   = (const float*)d_in[12];
  const float* hwg_b   = (const float*)d_in[13];
  const float* wih0f   = (const float*)d_in[14];
  const float* whh0f   = (const float*)d_in[15];
  const float* b0f     = (const float*)d_in[16];
  const float* wih0b   = (const float*)d_in[17];
  const float* whh0b   = (const float*)d_in[18];
  const float* b0b     = (const float*)d_in[19];
  const float* wih1f   = (const float*)d_in[20];
  const float* whh1f   = (const float*)d_in[21];
  const float* b1f     = (const float*)d_in[22];
  const float* wih1b   = (const float*)d_in[23];
  const float* whh1b   = (const float*)d_in[24];
  const float* b1b     = (const float*)d_in[25];
  const float* cls_w   = (const float*)d_in[26];
  const float* cls_b   = (const float*)d_in[27];
  const float* trans   = (const float*)d_in[28];
  const float* start_t = (const float*)d_in[29];
  const float* end_t   = (const float*)d_in[30];

  // Workspace layout. tbl fp32 | bf16 weights | bf16 activations. ~210 MB.
  char* ws = (char*)d_ws;
  const size_t OFF_W0 = 393216;                            // tbl is [0, 372KB)
  const size_t OFF_W1 = OFF_W0 + (size_t)1024 * 192 * 2;
  const size_t OFF_WA = OFF_W1 + (size_t)1024 * 256 * 2;
  const size_t OFF_WG = OFF_WA + (size_t)192 * 192 * 2;
  const size_t OFF_WH = OFF_WG + (size_t)192 * 192 * 2;    // 4x whh bf16 (512KB)
  const size_t OFF_A  = OFF_WH + (size_t)4 * 512 * 128 * 2;
  const size_t SZ_A   = (size_t)kM * 192 * 2;              // 24 MB
  const size_t OFF_B  = OFF_A + SZ_A;
  const size_t OFF_O0 = OFF_B + SZ_A;                      // out0 bf16 (32MB); em fp32 later
  const size_t OFF_XG = OFF_O0 + (size_t)kM * 256 * 2;     // xg bf16 dual (128MB)
  float* tbl  = (float*)ws;
  bf16*  W0b  = (bf16*)(ws + OFF_W0);
  bf16*  W1b  = (bf16*)(ws + OFF_W1);
  bf16*  WAb  = (bf16*)(ws + OFF_WA);
  bf16*  WGb  = (bf16*)(ws + OFF_WG);
  bf16*  WHb  = (bf16*)(ws + OFF_WH);
  bf16*  bufA = (bf16*)(ws + OFF_A);
  bf16*  bufB = (bf16*)(ws + OFF_B);
  bf16*  out0 = (bf16*)(ws + OFF_O0);
  bf16*  out1 = (bf16*)(ws + OFF_A);                       // bufA/bufB dead by rec1
  bf16*  xg   = (bf16*)(ws + OFF_XG);
  float* em   = (float*)(ws + OFF_O0);                     // out0 dead after proj1
  float* resv = (float*)(ws + OFF_O0 + (size_t)kM * 17 * 4);

  // fused weight conversion + char-projection-table prepass
  k_wprep<<<3468, 256, 0, stream>>>(wih0f, wih0b, wih1f, wih1b, hw_w, hwg_w,
                                    whh0f, whh0b, whh1f, whh1b,
                                    emb, cw3, cw5, cw7,
                                    W0b, W1b, WAb, WGb, WHb, tbl);

  k_conv<<<kB * (kS / 64), 192, 0, stream>>>(x, tbl, cb3, cb5, cb7, bufA);
  k_hw<<<dim3(3, kM / 128), 256, 0, stream>>>(bufA, WAb, hw_b, WGb, hwg_b, bufB);

  k_pgemm<<<dim3(8, kM / 128), 256, 0, stream>>>(bufB, 192, W0b, b0f, b0b, xg);
  k_rec6<<<128, 256, 0, stream>>>(xg, WHb + 0 * 65536, WHb + 1 * 65536, out0);
  k_pgemm<<<dim3(8, kM / 128), 256, 0, stream>>>(out0, 256, W1b, b1f, b1b, xg);
  k_rec6<<<128, 256, 0, stream>>>(xg, WHb + 2 * 65536, WHb + 3 * 65536, out1);

  k_cls<<<kM / 128, 256, 0, stream>>>(out1, cls_w, cls_b, x, em);
  k_crf<<<kB, 64, 0, stream>>>(em, tags, mask, trans, start_t, end_t, resv);
  k_loss<<<1, 128, 0, stream>>>(resv, (float*)d_out);
}